// Round 4
// baseline (1863.618 us; speedup 1.0000x reference)
//
#include <hip/hip_runtime.h>
#include <hip/hip_bf16.h>
#include <math.h>

typedef __hip_bfloat16 bf16;
typedef short bf16x8 __attribute__((ext_vector_type(8)));
typedef short s16x4 __attribute__((ext_vector_type(4)));
typedef float f32x4 __attribute__((ext_vector_type(4)));

__device__ __forceinline__ float b2f(bf16 x) { return __bfloat162float(x); }
__device__ __forceinline__ bf16  f2b(float x) { return __float2bfloat16(x); }
__device__ __forceinline__ float leaky(float x) { return x >= 0.0f ? x : 0.01f * x; }
__device__ __forceinline__ float sb2f(short s) {
  return __uint_as_float(((unsigned)(unsigned short)s) << 16);
}
__device__ __forceinline__ short f2bs(float x) {
  unsigned u = __float_as_uint(x);
  u += 0x7FFFu + ((u >> 16) & 1u);
  return (short)(u >> 16);
}
__device__ __forceinline__ float ldF(const void* p, size_t i, int f) {
  return f ? ((const float*)p)[i] : b2f(((const bf16*)p)[i]);
}
__device__ __forceinline__ bf16x8 ldA8(const char* row, int k, int f) {
  if (!f) return *(const bf16x8*)(row + (size_t)k * 2);
  const float4* p = (const float4*)(row + (size_t)k * 4);
  float4 a = p[0], b = p[1];
  bf16x8 r;
  r[0] = f2bs(a.x); r[1] = f2bs(a.y); r[2] = f2bs(a.z); r[3] = f2bs(a.w);
  r[4] = f2bs(b.x); r[5] = f2bs(b.y); r[6] = f2bs(b.z); r[7] = f2bs(b.w);
  return r;
}
__device__ __forceinline__ bf16x8 ldA8sum(const bf16* base, int K0, int s, int t, int k) {
  bf16x8 u = *(const bf16x8*)(base + (size_t)s * K0 + k);
  bf16x8 v = *(const bf16x8*)(base + (size_t)t * K0 + k);
  bf16x8 r;
#pragma unroll
  for (int j = 0; j < 8; ++j) r[j] = f2bs(sb2f(u[j]) + sb2f(v[j]));
  return r;
}

// ---- dtype detector ----
__global__ void k_detect(const unsigned* __restrict__ w, int* __restrict__ flag) {
  __shared__ int cnt[256];
  unsigned x = w[threadIdx.x];
  unsigned ex = (x >> 7) & 0xFFu;
  cnt[threadIdx.x] = (ex >= 96u && ex <= 144u) ? 1 : 0;
  __syncthreads();
  for (int s = 128; s > 0; s >>= 1) {
    if (threadIdx.x < s) cnt[threadIdx.x] += cnt[threadIdx.x + s];
    __syncthreads();
  }
  if (threadIdx.x == 0) *flag = (cnt[0] < 128) ? 1 : 0;  // 1 = f32 inputs
}

// ---- all-weights canonicalization in one launch ----
struct WArgs { const void* src[21]; int beg[22]; int len[21]; };
__global__ void k_cvt_all(WArgs wa, bf16* __restrict__ dst, int total,
                          const int* __restrict__ flagp) {
  int f = *flagp;
  for (int i = blockIdx.x * 256 + threadIdx.x; i < total; i += gridDim.x * 256) {
    int t = 0;
    while (t < 20 && i >= wa.beg[t + 1]) ++t;
    int loc = i - wa.beg[t];
    bf16 v = f2b(0.0f);
    if (loc < wa.len[t])
      v = f ? f2b(((const float*)wa.src[t])[loc]) : ((const bf16*)wa.src[t])[loc];
    dst[i] = v;
  }
}

// ---- big-input f32->bf16 canonicalization (no-op in bf16 mode) ----
__global__ void k_cvt3(const float* __restrict__ a, bf16* __restrict__ da, size_t na,
                       const float* __restrict__ b, bf16* __restrict__ db, size_t nb,
                       const float* __restrict__ c, bf16* __restrict__ dc, size_t nc,
                       const int* __restrict__ flagp) {
  if (!*flagp) return;
  size_t tot = (na + nb + nc) >> 2;
  for (size_t i = (size_t)blockIdx.x * 256 + threadIdx.x; i < tot;
       i += (size_t)gridDim.x * 256) {
    size_t j = i << 2;
    const float* s; bf16* d; size_t loc;
    if (j < na)           { s = a; d = da; loc = j; }
    else if (j < na + nb) { s = b; d = db; loc = j - na; }
    else                  { s = c; d = dc; loc = j - na - nb; }
    float4 v = *(const float4*)(s + loc);
    s16x4 o; o[0] = f2bs(v.x); o[1] = f2bs(v.y); o[2] = f2bs(v.z); o[3] = f2bs(v.w);
    *(s16x4*)(d + loc) = o;
  }
}

__global__ void k_izero(int* __restrict__ p, int n) {
  int i = blockIdx.x * 256 + threadIdx.x;
  for (; i < n; i += gridDim.x * 256) p[i] = 0;
}

// ---------------- CSR build ----------------
__global__ void k_hist(const int* __restrict__ seg, int* __restrict__ deg, int n) {
  int i = blockIdx.x * 256 + threadIdx.x;
  if (i < n) atomicAdd(&deg[seg[i]], 1);
}

// ---- multi-block hierarchical scan ----
__global__ __launch_bounds__(256)
void k_scan_local(const int* __restrict__ deg, int* __restrict__ rp,
                  int* __restrict__ bsum, int n) {
  __shared__ int sh[256];
  int tid = threadIdx.x;
  int base = blockIdx.x * 4096 + tid * 16;
  int v[16]; int s = 0;
#pragma unroll
  for (int j = 0; j < 16; ++j) { v[j] = (base + j < n) ? deg[base + j] : 0; s += v[j]; }
  sh[tid] = s;
  __syncthreads();
  for (int o = 1; o < 256; o <<= 1) {
    int t = (tid >= o) ? sh[tid - o] : 0;
    __syncthreads();
    sh[tid] += t;
    __syncthreads();
  }
  int run = sh[tid] - s;
#pragma unroll
  for (int j = 0; j < 16; ++j) {
    run += v[j];
    if (base + j < n) rp[base + j + 1] = run;
  }
  if (tid == 255) bsum[blockIdx.x] = sh[255];
  if (blockIdx.x == 0 && tid == 0) rp[0] = 0;
}
__global__ __launch_bounds__(256)
void k_scan_bsum(int* __restrict__ bsum, int nb) {
  __shared__ int sh[256];
  __shared__ int carry;
  int tid = threadIdx.x;
  if (tid == 0) carry = 0;
  __syncthreads();
  for (int base = 0; base < nb; base += 256) {
    int i = base + tid;
    int v = (i < nb) ? bsum[i] : 0;
    sh[tid] = v;
    __syncthreads();
    for (int o = 1; o < 256; o <<= 1) {
      int t = (tid >= o) ? sh[tid - o] : 0;
      __syncthreads();
      sh[tid] += t;
      __syncthreads();
    }
    if (i < nb) bsum[i] = carry + sh[tid] - v;
    int tot = sh[255];
    __syncthreads();
    if (tid == 0) carry += tot;
    __syncthreads();
  }
}
__global__ __launch_bounds__(256)
void k_scan_add(int* __restrict__ rp, const int* __restrict__ bsum, int n) {
  int b = blockIdx.x + 1;
  int ofs = bsum[b];
  int base = b * 4096 + threadIdx.x * 16;
#pragma unroll
  for (int j = 0; j < 16; ++j) {
    int idx = base + j + 1;
    if (idx <= n) rp[idx] += ofs;
  }
}

// slot + materialize CSR-ordered aux values + inverse permutation
__global__ void k_slot(const int* __restrict__ seg, const int* __restrict__ rp,
                       int* __restrict__ cur, int* __restrict__ eid,
                       const int* __restrict__ aux, int* __restrict__ auxval,
                       int* __restrict__ pos, int n) {
  int i = blockIdx.x * 256 + threadIdx.x;
  if (i >= n) return;
  int t = seg[i];
  int p = atomicAdd(&cur[t], 1);
  int j = rp[t] + p;
  eid[j] = i;
  if (auxval) auxval[j] = aux[i];
  if (pos) pos[i] = j;
}

// ---------------- gather-mean ----------------
__global__ void k_gmean(const void* __restrict__ X, const void* __restrict__ Xc, int mode,
                        const int* __restrict__ rp, const int* __restrict__ eid,
                        bf16* __restrict__ out, int n, int width,
                        const int* __restrict__ flagp) {
  int f = (mode == 2) ? *flagp : mode;
  if (Xc && f) { X = Xc; f = 0; }
  int d = threadIdx.x;
  int row = blockIdx.x * blockDim.y + threadIdx.y;
  if (row >= n) return;
  int b = rp[row], e = rp[row + 1];
  float s = 0.0f;
  for (int j = b; j < e; ++j) s += ldF(X, (size_t)eid[j] * width + d, f);
  out[(size_t)row * width + d] = f2b(s / fmaxf((float)(e - b), 1.0f));
}

// =================== MFMA GEMM: C[.,colofs+0..63] = A @ Wh^T (+bias) ===================
__global__ __launch_bounds__(256)
void k_mgemm(const void* __restrict__ A0, const void* __restrict__ A0c, int m0mode, int K0,
             const void* __restrict__ A1, int m1mode, int Ktot,
             const bf16* __restrict__ W, int whs, const bf16* __restrict__ bias,
             bf16* __restrict__ C, int cs, int M,
             const int* __restrict__ gs, const int* __restrict__ gd,
             const int* __restrict__ flagp) {
  int tid = threadIdx.x;
  int w = tid >> 6, lane = tid & 63, l15 = lane & 15, q = lane >> 4;
  int h = blockIdx.y;
  int fl = *flagp;
  int f0 = (m0mode == 2) ? fl : m0mode;
  if (A0c && f0) { A0 = A0c; f0 = 0; }
  int f1 = (m1mode == 2) ? fl : m1mode;
  const bf16* Wh = W + (size_t)h * whs;
  int colofs = h * 64;
  int m0 = blockIdx.x * 64 + w * 16;
  int mA = m0 + l15; if (mA > M - 1) mA = M - 1;
  int sA = 0, tA = 0;
  const char* rowA0 = nullptr;
  if (gs) { sA = gs[mA]; tA = gd[mA]; }
  else rowA0 = (const char*)A0 + (size_t)mA * K0 * (f0 ? 4 : 2);
  const char* rowA1 = A1 ? (const char*)A1 + (size_t)mA * (Ktot - K0) * (f1 ? 4 : 2) : nullptr;

  f32x4 acc[4] = {{0,0,0,0},{0,0,0,0},{0,0,0,0},{0,0,0,0}};
  for (int k = q * 8; k < Ktot; k += 32) {
    bf16x8 a;
    if (k < K0) a = gs ? ldA8sum((const bf16*)A0, K0, sA, tA, k) : ldA8(rowA0, k, f0);
    else        a = ldA8(rowA1, k - K0, f1);
    const bf16* wb = Wh + (size_t)l15 * Ktot + k;
#pragma unroll
    for (int t = 0; t < 4; ++t)
      acc[t] = __builtin_amdgcn_mfma_f32_16x16x32_bf16(
          a, *(const bf16x8*)(wb + (size_t)(t * 16) * Ktot), acc[t], 0, 0, 0);
  }
#pragma unroll
  for (int t = 0; t < 4; ++t) {
    int col = t * 16 + l15;
    float bv = bias ? b2f(bias[colofs + col]) : 0.0f;
#pragma unroll
    for (int r = 0; r < 4; ++r) {
      int m = m0 + q * 4 + r;
      if (m < M) C[(size_t)m * cs + colofs + col] = f2b(acc[t][r] + bv);
    }
  }
}

// ====== fused combine with ON-THE-FLY projections, all 4 heads ======
// fo(e,h,:) = A[e]@Wf_h^T + S[gi[e]]@Wn1_h^T + S[gj[e]]@Wn2_h^T + bias_h
// logits lg4[pos(e)*4+h] = sum_col leaky(fo)*attn ; optional fout[e] = sum_h leaky(fo)
template<int NKA, int NKS, bool HASF>
__global__ __launch_bounds__(256)
void k_mcombG(const void* __restrict__ A, const void* __restrict__ Ac, int mode,
              const bf16* __restrict__ Wf, int whsF,
              const bf16* __restrict__ S, const bf16* __restrict__ Sc,
              const bf16* __restrict__ Wn1, const bf16* __restrict__ Wn2, int whsS,
              const bf16* __restrict__ bias, const bf16* __restrict__ attn,
              const int* __restrict__ gi, const int* __restrict__ gj,
              const int* __restrict__ posw,
              float* __restrict__ lg4, bf16* __restrict__ fout,
              int M, const int* __restrict__ flagp) {
  constexpr int KA = NKA * 32, KS = NKS * 32;
  int tid = threadIdx.x;
  int w = tid >> 6, lane = tid & 63, l15 = lane & 15, q = lane >> 4;
  int fl = *flagp;
  int f = (mode == 2) ? fl : mode;
  if (Ac && f) { A = Ac; f = 0; }
  if (Sc && fl) S = Sc;
  int m0 = blockIdx.x * 64 + w * 16;
  int mA = m0 + l15; if (mA > M - 1) mA = M - 1;
  const char* rowA = (const char*)A + (size_t)mA * KA * (f ? 4 : 2);
  // A-fragments (streamed) + gathered src/dst table fragments
  bf16x8 af[NKA];
#pragma unroll
  for (int i = 0; i < NKA; ++i) af[i] = ldA8(rowA, q * 8 + 32 * i, f);
  const bf16* rowS = S + (size_t)gi[mA] * KS;
  const bf16* rowD = S + (size_t)gj[mA] * KS;
  bf16x8 as_[NKS], ad_[NKS];
#pragma unroll
  for (int i = 0; i < NKS; ++i) {
    as_[i] = *(const bf16x8*)(rowS + q * 8 + 32 * i);
    ad_[i] = *(const bf16x8*)(rowD + q * 8 + 32 * i);
  }
  int pIdx[4]; bool okr[4];
#pragma unroll
  for (int r = 0; r < 4; ++r) {
    int m = m0 + q * 4 + r;
    okr[r] = m < M; int mc = okr[r] ? m : M - 1;
    pIdx[r] = posw ? posw[mc] : mc;
  }
  f32x4 fs[4];
  if (HASF) {
#pragma unroll
    for (int t = 0; t < 4; ++t) fs[t] = {0, 0, 0, 0};
  }
#pragma unroll
  for (int h = 0; h < 4; ++h) {
    const bf16* Wfh = Wf + (size_t)h * whsF;
    const bf16* W1h = Wn1 + (size_t)h * whsS;
    const bf16* W2h = Wn2 + (size_t)h * whsS;
    f32x4 acc[4] = {{0,0,0,0},{0,0,0,0},{0,0,0,0},{0,0,0,0}};
#pragma unroll
    for (int i = 0; i < NKA; ++i) {
      const bf16* wf = Wfh + (size_t)l15 * KA + q * 8 + 32 * i;
#pragma unroll
      for (int t = 0; t < 4; ++t)
        acc[t] = __builtin_amdgcn_mfma_f32_16x16x32_bf16(
            af[i], *(const bf16x8*)(wf + (size_t)(t * 16) * KA), acc[t], 0, 0, 0);
    }
#pragma unroll
    for (int i = 0; i < NKS; ++i) {
      const bf16* w1 = W1h + (size_t)l15 * KS + q * 8 + 32 * i;
      const bf16* w2 = W2h + (size_t)l15 * KS + q * 8 + 32 * i;
#pragma unroll
      for (int t = 0; t < 4; ++t)
        acc[t] = __builtin_amdgcn_mfma_f32_16x16x32_bf16(
            as_[i], *(const bf16x8*)(w1 + (size_t)(t * 16) * KS), acc[t], 0, 0, 0);
#pragma unroll
      for (int t = 0; t < 4; ++t)
        acc[t] = __builtin_amdgcn_mfma_f32_16x16x32_bf16(
            ad_[i], *(const bf16x8*)(w2 + (size_t)(t * 16) * KS), acc[t], 0, 0, 0);
    }
    float bv[4], av[4];
#pragma unroll
    for (int t = 0; t < 4; ++t) {
      bv[t] = b2f(bias[h * 64 + t * 16 + l15]);
      av[t] = b2f(attn[h * 64 + t * 16 + l15]);
    }
    float part[4];
#pragma unroll
    for (int r = 0; r < 4; ++r) {
      float p = 0.0f;
#pragma unroll
      for (int t = 0; t < 4; ++t) {
        float v = acc[t][r] + bv[t];
        v = leaky(v);
        p += v * av[t];
        if (HASF) fs[t][r] += v;
      }
      part[r] = p;
    }
#pragma unroll
    for (int o = 1; o < 16; o <<= 1)
#pragma unroll
      for (int r = 0; r < 4; ++r) part[r] += __shfl_xor(part[r], o, 64);
    if (l15 == 0) {
#pragma unroll
      for (int r = 0; r < 4; ++r)
        if (okr[r]) lg4[(size_t)pIdx[r] * 4 + h] = part[r];
    }
  }
  if (HASF && fout) {
#pragma unroll
    for (int t = 0; t < 4; ++t) {
      int col = t * 16 + l15;
#pragma unroll
      for (int r = 0; r < 4; ++r)
        if (okr[r]) fout[(size_t)(m0 + q * 4 + r) * 64 + col] = f2b(fs[t][r]);
    }
  }
}

// ---------------- fused per-row CSR softmax (normalizes in place) ----------------
__global__ __launch_bounds__(256)
void k_smax4_csr(float* __restrict__ lg, const int* __restrict__ rp, int n) {
  int tid = blockIdx.x * 256 + threadIdx.x;
  int row = tid >> 2, h = tid & 3;
  if (row >= n) return;
  int b = rp[row], e = rp[row + 1];
  float m = -INFINITY;
  for (int j = b; j < e; ++j) m = fmaxf(m, lg[(size_t)j * 4 + h]);
  float s = 0.0f;
  for (int j = b; j < e; ++j) {
    float ex = expf(lg[(size_t)j * 4 + h] - m);
    lg[(size_t)j * 4 + h] = ex;
    s += ex;
  }
  float inv = 1.0f / s;
  for (int j = b; j < e; ++j) lg[(size_t)j * 4 + h] *= inv;
}
__global__ __launch_bounds__(256)
void k_smax4_eid(float* __restrict__ lg, const int* __restrict__ rp,
                 const int* __restrict__ eid, int n) {
  int tid = blockIdx.x * 256 + threadIdx.x;
  int row = tid >> 2, h = tid & 3;
  if (row >= n) return;
  int b = rp[row], e = rp[row + 1];
  float m = -INFINITY;
  for (int j = b; j < e; ++j) m = fmaxf(m, lg[(size_t)eid[j] * 4 + h]);
  float s = 0.0f;
  for (int j = b; j < e; ++j) {
    float ex = expf(lg[(size_t)eid[j] * 4 + h] - m);
    lg[(size_t)eid[j] * 4 + h] = ex;
    s += ex;
  }
  float inv = 1.0f / s;
  for (int j = b; j < e; ++j) lg[(size_t)eid[j] * 4 + h] *= inv;
}

// ---- P1 epilogue: one node/block, head = threadIdx.y (wave), normalized weights ----
__global__ __launch_bounds__(256)
void k_ghnode(const bf16* __restrict__ H, const float* __restrict__ lg4c,
              const int* __restrict__ rp, const int* __restrict__ srcv,
              bf16* __restrict__ hnode, int N) {
  int d = threadIdx.x, h = threadIdx.y;
  int n = blockIdx.x;
  int b = rp[n], e = rp[n + 1];
  float s = 0.0f;
  for (int j = b; j < e; ++j)
    s += b2f(H[(size_t)srcv[j] * 256 + h * 64 + d]) * lg4c[(size_t)j * 4 + h];
  float v = leaky(s);
  __shared__ float sh[4][64];
  if (h > 0) sh[h][d] = v;
  __syncthreads();
  if (h == 0)
    hnode[(size_t)n * 64 + d] = f2b(v + sh[1][d] + sh[2][d] + sh[3][d]);
}

// ---- P2 epilogue: normalized lgE4 in CSR order (head h), lsv materialized ----
__global__ void k_gout2(const bf16* __restrict__ M1, const float* __restrict__ lgE4,
                        int h, const int* __restrict__ rp, const int* __restrict__ lsv,
                        float* __restrict__ out, int E, int first) {
  int d = threadIdx.x;
  int t = blockIdx.x * 4 + threadIdx.y;
  if (t >= E) return;
  int b = rp[t], e = rp[t + 1];
  float s = 0.0f;
  for (int j = b; j < e; ++j)
    s += b2f(M1[(size_t)lsv[j] * 64 + d]) * lgE4[(size_t)j * 4 + h];
  float val = leaky(s);
  if (first) out[(size_t)t * 64 + d] = val;
  else       out[(size_t)t * 64 + d] += val;
}

// ---- P3 epilogue: normalized a (edge-order), lsv materialized ----
__global__ void k_gout3(const bf16* __restrict__ M2, const float* __restrict__ lg4n,
                        const int* __restrict__ rp, const int* __restrict__ lsv,
                        float* __restrict__ out, int E, int h) {
  int d = threadIdx.x;
  int t = blockIdx.x * 4 + threadIdx.y;
  if (t >= E) return;
  int b = rp[t], e = rp[t + 1];
  float s = 0.0f;
  for (int j = b; j < e; ++j) s += b2f(M2[(size_t)lsv[j] * 64 + d]);
  float a = lg4n[(size_t)t * 4 + h];
  out[(size_t)t * 64 + d] += leaky(a * s);
}

// ---- P3 pre: ne[e] = hnode[src[e]] + hnode[dst[e]] ----
__global__ void k_addpair(const bf16* __restrict__ hn, const int* __restrict__ src,
                          const int* __restrict__ dst, bf16* __restrict__ ne, int E) {
  int d = threadIdx.x;
  int e = blockIdx.x * 4 + threadIdx.y;
  if (e >= E) return;
  ne[(size_t)e * 64 + d] =
      f2b(b2f(hn[(size_t)src[e] * 64 + d]) + b2f(hn[(size_t)dst[e] * 64 + d]));
}

__global__ void k_cast(void* __restrict__ out, const float* __restrict__ a, size_t n,
                       const int* __restrict__ flagp) {
  int f = *flagp;
  size_t i = (size_t)blockIdx.x * blockDim.x + threadIdx.x;
  size_t st = (size_t)gridDim.x * blockDim.x;
  for (; i < n; i += st) {
    if (f) ((float*)out)[i] = a[i];
    else   ((bf16*)out)[i] = f2b(a[i]);
  }
}

extern "C" void kernel_launch(void* const* d_in, const int* in_sizes, int n_in,
                              void* d_out, int out_size, void* d_ws, size_t ws_size,
                              hipStream_t stream) {
  const int* src  = (const int*)d_in[24];
  const int* dst  = (const int*)d_in[25];
  const int* lsrc = (const int*)d_in[26];
  const int* ldst = (const int*)d_in[27];

  const int N  = in_sizes[0] / 128;
  const int E  = in_sizes[24];
  const int EL = in_sizes[26];
  (void)n_in; (void)out_size; (void)ws_size;

  // ---- workspace (~137 MB) ----
  char* base = (char*)d_ws;
  size_t off = 0;
  auto alloc = [&](size_t bytes) -> char* {
    char* p = base + off;
    off = (off + bytes + 255) & ~(size_t)255;
    return p;
  };
  int* flag = (int*)alloc(256);
  size_t wofs[28]; size_t wtot = 0;
  for (int i = 3; i <= 23; ++i) { wofs[i] = wtot; wtot += (size_t)((in_sizes[i] + 127) & ~127); }
  bf16* WA = (bf16*)alloc(wtot * 2);

  int*   tmpi  = (int*)alloc((size_t)2 * E * 4);        // deg | cur
  int*   rpN   = (int*)alloc((size_t)(N + 1) * 4);
  int*   eidN  = (int*)alloc((size_t)E * 4);
  int*   srcv  = (int*)alloc((size_t)E * 4);            // src[eid] in CSR order
  int*   posN  = (int*)alloc((size_t)E * 4);            // edge -> CSR slot
  int*   rpE   = (int*)alloc((size_t)(E + 1) * 4);
  int*   eidEL = (int*)alloc((size_t)EL * 4);
  int*   lsv   = (int*)alloc((size_t)EL * 4);           // lsrc[eid] in CSR order
  int*   posE  = (int*)alloc((size_t)EL * 4);           // lg-edge -> CSR slot
  int*   bsum  = (int*)alloc(((size_t)((E > N ? E : N) + 4095) / 4096 + 8) * 4);
  bf16*  fedge = (bf16*)alloc((size_t)E * 64 * 2);      // P1 -> P2/P3
  bf16*  hnode = (bf16*)alloc((size_t)N * 64 * 2);      // P1 -> P3
  float* outacc= (float*)alloc((size_t)E * 64 * 4);     // P2+ output accumulator
  bf16*  aggB  = (bf16*)alloc((size_t)E * 64 * 2);      // P1 agg / P2 aggx / P3 ne
  bf16*  SA    = (bf16*)alloc((size_t)N * 256 * 2 > (size_t)E * 64 * 2
                              ? (size_t)N * 256 * 2 : (size_t)E * 64 * 2);
  float* logE4 = (float*)alloc((size_t)E * 4 * 4);
  float* logEL4= (float*)alloc((size_t)EL * 4 * 4);
  bf16*  nb    = (bf16*)alloc((size_t)N * 128 * 2);     // nfeats bf16 canonical

  bf16* eb = (bf16*)outacc;       // efeats bf16 (P1 only; outacc first written in P2)
  bf16* xb = (bf16*)d_out;        // xfeats bf16 (d_out scratch until final cast)

  dim3 blk(256);
  const unsigned tN = (N + 63) / 64, tEg = (E + 63) / 64, tELg = (EL + 63) / 64;
  const unsigned gE4 = (E + 3) / 4;
  const unsigned cE = (E + 255) / 256, cEL = (EL + 255) / 256;
  const int nbN = (N + 4095) / 4096, nbE = (E + 4095) / 4096;

  // ---- dtype detect + weights + big-input canonicalization ----
  k_detect<<<dim3(1), blk, 0, stream>>>((const unsigned*)d_in[0], flag);
  WArgs wa;
  for (int i = 3; i <= 23; ++i) {
    wa.src[i - 3] = d_in[i];
    wa.beg[i - 3] = (int)wofs[i];
    wa.len[i - 3] = in_sizes[i];
  }
  wa.beg[21] = (int)wtot;
  k_cvt_all<<<dim3(512), blk, 0, stream>>>(wa, WA, (int)wtot, flag);
  k_cvt3<<<dim3(2048), blk, 0, stream>>>(
      (const float*)d_in[0], nb, (size_t)N * 128,
      (const float*)d_in[1], eb, (size_t)E * 128,
      (const float*)d_in[2], xb, (size_t)EL * 64, flag);

  // ---- CSR builds: dst->N (graph), ldst->E (line graph) ----
  int* deg = tmpi; int* cur = tmpi + E;
  k_izero<<<dim3(1024), blk, 0, stream>>>(tmpi, 2 * E);
  k_hist<<<dim3(cE), blk, 0, stream>>>(dst, deg, E);
  k_scan_local<<<dim3(nbN), blk, 0, stream>>>(deg, rpN, bsum, N);
  k_scan_bsum<<<dim3(1), blk, 0, stream>>>(bsum, nbN);
  if (nbN > 1) k_scan_add<<<dim3(nbN - 1), blk, 0, stream>>>(rpN, bsum, N);
  k_slot<<<dim3(cE), blk, 0, stream>>>(dst, rpN, cur, eidN, src, srcv, posN, E);
  k_izero<<<dim3(1024), blk, 0, stream>>>(tmpi, 2 * E);
  k_hist<<<dim3(cEL), blk, 0, stream>>>(ldst, deg, EL);
  k_scan_local<<<dim3(nbE), blk, 0, stream>>>(deg, rpE, bsum, E);
  k_scan_bsum<<<dim3(1), blk, 0, stream>>>(bsum, nbE);
  if (nbE > 1) k_scan_add<<<dim3(nbE - 1), blk, 0, stream>>>(rpE, bsum, E);
  k_slot<<<dim3(cEL), blk, 0, stream>>>(ldst, rpE, cur, eidEL, lsrc, lsv, posE, EL);

  // ================= Phase 1: EGAT =================
  k_gmean<<<dim3((N + 1) / 2), dim3(128, 2), 0, stream>>>(d_in[1], eb, 2, rpN, eidN,
                                                          aggB, N, 128, flag);
  // fo = efeats@Wfij + nfeats[src]@Wni + nfeats[dst]@Wnj + bias (on-the-fly)
  k_mcombG<4, 4, true><<<dim3(tEg), blk, 0, stream>>>(
      d_in[1], eb, 2, WA + wofs[5], 8192,
      (const bf16*)d_in[0], nb, WA + wofs[3], WA + wofs[4], 8192,
      WA + wofs[9], WA + wofs[8], src, dst, posN, logE4, fedge, E, flag);
  k_smax4_csr<<<dim3((N * 4 + 255) / 256), blk, 0, stream>>>(logE4, rpN, N);
  k_mgemm<<<dim3(tN, 4), blk, 0, stream>>>(d_in[0], nb, 2, 128, aggB, 0, 256,
      WA + wofs[6], 16384, WA + wofs[7], SA, 256, N, nullptr, nullptr, flag);
  k_ghnode<<<dim3(N), dim3(64, 4), 0, stream>>>(SA, logE4, rpN, srcv, hnode, N);

  // ================= Phase 2: line-graph branch =================
  k_gmean<<<dim3(gE4), dim3(64, 4), 0, stream>>>(d_in[2], xb, 2, rpE, eidEL, aggB, E, 64, flag);
  // all-heads logits in one pass: lgf = xfeats@Wfij + fedge[lsrc]@Wni + fedge[ldst]@Wnj + bias
  k_mcombG<2, 2, false><<<dim3(tELg), blk, 0, stream>>>(
      d_in[2], xb, 2, WA + wofs[12], 4096,
      fedge, nullptr, WA + wofs[10], WA + wofs[11], 4096,
      WA + wofs[16], WA + wofs[15], lsrc, ldst, posE, logEL4, nullptr, EL, flag);
  k_smax4_csr<<<dim3((E * 4 + 255) / 256), blk, 0, stream>>>(logEL4, rpE, E);
  for (int h = 0; h < 4; ++h) {
    k_mgemm<<<dim3(tEg, 1), blk, 0, stream>>>(fedge, nullptr, 0, 64, aggB, 0, 128,
        WA + wofs[13] + (size_t)h * 8192, 0, WA + wofs[14] + h * 64,
        SA, 64, E, nullptr, nullptr, flag);
    k_gout2<<<dim3(gE4), dim3(64, 4), 0, stream>>>(SA, logEL4, h, rpE, lsv,
                                                   outacc, E, h == 0 ? 1 : 0);
  }

  // ================= Phase 3: graph branch =================
  // gf = fedge@Wfij + hnode[src]@Wni + hnode[dst]@Wnj + bias (edge-order logits)
  k_mcombG<2, 2, false><<<dim3(tEg), blk, 0, stream>>>(
      fedge, nullptr, 0, WA + wofs[19], 4096,
      hnode, nullptr, WA + wofs[17], WA + wofs[18], 4096,
      WA + wofs[23], WA + wofs[22], src, dst, nullptr, logE4, nullptr, E, flag);
  k_smax4_eid<<<dim3((N * 4 + 255) / 256), blk, 0, stream>>>(logE4, rpN, eidN, N);
  k_addpair<<<dim3(gE4), dim3(64, 4), 0, stream>>>(hnode, src, dst, aggB, E);
  for (int h = 0; h < 4; ++h) {
    k_mgemm<<<dim3(tEg, 1), blk, 0, stream>>>(aggB, nullptr, 0, 64, fedge, 0, 128,
        WA + wofs[20] + (size_t)h * 8192, 0, WA + wofs[21] + h * 64,
        SA, 64, E, nullptr, nullptr, flag);
    k_gout3<<<dim3(gE4), dim3(64, 4), 0, stream>>>(SA, logE4, rpE, lsv,
                                                   outacc, E, h);
  }

  k_cast<<<dim3(2048), blk, 0, stream>>>(d_out, outacc, (size_t)E * 64, flag);
}

// Round 5
// 1861.748 us; speedup vs baseline: 1.0010x; 1.0010x over previous
//
#include <hip/hip_runtime.h>
#include <hip/hip_bf16.h>
#include <math.h>

typedef __hip_bfloat16 bf16;
typedef short bf16x8 __attribute__((ext_vector_type(8)));
typedef short s16x4 __attribute__((ext_vector_type(4)));
typedef float f32x4 __attribute__((ext_vector_type(4)));

__device__ __forceinline__ float b2f(bf16 x) { return __bfloat162float(x); }
__device__ __forceinline__ bf16  f2b(float x) { return __float2bfloat16(x); }
__device__ __forceinline__ float leaky(float x) { return x >= 0.0f ? x : 0.01f * x; }
__device__ __forceinline__ float sb2f(short s) {
  return __uint_as_float(((unsigned)(unsigned short)s) << 16);
}
__device__ __forceinline__ short f2bs(float x) {
  unsigned u = __float_as_uint(x);
  u += 0x7FFFu + ((u >> 16) & 1u);
  return (short)(u >> 16);
}
__device__ __forceinline__ float ldF(const void* p, size_t i, int f) {
  return f ? ((const float*)p)[i] : b2f(((const bf16*)p)[i]);
}
__device__ __forceinline__ bf16x8 ldA8(const char* row, int k, int f) {
  if (!f) return *(const bf16x8*)(row + (size_t)k * 2);
  const float4* p = (const float4*)(row + (size_t)k * 4);
  float4 a = p[0], b = p[1];
  bf16x8 r;
  r[0] = f2bs(a.x); r[1] = f2bs(a.y); r[2] = f2bs(a.z); r[3] = f2bs(a.w);
  r[4] = f2bs(b.x); r[5] = f2bs(b.y); r[6] = f2bs(b.z); r[7] = f2bs(b.w);
  return r;
}
__device__ __forceinline__ bf16x8 ldA8sum(const bf16* base, int K0, int s, int t, int k) {
  bf16x8 u = *(const bf16x8*)(base + (size_t)s * K0 + k);
  bf16x8 v = *(const bf16x8*)(base + (size_t)t * K0 + k);
  bf16x8 r;
#pragma unroll
  for (int j = 0; j < 8; ++j) r[j] = f2bs(sb2f(u[j]) + sb2f(v[j]));
  return r;
}

// ---- dtype detector ----
__global__ void k_detect(const unsigned* __restrict__ w, int* __restrict__ flag) {
  __shared__ int cnt[256];
  unsigned x = w[threadIdx.x];
  unsigned ex = (x >> 7) & 0xFFu;
  cnt[threadIdx.x] = (ex >= 96u && ex <= 144u) ? 1 : 0;
  __syncthreads();
  for (int s = 128; s > 0; s >>= 1) {
    if (threadIdx.x < s) cnt[threadIdx.x] += cnt[threadIdx.x + s];
    __syncthreads();
  }
  if (threadIdx.x == 0) *flag = (cnt[0] < 128) ? 1 : 0;  // 1 = f32 inputs
}

// ---- all-weights canonicalization in one launch ----
struct WArgs { const void* src[21]; int beg[22]; int len[21]; };
__global__ void k_cvt_all(WArgs wa, bf16* __restrict__ dst, int total,
                          const int* __restrict__ flagp) {
  int f = *flagp;
  for (int i = blockIdx.x * 256 + threadIdx.x; i < total; i += gridDim.x * 256) {
    int t = 0;
    while (t < 20 && i >= wa.beg[t + 1]) ++t;
    int loc = i - wa.beg[t];
    bf16 v = f2b(0.0f);
    if (loc < wa.len[t])
      v = f ? f2b(((const float*)wa.src[t])[loc]) : ((const bf16*)wa.src[t])[loc];
    dst[i] = v;
  }
}

// ---- nfeats/xfeats f32->bf16 canonicalization (no-op in bf16 mode) ----
__global__ void k_cvt2(const float* __restrict__ a, bf16* __restrict__ da, size_t na,
                       const float* __restrict__ c, bf16* __restrict__ dc, size_t nc,
                       const int* __restrict__ flagp) {
  if (!*flagp) return;
  size_t tot = (na + nc) >> 2;
  for (size_t i = (size_t)blockIdx.x * 256 + threadIdx.x; i < tot;
       i += (size_t)gridDim.x * 256) {
    size_t j = i << 2;
    const float* s; bf16* d; size_t loc;
    if (j < na) { s = a; d = da; loc = j; }
    else        { s = c; d = dc; loc = j - na; }
    float4 v = *(const float4*)(s + loc);
    s16x4 o; o[0] = f2bs(v.x); o[1] = f2bs(v.y); o[2] = f2bs(v.z); o[3] = f2bs(v.w);
    *(s16x4*)(d + loc) = o;
  }
}

// ---- efeats -> ebC: permuted (CSR-order) canonical copy, width 128, both modes ----
__global__ void k_cvtp(const void* __restrict__ X, const int* __restrict__ eid,
                       bf16* __restrict__ out, int n, const int* __restrict__ flagp) {
  int f = *flagp;
  int row = blockIdx.x * 4 + threadIdx.y;
  if (row >= n) return;
  int e = eid[row];
  int d0 = threadIdx.x * 2;
  if (f) {
    float2 v = *(const float2*)((const float*)X + (size_t)e * 128 + d0);
    unsigned pack = ((unsigned)(unsigned short)f2bs(v.y) << 16) |
                    (unsigned)(unsigned short)f2bs(v.x);
    *(unsigned*)((char*)out + (size_t)row * 256 + d0 * 2) = pack;
  } else {
    *(unsigned*)((char*)out + (size_t)row * 256 + d0 * 2) =
        *(const unsigned*)((const char*)X + (size_t)e * 256 + d0 * 2);
  }
}

__global__ void k_izero(int* __restrict__ p, int n) {
  int i = blockIdx.x * 256 + threadIdx.x;
  for (; i < n; i += gridDim.x * 256) p[i] = 0;
}

// ---------------- CSR build ----------------
__global__ void k_hist(const int* __restrict__ seg, int* __restrict__ deg, int n) {
  int i = blockIdx.x * 256 + threadIdx.x;
  if (i < n) atomicAdd(&deg[seg[i]], 1);
}

__global__ __launch_bounds__(256)
void k_scan_local(const int* __restrict__ deg, int* __restrict__ rp,
                  int* __restrict__ bsum, int n) {
  __shared__ int sh[256];
  int tid = threadIdx.x;
  int base = blockIdx.x * 4096 + tid * 16;
  int v[16]; int s = 0;
#pragma unroll
  for (int j = 0; j < 16; ++j) { v[j] = (base + j < n) ? deg[base + j] : 0; s += v[j]; }
  sh[tid] = s;
  __syncthreads();
  for (int o = 1; o < 256; o <<= 1) {
    int t = (tid >= o) ? sh[tid - o] : 0;
    __syncthreads();
    sh[tid] += t;
    __syncthreads();
  }
  int run = sh[tid] - s;
#pragma unroll
  for (int j = 0; j < 16; ++j) {
    run += v[j];
    if (base + j < n) rp[base + j + 1] = run;
  }
  if (tid == 255) bsum[blockIdx.x] = sh[255];
  if (blockIdx.x == 0 && tid == 0) rp[0] = 0;
}
__global__ __launch_bounds__(256)
void k_scan_bsum(int* __restrict__ bsum, int nb) {
  __shared__ int sh[256];
  __shared__ int carry;
  int tid = threadIdx.x;
  if (tid == 0) carry = 0;
  __syncthreads();
  for (int base = 0; base < nb; base += 256) {
    int i = base + tid;
    int v = (i < nb) ? bsum[i] : 0;
    sh[tid] = v;
    __syncthreads();
    for (int o = 1; o < 256; o <<= 1) {
      int t = (tid >= o) ? sh[tid - o] : 0;
      __syncthreads();
      sh[tid] += t;
      __syncthreads();
    }
    if (i < nb) bsum[i] = carry + sh[tid] - v;
    int tot = sh[255];
    __syncthreads();
    if (tid == 0) carry += tot;
    __syncthreads();
  }
}
__global__ __launch_bounds__(256)
void k_scan_add(int* __restrict__ rp, const int* __restrict__ bsum, int n) {
  int b = blockIdx.x + 1;
  int ofs = bsum[b];
  int base = b * 4096 + threadIdx.x * 16;
#pragma unroll
  for (int j = 0; j < 16; ++j) {
    int idx = base + j + 1;
    if (idx <= n) rp[idx] += ofs;
  }
}

// slot + materialize CSR-ordered aux values + inverse permutation
__global__ void k_slot(const int* __restrict__ seg, const int* __restrict__ rp,
                       int* __restrict__ cur, int* __restrict__ eid,
                       const int* __restrict__ aux1, int* __restrict__ av1,
                       const int* __restrict__ aux2, int* __restrict__ av2,
                       int* __restrict__ pos, int n) {
  int i = blockIdx.x * 256 + threadIdx.x;
  if (i >= n) return;
  int t = seg[i];
  int p = atomicAdd(&cur[t], 1);
  int j = rp[t] + p;
  eid[j] = i;
  if (av1) av1[j] = aux1[i];
  if (av2) av2[j] = aux2[i];
  if (pos) pos[i] = j;
}

// translate line-graph indices into CSR-slot space
__global__ void k_xlat(const int* __restrict__ lsrc, const int* __restrict__ ldst,
                       const int* __restrict__ posN,
                       int* __restrict__ lsvE, int* __restrict__ ldvE,
                       int* __restrict__ lsvC, int n) {
  int i = blockIdx.x * 256 + threadIdx.x;
  if (i >= n) return;
  lsvE[i] = posN[lsrc[i]];
  ldvE[i] = posN[ldst[i]];
  lsvC[i] = posN[lsvC[i]];   // in-place: lsv held bond ids, now CSR slots
}

// ---------------- gather-mean (eid=null -> sequential CSR read; orow -> scatter row) ----
__global__ void k_gmean(const void* __restrict__ X, const void* __restrict__ Xc, int mode,
                        const int* __restrict__ rp, const int* __restrict__ eid,
                        const int* __restrict__ orow,
                        bf16* __restrict__ out, int n, int width,
                        const int* __restrict__ flagp) {
  int f = (mode == 2) ? *flagp : mode;
  if (Xc && f) { X = Xc; f = 0; }
  int d = threadIdx.x;
  int row = blockIdx.x * blockDim.y + threadIdx.y;
  if (row >= n) return;
  int b = rp[row], e = rp[row + 1];
  float s = 0.0f;
  for (int j = b; j < e; ++j)
    s += ldF(X, (size_t)(eid ? eid[j] : j) * width + d, f);
  int orw = orow ? orow[row] : row;
  out[(size_t)orw * width + d] = f2b(s / fmaxf((float)(e - b), 1.0f));
}

// =================== MFMA GEMM: C[.,colofs+0..63] = A @ Wh^T (+bias) ===================
__global__ __launch_bounds__(256)
void k_mgemm(const void* __restrict__ A0, const void* __restrict__ A0c, int m0mode, int K0,
             const void* __restrict__ A1, int m1mode, int Ktot,
             const bf16* __restrict__ W, int whs, const bf16* __restrict__ bias,
             bf16* __restrict__ C, int cs, int M,
             const int* __restrict__ flagp) {
  int tid = threadIdx.x;
  int w = tid >> 6, lane = tid & 63, l15 = lane & 15, q = lane >> 4;
  int h = blockIdx.y;
  int fl = *flagp;
  int f0 = (m0mode == 2) ? fl : m0mode;
  if (A0c && f0) { A0 = A0c; f0 = 0; }
  int f1 = (m1mode == 2) ? fl : m1mode;
  const bf16* Wh = W + (size_t)h * whs;
  int colofs = h * 64;
  int m0 = blockIdx.x * 64 + w * 16;
  int mA = m0 + l15; if (mA > M - 1) mA = M - 1;
  const char* rowA0 = (const char*)A0 + (size_t)mA * K0 * (f0 ? 4 : 2);
  const char* rowA1 = A1 ? (const char*)A1 + (size_t)mA * (Ktot - K0) * (f1 ? 4 : 2) : nullptr;

  f32x4 acc[4] = {{0,0,0,0},{0,0,0,0},{0,0,0,0},{0,0,0,0}};
  for (int k = q * 8; k < Ktot; k += 32) {
    bf16x8 a;
    if (k < K0) a = ldA8(rowA0, k, f0);
    else        a = ldA8(rowA1, k - K0, f1);
    const bf16* wb = Wh + (size_t)l15 * Ktot + k;
#pragma unroll
    for (int t = 0; t < 4; ++t)
      acc[t] = __builtin_amdgcn_mfma_f32_16x16x32_bf16(
          a, *(const bf16x8*)(wb + (size_t)(t * 16) * Ktot), acc[t], 0, 0, 0);
  }
#pragma unroll
  for (int t = 0; t < 4; ++t) {
    int col = t * 16 + l15;
    float bv = bias ? b2f(bias[colofs + col]) : 0.0f;
#pragma unroll
    for (int r = 0; r < 4; ++r) {
      int m = m0 + q * 4 + r;
      if (m < M) C[(size_t)m * cs + colofs + col] = f2b(acc[t][r] + bv);
    }
  }
}

// ---- dual-output GEMM (shared A): SWIZZLED outputs (h*64 + l15*4 + t) ----
__global__ __launch_bounds__(256)
void k_mgemm2(const void* __restrict__ A, const void* __restrict__ Ac, int mode, int K,
              const bf16* __restrict__ W1, const bf16* __restrict__ W2, int whs,
              bf16* __restrict__ C1, bf16* __restrict__ C2, int cs, int M,
              const int* __restrict__ flagp) {
  int tid = threadIdx.x;
  int w = tid >> 6, lane = tid & 63, l15 = lane & 15, q = lane >> 4;
  int h = blockIdx.y;
  int f = (mode == 2) ? *flagp : mode;
  if (Ac && f) { A = Ac; f = 0; }
  const bf16* W1h = W1 + (size_t)h * whs;
  const bf16* W2h = W2 + (size_t)h * whs;
  int colofs = h * 64;
  int m0 = blockIdx.x * 64 + w * 16;
  int mA = m0 + l15; if (mA > M - 1) mA = M - 1;
  const char* rowA = (const char*)A + (size_t)mA * K * (f ? 4 : 2);

  f32x4 a1[4] = {{0,0,0,0},{0,0,0,0},{0,0,0,0},{0,0,0,0}};
  f32x4 a2[4] = {{0,0,0,0},{0,0,0,0},{0,0,0,0},{0,0,0,0}};
  for (int k = q * 8; k < K; k += 32) {
    bf16x8 a = ldA8(rowA, k, f);
    const bf16* w1 = W1h + (size_t)l15 * K + k;
    const bf16* w2 = W2h + (size_t)l15 * K + k;
#pragma unroll
    for (int t = 0; t < 4; ++t) {
      a1[t] = __builtin_amdgcn_mfma_f32_16x16x32_bf16(
          a, *(const bf16x8*)(w1 + (size_t)(t * 16) * K), a1[t], 0, 0, 0);
      a2[t] = __builtin_amdgcn_mfma_f32_16x16x32_bf16(
          a, *(const bf16x8*)(w2 + (size_t)(t * 16) * K), a2[t], 0, 0, 0);
    }
  }
#pragma unroll
  for (int r = 0; r < 4; ++r) {
    int m = m0 + q * 4 + r;
    if (m < M) {
      s16x4 o1, o2;
#pragma unroll
      for (int t = 0; t < 4; ++t) { o1[t] = f2bs(a1[t][r]); o2[t] = f2bs(a2[t][r]); }
      *(s16x4*)(C1 + (size_t)m * cs + colofs + l15 * 4) = o1;
      *(s16x4*)(C2 + (size_t)m * cs + colofs + l15 * 4) = o2;
    }
  }
}

// ====== all-heads fused combine, CSR-ORDERED (P1/P3) ======
// A is CSR-ordered bf16 stream; sv random gather; dv run-constant (L1);
// logits + fout written sequentially at CSR slot.
template<int NK>
__global__ __launch_bounds__(256)
void k_mcomb4C(const bf16* __restrict__ A,
               const bf16* __restrict__ W, int whs,
               const bf16* __restrict__ bias, const bf16* __restrict__ attn,
               const bf16* __restrict__ G1, const bf16* __restrict__ G2, int gstr,
               const int* __restrict__ sv, const int* __restrict__ dv,
               float* __restrict__ lg4, bf16* __restrict__ fout, int M) {
  constexpr int K = NK * 32;
  int tid = threadIdx.x;
  int w = tid >> 6, lane = tid & 63, l15 = lane & 15, q = lane >> 4;
  int m0 = blockIdx.x * 64 + w * 16;
  int mA = m0 + l15; if (mA > M - 1) mA = M - 1;
  const bf16* rowA = A + (size_t)mA * K;
  bf16x8 af[NK];
#pragma unroll
  for (int i = 0; i < NK; ++i) af[i] = *(const bf16x8*)(rowA + q * 8 + 32 * i);
  int sIdx[4], dIdx[4], mcs[4]; bool okr[4];
#pragma unroll
  for (int r = 0; r < 4; ++r) {
    int m = m0 + q * 4 + r;
    okr[r] = m < M; int mc = okr[r] ? m : M - 1;
    mcs[r] = mc;
    sIdx[r] = sv[mc]; dIdx[r] = dv[mc];
  }
  // preload gathers: one coalesced 8B load per (row, head, table)
  s16x4 gv1[4][4], gv2[4][4];
#pragma unroll
  for (int r = 0; r < 4; ++r) {
    const s16x4* p1 = (const s16x4*)(G1 + (size_t)sIdx[r] * gstr) + l15;
    const s16x4* p2 = (const s16x4*)(G2 + (size_t)dIdx[r] * gstr) + l15;
#pragma unroll
    for (int h = 0; h < 4; ++h) { gv1[r][h] = p1[h * 16]; gv2[r][h] = p2[h * 16]; }
  }
  f32x4 fs[4] = {{0,0,0,0},{0,0,0,0},{0,0,0,0},{0,0,0,0}};
#pragma unroll
  for (int h = 0; h < 4; ++h) {
    const bf16* Wh = W + (size_t)h * whs;
    f32x4 acc[4] = {{0,0,0,0},{0,0,0,0},{0,0,0,0},{0,0,0,0}};
#pragma unroll
    for (int i = 0; i < NK; ++i) {
      const bf16* wb = Wh + (size_t)l15 * K + q * 8 + 32 * i;
#pragma unroll
      for (int t = 0; t < 4; ++t)
        acc[t] = __builtin_amdgcn_mfma_f32_16x16x32_bf16(
            af[i], *(const bf16x8*)(wb + (size_t)(t * 16) * K), acc[t], 0, 0, 0);
    }
    float bv[4], av[4];
#pragma unroll
    for (int t = 0; t < 4; ++t) {
      bv[t] = b2f(bias[h * 64 + t * 16 + l15]);
      av[t] = b2f(attn[h * 64 + t * 16 + l15]);
    }
    float part[4];
#pragma unroll
    for (int r = 0; r < 4; ++r) {
      float p = 0.0f;
#pragma unroll
      for (int t = 0; t < 4; ++t) {
        float v = acc[t][r] + bv[t] + sb2f(gv1[r][h][t]) + sb2f(gv2[r][h][t]);
        v = leaky(v);
        p += v * av[t];
        fs[t][r] += v;
      }
      part[r] = p;
    }
#pragma unroll
    for (int o = 1; o < 16; o <<= 1)
#pragma unroll
      for (int r = 0; r < 4; ++r) part[r] += __shfl_xor(part[r], o, 64);
    if (l15 == 0) {
#pragma unroll
      for (int r = 0; r < 4; ++r)
        if (okr[r]) lg4[(size_t)mcs[r] * 4 + h] = part[r];
    }
  }
  if (fout) {
#pragma unroll
    for (int t = 0; t < 4; ++t) {
      int col = t * 16 + l15;
#pragma unroll
      for (int r = 0; r < 4; ++r)
        if (okr[r]) fout[(size_t)(m0 + q * 4 + r) * 64 + col] = f2b(fs[t][r]);
    }
  }
}

// ---- per-head fused combine (P2 line graph, element-order), SWIZZLED G1/G2 [*,64] ----
__global__ __launch_bounds__(256)
void k_mcomb(const void* __restrict__ A, const void* __restrict__ Ac, int mode, int K,
             const bf16* __restrict__ W, const bf16* __restrict__ bias,
             const bf16* __restrict__ attn,
             const bf16* __restrict__ G1, const bf16* __restrict__ G2, int gstr,
             const int* __restrict__ gi, const int* __restrict__ gj,
             const int* __restrict__ posw,
             float* __restrict__ lg, int M, const int* __restrict__ flagp) {
  int tid = threadIdx.x;
  int w = tid >> 6, lane = tid & 63, l15 = lane & 15, q = lane >> 4;
  int f = (mode == 2) ? *flagp : mode;
  if (Ac && f) { A = Ac; f = 0; }
  int m0 = blockIdx.x * 64 + w * 16;
  int mA = m0 + l15; if (mA > M - 1) mA = M - 1;
  const char* rowA = (const char*)A + (size_t)mA * K * (f ? 4 : 2);
  int mcs[4], pIdx[4]; bool okr[4];
#pragma unroll
  for (int r = 0; r < 4; ++r) {
    int m = m0 + q * 4 + r;
    okr[r] = m < M; mcs[r] = okr[r] ? m : M - 1;
    pIdx[r] = posw ? posw[mcs[r]] : mcs[r];
  }
  s16x4 gv1[4], gv2[4];
#pragma unroll
  for (int r = 0; r < 4; ++r) {
    gv1[r] = ((const s16x4*)(G1 + (size_t)gi[mcs[r]] * gstr))[l15];
    gv2[r] = ((const s16x4*)(G2 + (size_t)gj[mcs[r]] * gstr))[l15];
  }
  f32x4 acc[4] = {{0,0,0,0},{0,0,0,0},{0,0,0,0},{0,0,0,0}};
  for (int k = q * 8; k < K; k += 32) {
    bf16x8 a = ldA8(rowA, k, f);
    const bf16* wb = W + (size_t)l15 * K + k;
#pragma unroll
    for (int t = 0; t < 4; ++t)
      acc[t] = __builtin_amdgcn_mfma_f32_16x16x32_bf16(
          a, *(const bf16x8*)(wb + (size_t)(t * 16) * K), acc[t], 0, 0, 0);
  }
  float attv[4], bsv[4];
#pragma unroll
  for (int t = 0; t < 4; ++t) { attv[t] = b2f(attn[t*16+l15]); bsv[t] = b2f(bias[t*16+l15]); }
  float part[4];
#pragma unroll
  for (int r = 0; r < 4; ++r) {
    float p = 0.0f;
#pragma unroll
    for (int t = 0; t < 4; ++t) {
      float v = acc[t][r] + bsv[t] + sb2f(gv1[r][t]) + sb2f(gv2[r][t]);
      p += leaky(v) * attv[t];
    }
    part[r] = p;
  }
#pragma unroll
  for (int o = 1; o < 16; o <<= 1)
#pragma unroll
    for (int r = 0; r < 4; ++r) part[r] += __shfl_xor(part[r], o, 64);
  if (l15 == 0) {
#pragma unroll
    for (int r = 0; r < 4; ++r)
      if (okr[r]) lg[pIdx[r]] = part[r];
  }
}

// ---------------- fused per-row CSR softmax (normalizes in place) ----------------
__global__ __launch_bounds__(256)
void k_smax4_csr(float* __restrict__ lg, const int* __restrict__ rp, int n) {
  int tid = blockIdx.x * 256 + threadIdx.x;
  int row = tid >> 2, h = tid & 3;
  if (row >= n) return;
  int b = rp[row], e = rp[row + 1];
  float m = -INFINITY;
  for (int j = b; j < e; ++j) m = fmaxf(m, lg[(size_t)j * 4 + h]);
  float s = 0.0f;
  for (int j = b; j < e; ++j) {
    float ex = expf(lg[(size_t)j * 4 + h] - m);
    lg[(size_t)j * 4 + h] = ex;
    s += ex;
  }
  float inv = 1.0f / s;
  for (int j = b; j < e; ++j) lg[(size_t)j * 4 + h] *= inv;
}
__global__ __launch_bounds__(256)
void k_smax1_csr(float* __restrict__ lg, const int* __restrict__ rp, int n) {
  int row = blockIdx.x * 256 + threadIdx.x;
  if (row >= n) return;
  int b = rp[row], e = rp[row + 1];
  float m = -INFINITY;
  for (int j = b; j < e; ++j) m = fmaxf(m, lg[j]);
  float s = 0.0f;
  for (int j = b; j < e; ++j) { float ex = expf(lg[j] - m); lg[j] = ex; s += ex; }
  float inv = 1.0f / s;
  for (int j = b; j < e; ++j) lg[j] *= inv;
}

// ---- P1 epilogue ----
__global__ __launch_bounds__(256)
void k_ghnode(const bf16* __restrict__ H, const float* __restrict__ lg4c,
              const int* __restrict__ rp, const int* __restrict__ srcv,
              bf16* __restrict__ hnode, int N) {
  int d = threadIdx.x, h = threadIdx.y;
  int n = blockIdx.x;
  int b = rp[n], e = rp[n + 1];
  float s = 0.0f;
  for (int j = b; j < e; ++j)
    s += b2f(H[(size_t)srcv[j] * 256 + h * 64 + d]) * lg4c[(size_t)j * 4 + h];
  float v = leaky(s);
  __shared__ float sh[4][64];
  if (h > 0) sh[h][d] = v;
  __syncthreads();
  if (h == 0)
    hnode[(size_t)n * 64 + d] = f2b(v + sh[1][d] + sh[2][d] + sh[3][d]);
}

// ---- P2 epilogue: normalized lgE in CSR order, lsv = CSR-slot gather index ----
__global__ void k_gout2(const bf16* __restrict__ M1, const float* __restrict__ lgE,
                        const int* __restrict__ rp, const int* __restrict__ lsv,
                        float* __restrict__ out, int E, int first) {
  int d = threadIdx.x;
  int t = blockIdx.x * 4 + threadIdx.y;
  if (t >= E) return;
  int b = rp[t], e = rp[t + 1];
  float s = 0.0f;
  for (int j = b; j < e; ++j)
    s += b2f(M1[(size_t)lsv[j] * 64 + d]) * lgE[j];
  float val = leaky(s);
  if (first) out[(size_t)t * 64 + d] = val;
  else       out[(size_t)t * 64 + d] += val;
}

// ---- P3 epilogue: logits CSR-ordered -> a via posN[t] ----
__global__ void k_gout3(const bf16* __restrict__ M2, const float* __restrict__ lg4n,
                        const int* __restrict__ posN,
                        const int* __restrict__ rp, const int* __restrict__ lsv,
                        float* __restrict__ out, int E, int h) {
  int d = threadIdx.x;
  int t = blockIdx.x * 4 + threadIdx.y;
  if (t >= E) return;
  int b = rp[t], e = rp[t + 1];
  float s = 0.0f;
  for (int j = b; j < e; ++j) s += b2f(M2[(size_t)lsv[j] * 64 + d]);
  float a = lg4n[(size_t)posN[t] * 4 + h];
  out[(size_t)t * 64 + d] += leaky(a * s);
}

// ---- P3 pre: neC[j] = hnode[srcv[j]] + hnode[dstv[j]]  (CSR space) ----
__global__ void k_addpairC(const bf16* __restrict__ hn, const int* __restrict__ sv,
                           const int* __restrict__ dv, bf16* __restrict__ ne, int E) {
  int d = threadIdx.x;
  int j = blockIdx.x * 4 + threadIdx.y;
  if (j >= E) return;
  ne[(size_t)j * 64 + d] =
      f2b(b2f(hn[(size_t)sv[j] * 64 + d]) + b2f(hn[(size_t)dv[j] * 64 + d]));
}

__global__ void k_cast(void* __restrict__ out, const float* __restrict__ a, size_t n,
                       const int* __restrict__ flagp) {
  int f = *flagp;
  size_t i = (size_t)blockIdx.x * blockDim.x + threadIdx.x;
  size_t st = (size_t)gridDim.x * blockDim.x;
  for (; i < n; i += st) {
    if (f) ((float*)out)[i] = a[i];
    else   ((bf16*)out)[i] = f2b(a[i]);
  }
}

extern "C" void kernel_launch(void* const* d_in, const int* in_sizes, int n_in,
                              void* d_out, int out_size, void* d_ws, size_t ws_size,
                              hipStream_t stream) {
  const int* src  = (const int*)d_in[24];
  const int* dst  = (const int*)d_in[25];
  const int* lsrc = (const int*)d_in[26];
  const int* ldst = (const int*)d_in[27];

  const int N  = in_sizes[0] / 128;
  const int E  = in_sizes[24];
  const int EL = in_sizes[26];
  (void)n_in; (void)out_size; (void)ws_size;

  // ---- workspace (~162 MB) ----
  char* base = (char*)d_ws;
  size_t off = 0;
  auto alloc = [&](size_t bytes) -> char* {
    char* p = base + off;
    off = (off + bytes + 255) & ~(size_t)255;
    return p;
  };
  int* flag = (int*)alloc(256);
  size_t wofs[28]; size_t wtot = 0;
  for (int i = 3; i <= 23; ++i) { wofs[i] = wtot; wtot += (size_t)((in_sizes[i] + 127) & ~127); }
  bf16* WA = (bf16*)alloc(wtot * 2);

  int*   tmpi  = (int*)alloc((size_t)2 * E * 4);        // deg | cur
  int*   rpN   = (int*)alloc((size_t)(N + 1) * 4);
  int*   eidN  = (int*)alloc((size_t)E * 4);
  int*   srcv  = (int*)alloc((size_t)E * 4);            // src[eid] (CSR order)
  int*   dstv  = (int*)alloc((size_t)E * 4);            // dst[eid] (CSR order)
  int*   posN  = (int*)alloc((size_t)E * 4);            // edge -> CSR slot
  int*   rpE   = (int*)alloc((size_t)(E + 1) * 4);
  int*   eidEL = (int*)alloc((size_t)EL * 4);
  int*   lsv   = (int*)alloc((size_t)EL * 4);           // -> CSR-slot of lsrc (in place xlat)
  int*   lsvE  = (int*)alloc((size_t)EL * 4);           // posN[lsrc[el]] element order
  int*   ldvE  = (int*)alloc((size_t)EL * 4);           // posN[ldst[el]] element order
  int*   posE  = (int*)alloc((size_t)EL * 4);           // lg-edge -> CSR slot
  int*   bsum  = (int*)alloc(((size_t)((E > N ? E : N) + 4095) / 4096 + 8) * 4);
  bf16*  fedge = (bf16*)alloc((size_t)E * 64 * 2);      // CSR order, P1 -> P2/P3
  bf16*  hnode = (bf16*)alloc((size_t)N * 64 * 2);      // node order
  float* outacc= (float*)alloc((size_t)E * 64 * 4);     // bond order / alias ebC
  bf16*  aggB  = (bf16*)alloc((size_t)E * 64 * 2);      // P1 agg(node) / P2 aggx(CSR) / P3 ne(CSR)
  bf16*  SA    = (bf16*)alloc((size_t)N * 256 * 2 > (size_t)E * 64 * 2
                              ? (size_t)N * 256 * 2 : (size_t)E * 64 * 2);
  bf16*  SB    = (bf16*)alloc((size_t)N * 256 * 2 > (size_t)E * 64 * 2
                              ? (size_t)N * 256 * 2 : (size_t)E * 64 * 2);
  float* logE4 = (float*)alloc((size_t)E * 4 * 4);
  float* logh  = (float*)alloc((size_t)EL * 4);
  bf16*  nb    = (bf16*)alloc((size_t)N * 128 * 2);     // nfeats bf16 canonical

  bf16* ebC = (bf16*)outacc;      // efeats CSR-ordered bf16 (P1 only; outacc written in P2)
  bf16* xb  = (bf16*)d_out;       // xfeats bf16 canonical (f32 mode; else d_in[2] used)

  dim3 blk(256);
  const unsigned tN = (N + 63) / 64, tEg = (E + 63) / 64, tELg = (EL + 63) / 64;
  const unsigned gE4 = (E + 3) / 4;
  const unsigned cE = (E + 255) / 256, cEL = (EL + 255) / 256;
  const int nbN = (N + 4095) / 4096, nbE = (E + 4095) / 4096;

  // ---- dtype detect + weights + nfeats/xfeats canonicalization ----
  k_detect<<<dim3(1), blk, 0, stream>>>((const unsigned*)d_in[0], flag);
  WArgs wa;
  for (int i = 3; i <= 23; ++i) {
    wa.src[i - 3] = d_in[i];
    wa.beg[i - 3] = (int)wofs[i];
    wa.len[i - 3] = in_sizes[i];
  }
  wa.beg[21] = (int)wtot;
  k_cvt_all<<<dim3(512), blk, 0, stream>>>(wa, WA, (int)wtot, flag);
  k_cvt2<<<dim3(2048), blk, 0, stream>>>(
      (const float*)d_in[0], nb, (size_t)N * 128,
      (const float*)d_in[2], xb, (size_t)EL * 64, flag);

  // ---- CSR builds ----
  int* deg = tmpi; int* cur = tmpi + E;
  k_izero<<<dim3(1024), blk, 0, stream>>>(tmpi, 2 * E);
  k_hist<<<dim3(cE), blk, 0, stream>>>(dst, deg, E);
  k_scan_local<<<dim3(nbN), blk, 0, stream>>>(deg, rpN, bsum, N);
  k_scan_bsum<<<dim3(1), blk, 0, stream>>>(bsum, nbN);
  if (nbN > 1) k_scan_add<<<dim3(nbN - 1), blk, 0, stream>>>(rpN, bsum, N);
  k_slot<<<dim3(cE), blk, 0, stream>>>(dst, rpN, cur, eidN, src, srcv, dst, dstv, posN, E);
  // efeats -> CSR-ordered canonical copy
  k_cvtp<<<dim3(gE4), dim3(64, 4), 0, stream>>>(d_in[1], eidN, ebC, E, flag);
  k_izero<<<dim3(1024), blk, 0, stream>>>(tmpi, 2 * E);
  k_hist<<<dim3(cEL), blk, 0, stream>>>(ldst, deg, EL);
  k_scan_local<<<dim3(nbE), blk, 0, stream>>>(deg, rpE, bsum, E);
  k_scan_bsum<<<dim3(1), blk, 0, stream>>>(bsum, nbE);
  if (nbE > 1) k_scan_add<<<dim3(nbE - 1), blk, 0, stream>>>(rpE, bsum, E);
  k_slot<<<dim3(cEL), blk, 0, stream>>>(ldst, rpE, cur, eidEL, lsrc, lsv, nullptr, nullptr,
                                        posE, EL);
  k_xlat<<<dim3(cEL), blk, 0, stream>>>(lsrc, ldst, posN, lsvE, ldvE, lsv, EL);

  // ================= Phase 1: EGAT =================
  k_gmean<<<dim3((N + 1) / 2), dim3(128, 2), 0, stream>>>(ebC, nullptr, 0, rpN, nullptr,
                                                          nullptr, aggB, N, 128, flag);
  k_mgemm2<<<dim3(tN, 4), blk, 0, stream>>>(d_in[0], nb, 2, 128, WA + wofs[3], WA + wofs[4],
                                            8192, SA, SB, 256, N, flag);
  k_mcomb4C<4><<<dim3(tEg), blk, 0, stream>>>(ebC, WA + wofs[5], 8192,
      WA + wofs[9], WA + wofs[8], SA, SB, 256, srcv, dstv, logE4, fedge, E);
  k_smax4_csr<<<dim3((N * 4 + 255) / 256), blk, 0, stream>>>(logE4, rpN, N);
  k_mgemm<<<dim3(tN, 4), blk, 0, stream>>>(d_in[0], nb, 2, 128, aggB, 0, 256,
      WA + wofs[6], 16384, WA + wofs[7], SA, 256, N, flag);
  k_ghnode<<<dim3(N), dim3(64, 4), 0, stream>>>(SA, logE4, rpN, srcv, hnode, N);

  // ================= Phase 2: line-graph branch =================
  k_gmean<<<dim3(gE4), dim3(64, 4), 0, stream>>>(d_in[2], xb, 2, rpE, eidEL, posN,
                                                 aggB, E, 64, flag);
  for (int h = 0; h < 4; ++h) {
    k_mgemm2<<<dim3(tEg), blk, 0, stream>>>(fedge, nullptr, 0, 64,
        WA + wofs[10] + h * 4096, WA + wofs[11] + h * 4096, 0, SA, SB, 64, E, flag);
    k_mcomb<<<dim3(tELg), blk, 0, stream>>>(d_in[2], xb, 2, 64,
        WA + wofs[12] + h * 4096, WA + wofs[16] + h * 64, WA + wofs[15] + h * 64,
        SA, SB, 64, lsvE, ldvE, posE, logh, EL, flag);
    k_smax1_csr<<<dim3((E + 255) / 256), blk, 0, stream>>>(logh, rpE, E);
    k_mgemm<<<dim3(tEg, 1), blk, 0, stream>>>(fedge, nullptr, 0, 64, aggB, 0, 128,
        WA + wofs[13] + (size_t)h * 8192, 0, WA + wofs[14] + h * 64,
        SA, 64, E, flag);
    k_gout2<<<dim3(gE4), dim3(64, 4), 0, stream>>>(SA, logh, rpE, lsv,
                                                   outacc, E, h == 0 ? 1 : 0);
  }

  // ================= Phase 3: graph branch =================
  k_mgemm2<<<dim3(tN, 4), blk, 0, stream>>>(hnode, nullptr, 0, 64, WA + wofs[17],
                                            WA + wofs[18], 4096, SA, SB, 256, N, flag);
  k_mcomb4C<2><<<dim3(tEg), blk, 0, stream>>>(fedge, WA + wofs[19], 4096,
      WA + wofs[23], WA + wofs[22], SA, SB, 256, srcv, dstv, logE4, nullptr, E);
  k_smax4_csr<<<dim3((N * 4 + 255) / 256), blk, 0, stream>>>(logE4, rpN, N);
  k_addpairC<<<dim3(gE4), dim3(64, 4), 0, stream>>>(hnode, srcv, dstv, aggB, E);
  for (int h = 0; h < 4; ++h) {
    k_mgemm<<<dim3(tEg, 1), blk, 0, stream>>>(aggB, nullptr, 0, 64, fedge, 0, 128,
        WA + wofs[20] + (size_t)h * 8192, 0, WA + wofs[21] + h * 64,
        SA, 64, E, flag);
    k_gout3<<<dim3(gE4), dim3(64, 4), 0, stream>>>(SA, logE4, posN, rpE, lsv,
                                                   outacc, E, h);
  }

  k_cast<<<dim3(2048), blk, 0, stream>>>(d_out, outacc, (size_t)E * 64, flag);
}

// Round 6
// 1837.871 us; speedup vs baseline: 1.0140x; 1.0130x over previous
//
#include <hip/hip_runtime.h>
#include <hip/hip_bf16.h>
#include <math.h>

typedef __hip_bfloat16 bf16;
typedef short bf16x8 __attribute__((ext_vector_type(8)));
typedef short s16x4 __attribute__((ext_vector_type(4)));
typedef float f32x4 __attribute__((ext_vector_type(4)));

__device__ __forceinline__ float b2f(bf16 x) { return __bfloat162float(x); }
__device__ __forceinline__ bf16  f2b(float x) { return __float2bfloat16(x); }
__device__ __forceinline__ float leaky(float x) { return x >= 0.0f ? x : 0.01f * x; }
__device__ __forceinline__ float sb2f(short s) {
  return __uint_as_float(((unsigned)(unsigned short)s) << 16);
}
__device__ __forceinline__ short f2bs(float x) {
  unsigned u = __float_as_uint(x);
  u += 0x7FFFu + ((u >> 16) & 1u);
  return (short)(u >> 16);
}
__device__ __forceinline__ float ldF(const void* p, size_t i, int f) {
  return f ? ((const float*)p)[i] : b2f(((const bf16*)p)[i]);
}
__device__ __forceinline__ bf16x8 ldA8(const char* row, int k, int f) {
  if (!f) return *(const bf16x8*)(row + (size_t)k * 2);
  const float4* p = (const float4*)(row + (size_t)k * 4);
  float4 a = p[0], b = p[1];
  bf16x8 r;
  r[0] = f2bs(a.x); r[1] = f2bs(a.y); r[2] = f2bs(a.z); r[3] = f2bs(a.w);
  r[4] = f2bs(b.x); r[5] = f2bs(b.y); r[6] = f2bs(b.z); r[7] = f2bs(b.w);
  return r;
}

// ---- dtype detector ----
__global__ void k_detect(const unsigned* __restrict__ w, int* __restrict__ flag) {
  __shared__ int cnt[256];
  unsigned x = w[threadIdx.x];
  unsigned ex = (x >> 7) & 0xFFu;
  cnt[threadIdx.x] = (ex >= 96u && ex <= 144u) ? 1 : 0;
  __syncthreads();
  for (int s = 128; s > 0; s >>= 1) {
    if (threadIdx.x < s) cnt[threadIdx.x] += cnt[threadIdx.x + s];
    __syncthreads();
  }
  if (threadIdx.x == 0) *flag = (cnt[0] < 128) ? 1 : 0;  // 1 = f32 inputs
}

// ---- all-weights canonicalization ----
struct WArgs { const void* src[21]; int beg[22]; int len[21]; };
__global__ void k_cvt_all(WArgs wa, bf16* __restrict__ dst, int total,
                          const int* __restrict__ flagp) {
  int f = *flagp;
  for (int i = blockIdx.x * 256 + threadIdx.x; i < total; i += gridDim.x * 256) {
    int t = 0;
    while (t < 20 && i >= wa.beg[t + 1]) ++t;
    int loc = i - wa.beg[t];
    bf16 v = f2b(0.0f);
    if (loc < wa.len[t])
      v = f ? f2b(((const float*)wa.src[t])[loc]) : ((const bf16*)wa.src[t])[loc];
    dst[i] = v;
  }
}

// ---- nfeats/xfeats f32->bf16 canonicalization (no-op in bf16 mode) ----
__global__ void k_cvt2(const float* __restrict__ a, bf16* __restrict__ da, size_t na,
                       const float* __restrict__ c, bf16* __restrict__ dc, size_t nc,
                       const int* __restrict__ flagp) {
  if (!*flagp) return;
  size_t tot = (na + nc) >> 2;
  for (size_t i = (size_t)blockIdx.x * 256 + threadIdx.x; i < tot;
       i += (size_t)gridDim.x * 256) {
    size_t j = i << 2;
    const float* s; bf16* d; size_t loc;
    if (j < na) { s = a; d = da; loc = j; }
    else        { s = c; d = dc; loc = j - na; }
    float4 v = *(const float4*)(s + loc);
    s16x4 o; o[0] = f2bs(v.x); o[1] = f2bs(v.y); o[2] = f2bs(v.z); o[3] = f2bs(v.w);
    *(s16x4*)(d + loc) = o;
  }
}

__global__ void k_izero(int* __restrict__ p, int n) {
  int i = blockIdx.x * 256 + threadIdx.x;
  for (; i < n; i += gridDim.x * 256) p[i] = 0;
}

// ---------------- CSR build ----------------
__global__ void k_hist(const int* __restrict__ seg, int* __restrict__ deg, int n) {
  int i = blockIdx.x * 256 + threadIdx.x;
  if (i < n) atomicAdd(&deg[seg[i]], 1);
}

__global__ __launch_bounds__(256)
void k_scan_local(const int* __restrict__ deg, int* __restrict__ rp,
                  int* __restrict__ bsum, int n) {
  __shared__ int sh[256];
  int tid = threadIdx.x;
  int base = blockIdx.x * 4096 + tid * 16;
  int v[16]; int s = 0;
#pragma unroll
  for (int j = 0; j < 16; ++j) { v[j] = (base + j < n) ? deg[base + j] : 0; s += v[j]; }
  sh[tid] = s;
  __syncthreads();
  for (int o = 1; o < 256; o <<= 1) {
    int t = (tid >= o) ? sh[tid - o] : 0;
    __syncthreads();
    sh[tid] += t;
    __syncthreads();
  }
  int run = sh[tid] - s;
#pragma unroll
  for (int j = 0; j < 16; ++j) {
    run += v[j];
    if (base + j < n) rp[base + j + 1] = run;
  }
  if (tid == 255) bsum[blockIdx.x] = sh[255];
  if (blockIdx.x == 0 && tid == 0) rp[0] = 0;
}
__global__ __launch_bounds__(256)
void k_scan_bsum(int* __restrict__ bsum, int nb) {
  __shared__ int sh[256];
  __shared__ int carry;
  int tid = threadIdx.x;
  if (tid == 0) carry = 0;
  __syncthreads();
  for (int base = 0; base < nb; base += 256) {
    int i = base + tid;
    int v = (i < nb) ? bsum[i] : 0;
    sh[tid] = v;
    __syncthreads();
    for (int o = 1; o < 256; o <<= 1) {
      int t = (tid >= o) ? sh[tid - o] : 0;
      __syncthreads();
      sh[tid] += t;
      __syncthreads();
    }
    if (i < nb) bsum[i] = carry + sh[tid] - v;
    int tot = sh[255];
    __syncthreads();
    if (tid == 0) carry += tot;
    __syncthreads();
  }
}
__global__ __launch_bounds__(256)
void k_scan_add(int* __restrict__ rp, const int* __restrict__ bsum, int n) {
  int b = blockIdx.x + 1;
  int ofs = bsum[b];
  int base = b * 4096 + threadIdx.x * 16;
#pragma unroll
  for (int j = 0; j < 16; ++j) {
    int idx = base + j + 1;
    if (idx <= n) rp[idx] += ofs;
  }
}

__global__ void k_slot(const int* __restrict__ seg, const int* __restrict__ rp,
                       int* __restrict__ cur, int* __restrict__ eid,
                       const int* __restrict__ aux1, int* __restrict__ av1,
                       int* __restrict__ pos, int n) {
  int i = blockIdx.x * 256 + threadIdx.x;
  if (i >= n) return;
  int t = seg[i];
  int p = atomicAdd(&cur[t], 1);
  int j = rp[t] + p;
  eid[j] = i;
  if (av1) av1[j] = aux1[i];
  if (pos) pos[i] = j;
}

// ---------------- gather-mean ----------------
__global__ void k_gmean(const void* __restrict__ X, const void* __restrict__ Xc, int mode,
                        const int* __restrict__ rp, const int* __restrict__ eid,
                        bf16* __restrict__ out, int n, int width,
                        const int* __restrict__ flagp) {
  int f = (mode == 2) ? *flagp : mode;
  if (Xc && f) { X = Xc; f = 0; }
  int d = threadIdx.x;
  int row = blockIdx.x * blockDim.y + threadIdx.y;
  if (row >= n) return;
  int b = rp[row], e = rp[row + 1];
  float s = 0.0f;
  for (int j = b; j < e; ++j) s += ldF(X, (size_t)eid[j] * width + d, f);
  out[(size_t)row * width + d] = f2b(s / fmaxf((float)(e - b), 1.0f));
}

// =================== MFMA GEMM: C[.,colofs+0..63] = A @ Wh^T (+bias), unswizzled ====
__global__ __launch_bounds__(256)
void k_mgemm(const void* __restrict__ A0, const void* __restrict__ A0c, int m0mode, int K0,
             const void* __restrict__ A1, int m1mode, int Ktot,
             const bf16* __restrict__ W, int whs, const bf16* __restrict__ bias,
             bf16* __restrict__ C, int cs, int M,
             const int* __restrict__ flagp) {
  int tid = threadIdx.x;
  int w = tid >> 6, lane = tid & 63, l15 = lane & 15, q = lane >> 4;
  int h = blockIdx.y;
  int fl = *flagp;
  int f0 = (m0mode == 2) ? fl : m0mode;
  if (A0c && f0) { A0 = A0c; f0 = 0; }
  int f1 = (m1mode == 2) ? fl : m1mode;
  const bf16* Wh = W + (size_t)h * whs;
  int colofs = h * 64;
  int m0 = blockIdx.x * 64 + w * 16;
  int mA = m0 + l15; if (mA > M - 1) mA = M - 1;
  const char* rowA0 = (const char*)A0 + (size_t)mA * K0 * (f0 ? 4 : 2);
  const char* rowA1 = A1 ? (const char*)A1 + (size_t)mA * (Ktot - K0) * (f1 ? 4 : 2) : nullptr;

  f32x4 acc[4] = {{0,0,0,0},{0,0,0,0},{0,0,0,0},{0,0,0,0}};
  for (int k = q * 8; k < Ktot; k += 32) {
    bf16x8 a;
    if (k < K0) a = ldA8(rowA0, k, f0);
    else        a = ldA8(rowA1, k - K0, f1);
    const bf16* wb = Wh + (size_t)l15 * Ktot + k;
#pragma unroll
    for (int t = 0; t < 4; ++t)
      acc[t] = __builtin_amdgcn_mfma_f32_16x16x32_bf16(
          a, *(const bf16x8*)(wb + (size_t)(t * 16) * Ktot), acc[t], 0, 0, 0);
  }
#pragma unroll
  for (int t = 0; t < 4; ++t) {
    int col = t * 16 + l15;
    float bv = bias ? b2f(bias[colofs + col]) : 0.0f;
#pragma unroll
    for (int r = 0; r < 4; ++r) {
      int m = m0 + q * 4 + r;
      if (m < M) C[(size_t)m * cs + colofs + col] = f2b(acc[t][r] + bv);
    }
  }
}

// ---- dual-output GEMM, h-contiguous swizzle: elem(h,col=t*16+l15) at l15*4*HB+hy*4+t ----
__global__ __launch_bounds__(256)
void k_mgemm2sw(const void* __restrict__ A, const void* __restrict__ Ac, int mode, int K,
                const bf16* __restrict__ W1, const bf16* __restrict__ W2, int whs,
                int h0, int HB, bf16* __restrict__ C1, bf16* __restrict__ C2, int M,
                const int* __restrict__ flagp) {
  int tid = threadIdx.x;
  int w = tid >> 6, lane = tid & 63, l15 = lane & 15, q = lane >> 4;
  int hy = blockIdx.y;
  int h = h0 + hy;
  int f = (mode == 2) ? *flagp : mode;
  if (Ac && f) { A = Ac; f = 0; }
  const bf16* W1h = W1 + (size_t)h * whs;
  const bf16* W2h = W2 + (size_t)h * whs;
  int cs = HB * 64;
  int m0 = blockIdx.x * 64 + w * 16;
  int mA = m0 + l15; if (mA > M - 1) mA = M - 1;
  const char* rowA = (const char*)A + (size_t)mA * K * (f ? 4 : 2);

  f32x4 a1[4] = {{0,0,0,0},{0,0,0,0},{0,0,0,0},{0,0,0,0}};
  f32x4 a2[4] = {{0,0,0,0},{0,0,0,0},{0,0,0,0},{0,0,0,0}};
  for (int k = q * 8; k < K; k += 32) {
    bf16x8 a = ldA8(rowA, k, f);
    const bf16* w1 = W1h + (size_t)l15 * K + k;
    const bf16* w2 = W2h + (size_t)l15 * K + k;
#pragma unroll
    for (int t = 0; t < 4; ++t) {
      a1[t] = __builtin_amdgcn_mfma_f32_16x16x32_bf16(
          a, *(const bf16x8*)(w1 + (size_t)(t * 16) * K), a1[t], 0, 0, 0);
      a2[t] = __builtin_amdgcn_mfma_f32_16x16x32_bf16(
          a, *(const bf16x8*)(w2 + (size_t)(t * 16) * K), a2[t], 0, 0, 0);
    }
  }
  int ofs = l15 * 4 * HB + hy * 4;
#pragma unroll
  for (int r = 0; r < 4; ++r) {
    int m = m0 + q * 4 + r;
    if (m < M) {
      s16x4 o1, o2;
#pragma unroll
      for (int t = 0; t < 4; ++t) { o1[t] = f2bs(a1[t][r]); o2[t] = f2bs(a2[t][r]); }
      *(s16x4*)(C1 + (size_t)m * cs + ofs) = o1;
      *(s16x4*)(C2 + (size_t)m * cs + ofs) = o2;
    }
  }
}

// ====== all-heads fused combine (P1): 2x16B gathers per (r,table) ======
template<int NK>
__global__ __launch_bounds__(256)
void k_mcomb4sw(const void* __restrict__ A, const void* __restrict__ Ac, int mode,
                const bf16* __restrict__ W, int whs,
                const bf16* __restrict__ bias, const bf16* __restrict__ attn,
                const bf16* __restrict__ G1, const bf16* __restrict__ G2,
                const int* __restrict__ gi, const int* __restrict__ gj,
                const int* __restrict__ posw,
                float* __restrict__ lg4, bf16* __restrict__ fout,
                int M, const int* __restrict__ flagp) {
  constexpr int K = NK * 32;
  int tid = threadIdx.x;
  int w = tid >> 6, lane = tid & 63, l15 = lane & 15, q = lane >> 4;
  int f = (mode == 2) ? *flagp : mode;
  if (Ac && f) { A = Ac; f = 0; }
  int m0 = blockIdx.x * 64 + w * 16;
  int mA = m0 + l15; if (mA > M - 1) mA = M - 1;
  const char* rowA = (const char*)A + (size_t)mA * K * (f ? 4 : 2);
  bf16x8 af[NK];
#pragma unroll
  for (int i = 0; i < NK; ++i) af[i] = ldA8(rowA, q * 8 + 32 * i, f);
  int pIdx[4]; bool okr[4];
  bf16x8 gv1[4][2], gv2[4][2];
#pragma unroll
  for (int r = 0; r < 4; ++r) {
    int m = m0 + q * 4 + r;
    okr[r] = m < M; int mc = okr[r] ? m : M - 1;
    pIdx[r] = posw ? posw[mc] : mc;
    const bf16* p1 = G1 + (size_t)gi[mc] * 256 + l15 * 16;
    const bf16* p2 = G2 + (size_t)gj[mc] * 256 + l15 * 16;
    gv1[r][0] = *(const bf16x8*)p1; gv1[r][1] = *(const bf16x8*)(p1 + 8);
    gv2[r][0] = *(const bf16x8*)p2; gv2[r][1] = *(const bf16x8*)(p2 + 8);
  }
  f32x4 fs[4] = {{0,0,0,0},{0,0,0,0},{0,0,0,0},{0,0,0,0}};
#pragma unroll
  for (int h = 0; h < 4; ++h) {
    const bf16* Wh = W + (size_t)h * whs;
    f32x4 acc[4] = {{0,0,0,0},{0,0,0,0},{0,0,0,0},{0,0,0,0}};
#pragma unroll
    for (int i = 0; i < NK; ++i) {
      const bf16* wb = Wh + (size_t)l15 * K + q * 8 + 32 * i;
#pragma unroll
      for (int t = 0; t < 4; ++t)
        acc[t] = __builtin_amdgcn_mfma_f32_16x16x32_bf16(
            af[i], *(const bf16x8*)(wb + (size_t)(t * 16) * K), acc[t], 0, 0, 0);
    }
    float bv[4], av[4];
#pragma unroll
    for (int t = 0; t < 4; ++t) {
      bv[t] = b2f(bias[h * 64 + t * 16 + l15]);
      av[t] = b2f(attn[h * 64 + t * 16 + l15]);
    }
    float part[4];
#pragma unroll
    for (int r = 0; r < 4; ++r) {
      float p = 0.0f;
#pragma unroll
      for (int t = 0; t < 4; ++t) {
        float v = acc[t][r] + bv[t] + sb2f(gv1[r][h >> 1][(h & 1) * 4 + t])
                                    + sb2f(gv2[r][h >> 1][(h & 1) * 4 + t]);
        v = leaky(v);
        p += v * av[t];
        fs[t][r] += v;
      }
      part[r] = p;
    }
#pragma unroll
    for (int o = 1; o < 16; o <<= 1)
#pragma unroll
      for (int r = 0; r < 4; ++r) part[r] += __shfl_xor(part[r], o, 64);
    if (l15 == 0) {
#pragma unroll
      for (int r = 0; r < 4; ++r)
        if (okr[r]) lg4[(size_t)pIdx[r] * 4 + h] = part[r];
    }
  }
  if (fout) {
#pragma unroll
    for (int t = 0; t < 4; ++t) {
      int col = t * 16 + l15;
#pragma unroll
      for (int r = 0; r < 4; ++r)
        if (okr[r]) fout[(size_t)(m0 + q * 4 + r) * 64 + col] = f2b(fs[t][r]);
    }
  }
}

// ====== 2-head fused combine (P2/P3): one 16B gather per (r,table) ======
template<int NK>
__global__ __launch_bounds__(256)
void k_mcomb2h(const void* __restrict__ A, const void* __restrict__ Ac, int mode,
               const bf16* __restrict__ W, int whs, int h0,
               const bf16* __restrict__ bias, const bf16* __restrict__ attn,
               const bf16* __restrict__ G1, const bf16* __restrict__ G2,
               const int* __restrict__ gi, const int* __restrict__ gj,
               const int* __restrict__ posw,
               float* __restrict__ lg4, int M, const int* __restrict__ flagp) {
  constexpr int K = NK * 32;
  int tid = threadIdx.x;
  int w = tid >> 6, lane = tid & 63, l15 = lane & 15, q = lane >> 4;
  int f = (mode == 2) ? *flagp : mode;
  if (Ac && f) { A = Ac; f = 0; }
  int m0 = blockIdx.x * 64 + w * 16;
  int mA = m0 + l15; if (mA > M - 1) mA = M - 1;
  const char* rowA = (const char*)A + (size_t)mA * K * (f ? 4 : 2);
  bf16x8 af[NK];
#pragma unroll
  for (int i = 0; i < NK; ++i) af[i] = ldA8(rowA, q * 8 + 32 * i, f);
  int pIdx[4]; bool okr[4];
  bf16x8 gv1[4], gv2[4];
#pragma unroll
  for (int r = 0; r < 4; ++r) {
    int m = m0 + q * 4 + r;
    okr[r] = m < M; int mc = okr[r] ? m : M - 1;
    pIdx[r] = posw ? posw[mc] : mc;
    gv1[r] = *(const bf16x8*)(G1 + (size_t)gi[mc] * 128 + l15 * 8);
    gv2[r] = *(const bf16x8*)(G2 + (size_t)gj[mc] * 128 + l15 * 8);
  }
#pragma unroll
  for (int hy = 0; hy < 2; ++hy) {
    int h = h0 + hy;
    const bf16* Wh = W + (size_t)h * whs;
    f32x4 acc[4] = {{0,0,0,0},{0,0,0,0},{0,0,0,0},{0,0,0,0}};
#pragma unroll
    for (int i = 0; i < NK; ++i) {
      const bf16* wb = Wh + (size_t)l15 * K + q * 8 + 32 * i;
#pragma unroll
      for (int t = 0; t < 4; ++t)
        acc[t] = __builtin_amdgcn_mfma_f32_16x16x32_bf16(
            af[i], *(const bf16x8*)(wb + (size_t)(t * 16) * K), acc[t], 0, 0, 0);
    }
    float bv[4], av[4];
#pragma unroll
    for (int t = 0; t < 4; ++t) {
      bv[t] = b2f(bias[h * 64 + t * 16 + l15]);
      av[t] = b2f(attn[h * 64 + t * 16 + l15]);
    }
    float part[4];
#pragma unroll
    for (int r = 0; r < 4; ++r) {
      float p = 0.0f;
#pragma unroll
      for (int t = 0; t < 4; ++t) {
        float v = acc[t][r] + bv[t] + sb2f(gv1[r][hy * 4 + t]) + sb2f(gv2[r][hy * 4 + t]);
        p += leaky(v) * av[t];
      }
      part[r] = p;
    }
#pragma unroll
    for (int o = 1; o < 16; o <<= 1)
#pragma unroll
      for (int r = 0; r < 4; ++r) part[r] += __shfl_xor(part[r], o, 64);
    if (l15 == 0) {
#pragma unroll
      for (int r = 0; r < 4; ++r)
        if (okr[r]) lg4[(size_t)pIdx[r] * 4 + h] = part[r];
    }
  }
}

// ---------------- fused per-row CSR softmax (normalizes in place) ----------------
__global__ __launch_bounds__(256)
void k_smax4_csr(float* __restrict__ lg, const int* __restrict__ rp, int n) {
  int tid = blockIdx.x * 256 + threadIdx.x;
  int row = tid >> 2, h = tid & 3;
  if (row >= n) return;
  int b = rp[row], e = rp[row + 1];
  float m = -INFINITY;
  for (int j = b; j < e; ++j) m = fmaxf(m, lg[(size_t)j * 4 + h]);
  float s = 0.0f;
  for (int j = b; j < e; ++j) {
    float ex = expf(lg[(size_t)j * 4 + h] - m);
    lg[(size_t)j * 4 + h] = ex;
    s += ex;
  }
  float inv = 1.0f / s;
  for (int j = b; j < e; ++j) lg[(size_t)j * 4 + h] *= inv;
}
__global__ __launch_bounds__(256)
void k_smax4_eid(float* __restrict__ lg, const int* __restrict__ rp,
                 const int* __restrict__ eid, int n) {
  int tid = blockIdx.x * 256 + threadIdx.x;
  int row = tid >> 2, h = tid & 3;
  if (row >= n) return;
  int b = rp[row], e = rp[row + 1];
  float m = -INFINITY;
  for (int j = b; j < e; ++j) m = fmaxf(m, lg[(size_t)eid[j] * 4 + h]);
  float s = 0.0f;
  for (int j = b; j < e; ++j) {
    float ex = expf(lg[(size_t)eid[j] * 4 + h] - m);
    lg[(size_t)eid[j] * 4 + h] = ex;
    s += ex;
  }
  float inv = 1.0f / s;
  for (int j = b; j < e; ++j) lg[(size_t)eid[j] * 4 + h] *= inv;
}

// ---- P1 epilogue: one node/block, head = wave ----
__global__ __launch_bounds__(256)
void k_ghnode(const bf16* __restrict__ H, const float* __restrict__ lg4c,
              const int* __restrict__ rp, const int* __restrict__ srcv,
              bf16* __restrict__ hnode, int N) {
  int d = threadIdx.x, h = threadIdx.y;
  int n = blockIdx.x;
  int b = rp[n], e = rp[n + 1];
  float s = 0.0f;
  for (int j = b; j < e; ++j)
    s += b2f(H[(size_t)srcv[j] * 256 + h * 64 + d]) * lg4c[(size_t)j * 4 + h];
  float v = leaky(s);
  __shared__ float sh[4][64];
  if (h > 0) sh[h][d] = v;
  __syncthreads();
  if (h == 0)
    hnode[(size_t)n * 64 + d] = f2b(v + sh[1][d] + sh[2][d] + sh[3][d]);
}

// ---- P2 epilogue: normalized lgE4 in CSR order (head h), lsv materialized ----
__global__ void k_gout2(const bf16* __restrict__ M1, const float* __restrict__ lgE4,
                        int h, const int* __restrict__ rp, const int* __restrict__ lsv,
                        float* __restrict__ out, int E, int first) {
  int d = threadIdx.x;
  int t = blockIdx.x * 4 + threadIdx.y;
  if (t >= E) return;
  int b = rp[t], e = rp[t + 1];
  float s = 0.0f;
  for (int j = b; j < e; ++j)
    s += b2f(M1[(size_t)lsv[j] * 64 + d]) * lgE4[(size_t)j * 4 + h];
  float val = leaky(s);
  if (first) out[(size_t)t * 64 + d] = val;
  else       out[(size_t)t * 64 + d] += val;
}

// ---- P3 epilogue: normalized a (edge-order [E,4]) ----
__global__ void k_gout3(const bf16* __restrict__ M2, const float* __restrict__ lg4n,
                        const int* __restrict__ rp, const int* __restrict__ lsv,
                        float* __restrict__ out, int E, int h) {
  int d = threadIdx.x;
  int t = blockIdx.x * 4 + threadIdx.y;
  if (t >= E) return;
  int b = rp[t], e = rp[t + 1];
  float s = 0.0f;
  for (int j = b; j < e; ++j) s += b2f(M2[(size_t)lsv[j] * 64 + d]);
  float a = lg4n[(size_t)t * 4 + h];
  out[(size_t)t * 64 + d] += leaky(a * s);
}

// ---- P3 pre: ne[e] = hnode[src[e]] + hnode[dst[e]] ----
__global__ void k_addpair(const bf16* __restrict__ hn, const int* __restrict__ src,
                          const int* __restrict__ dst, bf16* __restrict__ ne, int E) {
  int d = threadIdx.x;
  int e = blockIdx.x * 4 + threadIdx.y;
  if (e >= E) return;
  ne[(size_t)e * 64 + d] =
      f2b(b2f(hn[(size_t)src[e] * 64 + d]) + b2f(hn[(size_t)dst[e] * 64 + d]));
}

__global__ void k_cast(void* __restrict__ out, const float* __restrict__ a, size_t n,
                       const int* __restrict__ flagp) {
  int f = *flagp;
  size_t i = (size_t)blockIdx.x * blockDim.x + threadIdx.x;
  size_t st = (size_t)gridDim.x * blockDim.x;
  for (; i < n; i += st) {
    if (f) ((float*)out)[i] = a[i];
    else   ((bf16*)out)[i] = f2b(a[i]);
  }
}

extern "C" void kernel_launch(void* const* d_in, const int* in_sizes, int n_in,
                              void* d_out, int out_size, void* d_ws, size_t ws_size,
                              hipStream_t stream) {
  const int* src  = (const int*)d_in[24];
  const int* dst  = (const int*)d_in[25];
  const int* lsrc = (const int*)d_in[26];
  const int* ldst = (const int*)d_in[27];

  const int N  = in_sizes[0] / 128;
  const int E  = in_sizes[24];
  const int EL = in_sizes[26];
  (void)n_in; (void)out_size; (void)ws_size;

  // ---- workspace (~149 MB) ----
  char* base = (char*)d_ws;
  size_t off = 0;
  auto alloc = [&](size_t bytes) -> char* {
    char* p = base + off;
    off = (off + bytes + 255) & ~(size_t)255;
    return p;
  };
  int* flag = (int*)alloc(256);
  size_t wofs[28]; size_t wtot = 0;
  for (int i = 3; i <= 23; ++i) { wofs[i] = wtot; wtot += (size_t)((in_sizes[i] + 127) & ~127); }
  bf16* WA = (bf16*)alloc(wtot * 2);

  int*   tmpi  = (int*)alloc((size_t)2 * E * 4);        // deg | cur
  int*   rpN   = (int*)alloc((size_t)(N + 1) * 4);
  int*   eidN  = (int*)alloc((size_t)E * 4);
  int*   srcv  = (int*)alloc((size_t)E * 4);            // src[eid] (CSR order)
  int*   posN  = (int*)alloc((size_t)E * 4);            // edge -> CSR slot
  int*   rpE   = (int*)alloc((size_t)(E + 1) * 4);
  int*   eidEL = (int*)alloc((size_t)EL * 4);
  int*   lsv   = (int*)alloc((size_t)EL * 4);           // lsrc[eid] (CSR order)
  int*   posE  = (int*)alloc((size_t)EL * 4);           // lg-edge -> CSR slot
  int*   bsum  = (int*)alloc(((size_t)((E > N ? E : N) + 4095) / 4096 + 8) * 4);
  bf16*  fedge = (bf16*)alloc((size_t)E * 64 * 2);      // P1 -> P2/P3 (element order)
  bf16*  hnode = (bf16*)alloc((size_t)N * 64 * 2);
  float* outacc= (float*)alloc((size_t)E * 64 * 4);     // accumulator; aliased as table SBo
  bf16*  aggB  = (bf16*)alloc((size_t)E * 64 * 2);      // P1 agg[N,128]/P2 aggx/P3 ne
  size_t saElems = (size_t)E * 128 > (size_t)N * 256 ? (size_t)E * 128 : (size_t)N * 256;
  bf16*  SA    = (bf16*)alloc(saElems * 2);             // 38.4 MB table region
  float* logE4 = (float*)alloc((size_t)E * 4 * 4);
  float* logEL4= (float*)alloc((size_t)EL * 4 * 4);
  bf16*  nb    = (bf16*)alloc((size_t)N * 128 * 2);     // nfeats bf16 canonical

  bf16* SBo = (bf16*)outacc;      // second table region (free until P2 phase B)
  bf16* xb  = (bf16*)d_out;       // xfeats bf16 canonical (scratch until final cast)

  dim3 blk(256);
  const unsigned tN = (N + 63) / 64, tEg = (E + 63) / 64, tELg = (EL + 63) / 64;
  const unsigned gE4 = (E + 3) / 4;
  const unsigned cE = (E + 255) / 256, cEL = (EL + 255) / 256;
  const int nbN = (N + 4095) / 4096, nbE = (E + 4095) / 4096;

  // ---- dtype detect + weights + nfeats/xfeats canonicalization ----
  k_detect<<<dim3(1), blk, 0, stream>>>((const unsigned*)d_in[0], flag);
  WArgs wa;
  for (int i = 3; i <= 23; ++i) {
    wa.src[i - 3] = d_in[i];
    wa.beg[i - 3] = (int)wofs[i];
    wa.len[i - 3] = in_sizes[i];
  }
  wa.beg[21] = (int)wtot;
  k_cvt_all<<<dim3(512), blk, 0, stream>>>(wa, WA, (int)wtot, flag);
  k_cvt2<<<dim3(2048), blk, 0, stream>>>(
      (const float*)d_in[0], nb, (size_t)N * 128,
      (const float*)d_in[2], xb, (size_t)EL * 64, flag);

  // ---- CSR builds ----
  int* deg = tmpi; int* cur = tmpi + E;
  k_izero<<<dim3(1024), blk, 0, stream>>>(tmpi, 2 * E);
  k_hist<<<dim3(cE), blk, 0, stream>>>(dst, deg, E);
  k_scan_local<<<dim3(nbN), blk, 0, stream>>>(deg, rpN, bsum, N);
  k_scan_bsum<<<dim3(1), blk, 0, stream>>>(bsum, nbN);
  if (nbN > 1) k_scan_add<<<dim3(nbN - 1), blk, 0, stream>>>(rpN, bsum, N);
  k_slot<<<dim3(cE), blk, 0, stream>>>(dst, rpN, cur, eidN, src, srcv, posN, E);
  k_izero<<<dim3(1024), blk, 0, stream>>>(tmpi, 2 * E);
  k_hist<<<dim3(cEL), blk, 0, stream>>>(ldst, deg, EL);
  k_scan_local<<<dim3(nbE), blk, 0, stream>>>(deg, rpE, bsum, E);
  k_scan_bsum<<<dim3(1), blk, 0, stream>>>(bsum, nbE);
  if (nbE > 1) k_scan_add<<<dim3(nbE - 1), blk, 0, stream>>>(rpE, bsum, E);
  k_slot<<<dim3(cEL), blk, 0, stream>>>(ldst, rpE, cur, eidEL, lsrc, lsv, posE, EL);

  // ================= Phase 1: EGAT =================
  k_gmean<<<dim3((N + 1) / 2), dim3(128, 2), 0, stream>>>(d_in[1], nullptr, 2, rpN, eidN,
                                                          aggB, N, 128, flag);
  // tables [N,256] h-contig swizzle: SA = nfeats@Wni, SBo = nfeats@Wnj
  k_mgemm2sw<<<dim3(tN, 4), blk, 0, stream>>>(d_in[0], nb, 2, 128,
      WA + wofs[3], WA + wofs[4], 8192, 0, 4, SA, SBo, N, flag);
  k_mcomb4sw<4><<<dim3(tEg), blk, 0, stream>>>(d_in[1], nullptr, 2, WA + wofs[5], 8192,
      WA + wofs[9], WA + wofs[8], SA, SBo, src, dst, posN, logE4, fedge, E, flag);
  k_smax4_csr<<<dim3((N * 4 + 255) / 256), blk, 0, stream>>>(logE4, rpN, N);
  k_mgemm<<<dim3(tN, 4), blk, 0, stream>>>(d_in[0], nb, 2, 128, aggB, 0, 256,
      WA + wofs[6], 16384, WA + wofs[7], SA, 256, N, flag);
  k_ghnode<<<dim3(N), dim3(64, 4), 0, stream>>>(SA, logE4, rpN, srcv, hnode, N);

  // ================= Phase 2: line-graph branch =================
  k_gmean<<<dim3(gE4), dim3(64, 4), 0, stream>>>(d_in[2], xb, 2, rpE, eidEL, aggB, E, 64, flag);
  // phase A: all-head logits in 2 passes (2 heads per pass)
  for (int p = 0; p < 2; ++p) {
    k_mgemm2sw<<<dim3(tEg, 2), blk, 0, stream>>>(fedge, nullptr, 0, 64,
        WA + wofs[10], WA + wofs[11], 4096, 2 * p, 2, SA, SBo, E, flag);
    k_mcomb2h<2><<<dim3(tELg), blk, 0, stream>>>(d_in[2], xb, 2, WA + wofs[12], 4096, 2 * p,
        WA + wofs[16], WA + wofs[15], SA, SBo, lsrc, ldst, posE, logEL4, EL, flag);
  }
  k_smax4_csr<<<dim3((E * 4 + 255) / 256), blk, 0, stream>>>(logEL4, rpE, E);
  // phase B: per-head message + aggregation (outacc first written here)
  for (int h = 0; h < 4; ++h) {
    k_mgemm<<<dim3(tEg, 1), blk, 0, stream>>>(fedge, nullptr, 0, 64, aggB, 0, 128,
        WA + wofs[13] + (size_t)h * 8192, 0, WA + wofs[14] + h * 64,
        SA, 64, E, flag);
    k_gout2<<<dim3(gE4), dim3(64, 4), 0, stream>>>(SA, logEL4, h, rpE, lsv,
                                                   outacc, E, h == 0 ? 1 : 0);
  }

  // ================= Phase 3: graph branch =================
  // tables 2x[N,128] both inside SA (outacc is live now)
  for (int p = 0; p < 2; ++p) {
    k_mgemm2sw<<<dim3(tN, 2), blk, 0, stream>>>(hnode, nullptr, 0, 64,
        WA + wofs[17], WA + wofs[18], 4096, 2 * p, 2, SA, SA + (size_t)N * 128, N, flag);
    k_mcomb2h<2><<<dim3(tEg), blk, 0, stream>>>(fedge, nullptr, 0, WA + wofs[19], 4096, 2 * p,
        WA + wofs[23], WA + wofs[22], SA, SA + (size_t)N * 128, src, dst, nullptr,
        logE4, E, flag);
  }
  k_smax4_eid<<<dim3((N * 4 + 255) / 256), blk, 0, stream>>>(logE4, rpN, eidN, N);
  k_addpair<<<dim3(gE4), dim3(64, 4), 0, stream>>>(hnode, src, dst, aggB, E);
  for (int h = 0; h < 4; ++h) {
    k_mgemm<<<dim3(tEg, 1), blk, 0, stream>>>(aggB, nullptr, 0, 64, fedge, 0, 128,
        WA + wofs[20] + (size_t)h * 8192, 0, WA + wofs[21] + h * 64,
        SA, 64, E, flag);
    k_gout3<<<dim3(gE4), dim3(64, 4), 0, stream>>>(SA, logE4, rpE, lsv,
                                                   outacc, E, h);
  }

  k_cast<<<dim3(2048), blk, 0, stream>>>(d_out, outacc, (size_t)E * 64, flag);
}

// Round 7
// 1639.103 us; speedup vs baseline: 1.1370x; 1.1213x over previous
//
#include <hip/hip_runtime.h>
#include <hip/hip_bf16.h>
#include <math.h>

typedef __hip_bfloat16 bf16;
typedef short bf16x8 __attribute__((ext_vector_type(8)));
typedef short s16x4 __attribute__((ext_vector_type(4)));
typedef float f32x4 __attribute__((ext_vector_type(4)));

__device__ __forceinline__ float b2f(bf16 x) { return __bfloat162float(x); }
__device__ __forceinline__ bf16  f2b(float x) { return __float2bfloat16(x); }
__device__ __forceinline__ float leaky(float x) { return x >= 0.0f ? x : 0.01f * x; }
__device__ __forceinline__ float sb2f(short s) {
  return __uint_as_float(((unsigned)(unsigned short)s) << 16);
}
__device__ __forceinline__ short f2bs(float x) {
  unsigned u = __float_as_uint(x);
  u += 0x7FFFu + ((u >> 16) & 1u);
  return (short)(u >> 16);
}
__device__ __forceinline__ float ldF(const void* p, size_t i, int f) {
  return f ? ((const float*)p)[i] : b2f(((const bf16*)p)[i]);
}
__device__ __forceinline__ bf16x8 ldA8(const char* row, int k, int f) {
  if (!f) return *(const bf16x8*)(row + (size_t)k * 2);
  const float4* p = (const float4*)(row + (size_t)k * 4);
  float4 a = p[0], b = p[1];
  bf16x8 r;
  r[0] = f2bs(a.x); r[1] = f2bs(a.y); r[2] = f2bs(a.z); r[3] = f2bs(a.w);
  r[4] = f2bs(b.x); r[5] = f2bs(b.y); r[6] = f2bs(b.z); r[7] = f2bs(b.w);
  return r;
}

// ---- dtype detector ----
__global__ void k_detect(const unsigned* __restrict__ w, int* __restrict__ flag) {
  __shared__ int cnt[256];
  unsigned x = w[threadIdx.x];
  unsigned ex = (x >> 7) & 0xFFu;
  cnt[threadIdx.x] = (ex >= 96u && ex <= 144u) ? 1 : 0;
  __syncthreads();
  for (int s = 128; s > 0; s >>= 1) {
    if (threadIdx.x < s) cnt[threadIdx.x] += cnt[threadIdx.x + s];
    __syncthreads();
  }
  if (threadIdx.x == 0) *flag = (cnt[0] < 128) ? 1 : 0;  // 1 = f32 inputs
}

// ---- all-weights canonicalization ----
struct WArgs { const void* src[21]; int beg[22]; int len[21]; };
__global__ void k_cvt_all(WArgs wa, bf16* __restrict__ dst, int total,
                          const int* __restrict__ flagp) {
  int f = *flagp;
  for (int i = blockIdx.x * 256 + threadIdx.x; i < total; i += gridDim.x * 256) {
    int t = 0;
    while (t < 20 && i >= wa.beg[t + 1]) ++t;
    int loc = i - wa.beg[t];
    bf16 v = f2b(0.0f);
    if (loc < wa.len[t])
      v = f ? f2b(((const float*)wa.src[t])[loc]) : ((const bf16*)wa.src[t])[loc];
    dst[i] = v;
  }
}

// ---- nfeats/xfeats f32->bf16 canonicalization (no-op in bf16 mode) ----
__global__ void k_cvt2(const float* __restrict__ a, bf16* __restrict__ da, size_t na,
                       const float* __restrict__ c, bf16* __restrict__ dc, size_t nc,
                       const int* __restrict__ flagp) {
  if (!*flagp) return;
  size_t tot = (na + nc) >> 2;
  for (size_t i = (size_t)blockIdx.x * 256 + threadIdx.x; i < tot;
       i += (size_t)gridDim.x * 256) {
    size_t j = i << 2;
    const float* s; bf16* d; size_t loc;
    if (j < na) { s = a; d = da; loc = j; }
    else        { s = c; d = dc; loc = j - na; }
    float4 v = *(const float4*)(s + loc);
    s16x4 o; o[0] = f2bs(v.x); o[1] = f2bs(v.y); o[2] = f2bs(v.z); o[3] = f2bs(v.w);
    *(s16x4*)(d + loc) = o;
  }
}

__global__ void k_izero(int* __restrict__ p, int n) {
  int i = blockIdx.x * 256 + threadIdx.x;
  for (; i < n; i += gridDim.x * 256) p[i] = 0;
}

// ---------------- CSR build ----------------
__global__ void k_hist(const int* __restrict__ seg, int* __restrict__ deg, int n) {
  int i = blockIdx.x * 256 + threadIdx.x;
  if (i < n) atomicAdd(&deg[seg[i]], 1);
}

__global__ __launch_bounds__(256)
void k_scan_local(const int* __restrict__ deg, int* __restrict__ rp,
                  int* __restrict__ bsum, int n) {
  __shared__ int sh[256];
  int tid = threadIdx.x;
  int base = blockIdx.x * 4096 + tid * 16;
  int v[16]; int s = 0;
#pragma unroll
  for (int j = 0; j < 16; ++j) { v[j] = (base + j < n) ? deg[base + j] : 0; s += v[j]; }
  sh[tid] = s;
  __syncthreads();
  for (int o = 1; o < 256; o <<= 1) {
    int t = (tid >= o) ? sh[tid - o] : 0;
    __syncthreads();
    sh[tid] += t;
    __syncthreads();
  }
  int run = sh[tid] - s;
#pragma unroll
  for (int j = 0; j < 16; ++j) {
    run += v[j];
    if (base + j < n) rp[base + j + 1] = run;
  }
  if (tid == 255) bsum[blockIdx.x] = sh[255];
  if (blockIdx.x == 0 && tid == 0) rp[0] = 0;
}
__global__ __launch_bounds__(256)
void k_scan_bsum(int* __restrict__ bsum, int nb) {
  __shared__ int sh[256];
  __shared__ int carry;
  int tid = threadIdx.x;
  if (tid == 0) carry = 0;
  __syncthreads();
  for (int base = 0; base < nb; base += 256) {
    int i = base + tid;
    int v = (i < nb) ? bsum[i] : 0;
    sh[tid] = v;
    __syncthreads();
    for (int o = 1; o < 256; o <<= 1) {
      int t = (tid >= o) ? sh[tid - o] : 0;
      __syncthreads();
      sh[tid] += t;
      __syncthreads();
    }
    if (i < nb) bsum[i] = carry + sh[tid] - v;
    int tot = sh[255];
    __syncthreads();
    if (tid == 0) carry += tot;
    __syncthreads();
  }
}
__global__ __launch_bounds__(256)
void k_scan_add(int* __restrict__ rp, const int* __restrict__ bsum, int n) {
  int b = blockIdx.x + 1;
  int ofs = bsum[b];
  int base = b * 4096 + threadIdx.x * 16;
#pragma unroll
  for (int j = 0; j < 16; ++j) {
    int idx = base + j + 1;
    if (idx <= n) rp[idx] += ofs;
  }
}

__global__ void k_slot(const int* __restrict__ seg, const int* __restrict__ rp,
                       int* __restrict__ cur, int* __restrict__ eid,
                       const int* __restrict__ aux1, int* __restrict__ av1,
                       int* __restrict__ pos, int n) {
  int i = blockIdx.x * 256 + threadIdx.x;
  if (i >= n) return;
  int t = seg[i];
  int p = atomicAdd(&cur[t], 1);
  int j = rp[t] + p;
  eid[j] = i;
  if (av1) av1[j] = aux1[i];
  if (pos) pos[i] = j;
}

// ---------------- gather-mean ----------------
__global__ void k_gmean(const void* __restrict__ X, const void* __restrict__ Xc, int mode,
                        const int* __restrict__ rp, const int* __restrict__ eid,
                        bf16* __restrict__ out, int n, int width,
                        const int* __restrict__ flagp) {
  int f = (mode == 2) ? *flagp : mode;
  if (Xc && f) { X = Xc; f = 0; }
  int d = threadIdx.x;
  int row = blockIdx.x * blockDim.y + threadIdx.y;
  if (row >= n) return;
  int b = rp[row], e = rp[row + 1];
  float s = 0.0f;
  for (int j = b; j < e; ++j) s += ldF(X, (size_t)eid[j] * width + d, f);
  out[(size_t)row * width + d] = f2b(s / fmaxf((float)(e - b), 1.0f));
}

// =================== MFMA GEMM: C[.,colofs+0..63] = A @ Wh^T (+bias), unswizzled ====
__global__ __launch_bounds__(256)
void k_mgemm(const void* __restrict__ A0, const void* __restrict__ A0c, int m0mode, int K0,
             const void* __restrict__ A1, int m1mode, int Ktot,
             const bf16* __restrict__ W, int whs, const bf16* __restrict__ bias,
             bf16* __restrict__ C, int cs, int M,
             const int* __restrict__ flagp) {
  int tid = threadIdx.x;
  int w = tid >> 6, lane = tid & 63, l15 = lane & 15, q = lane >> 4;
  int h = blockIdx.y;
  int fl = *flagp;
  int f0 = (m0mode == 2) ? fl : m0mode;
  if (A0c && f0) { A0 = A0c; f0 = 0; }
  int f1 = (m1mode == 2) ? fl : m1mode;
  const bf16* Wh = W + (size_t)h * whs;
  int colofs = h * 64;
  int m0 = blockIdx.x * 64 + w * 16;
  int mA = m0 + l15; if (mA > M - 1) mA = M - 1;
  const char* rowA0 = (const char*)A0 + (size_t)mA * K0 * (f0 ? 4 : 2);
  const char* rowA1 = A1 ? (const char*)A1 + (size_t)mA * (Ktot - K0) * (f1 ? 4 : 2) : nullptr;

  f32x4 acc[4] = {{0,0,0,0},{0,0,0,0},{0,0,0,0},{0,0,0,0}};
  for (int k = q * 8; k < Ktot; k += 32) {
    bf16x8 a;
    if (k < K0) a = ldA8(rowA0, k, f0);
    else        a = ldA8(rowA1, k - K0, f1);
    const bf16* wb = Wh + (size_t)l15 * Ktot + k;
#pragma unroll
    for (int t = 0; t < 4; ++t)
      acc[t] = __builtin_amdgcn_mfma_f32_16x16x32_bf16(
          a, *(const bf16x8*)(wb + (size_t)(t * 16) * Ktot), acc[t], 0, 0, 0);
  }
#pragma unroll
  for (int t = 0; t < 4; ++t) {
    int col = t * 16 + l15;
    float bv = bias ? b2f(bias[colofs + col]) : 0.0f;
#pragma unroll
    for (int r = 0; r < 4; ++r) {
      int m = m0 + q * 4 + r;
      if (m < M) C[(size_t)m * cs + colofs + col] = f2b(acc[t][r] + bv);
    }
  }
}

// ---- dual-output GEMM, h-contiguous swizzle: elem(h,col=t*16+l15) at l15*4*HB+hy*4+t ----
__global__ __launch_bounds__(256)
void k_mgemm2sw(const void* __restrict__ A, const void* __restrict__ Ac, int mode, int K,
                const bf16* __restrict__ W1, const bf16* __restrict__ W2, int whs,
                int h0, int HB, bf16* __restrict__ C1, bf16* __restrict__ C2, int M,
                const int* __restrict__ flagp) {
  int tid = threadIdx.x;
  int w = tid >> 6, lane = tid & 63, l15 = lane & 15, q = lane >> 4;
  int hy = blockIdx.y;
  int h = h0 + hy;
  int f = (mode == 2) ? *flagp : mode;
  if (Ac && f) { A = Ac; f = 0; }
  const bf16* W1h = W1 + (size_t)h * whs;
  const bf16* W2h = W2 + (size_t)h * whs;
  int cs = HB * 64;
  int m0 = blockIdx.x * 64 + w * 16;
  int mA = m0 + l15; if (mA > M - 1) mA = M - 1;
  const char* rowA = (const char*)A + (size_t)mA * K * (f ? 4 : 2);

  f32x4 a1[4] = {{0,0,0,0},{0,0,0,0},{0,0,0,0},{0,0,0,0}};
  f32x4 a2[4] = {{0,0,0,0},{0,0,0,0},{0,0,0,0},{0,0,0,0}};
  for (int k = q * 8; k < K; k += 32) {
    bf16x8 a = ldA8(rowA, k, f);
    const bf16* w1 = W1h + (size_t)l15 * K + k;
    const bf16* w2 = W2h + (size_t)l15 * K + k;
#pragma unroll
    for (int t = 0; t < 4; ++t) {
      a1[t] = __builtin_amdgcn_mfma_f32_16x16x32_bf16(
          a, *(const bf16x8*)(w1 + (size_t)(t * 16) * K), a1[t], 0, 0, 0);
      a2[t] = __builtin_amdgcn_mfma_f32_16x16x32_bf16(
          a, *(const bf16x8*)(w2 + (size_t)(t * 16) * K), a2[t], 0, 0, 0);
    }
  }
  int ofs = l15 * 4 * HB + hy * 4;
#pragma unroll
  for (int r = 0; r < 4; ++r) {
    int m = m0 + q * 4 + r;
    if (m < M) {
      s16x4 o1, o2;
#pragma unroll
      for (int t = 0; t < 4; ++t) { o1[t] = f2bs(a1[t][r]); o2[t] = f2bs(a2[t][r]); }
      *(s16x4*)(C1 + (size_t)m * cs + ofs) = o1;
      *(s16x4*)(C2 + (size_t)m * cs + ofs) = o2;
    }
  }
}

// ====== all-heads fused combine (P1): 2x16B gathers per (r,table) ======
template<int NK>
__global__ __launch_bounds__(256)
void k_mcomb4sw(const void* __restrict__ A, const void* __restrict__ Ac, int mode,
                const bf16* __restrict__ W, int whs,
                const bf16* __restrict__ bias, const bf16* __restrict__ attn,
                const bf16* __restrict__ G1, const bf16* __restrict__ G2,
                const int* __restrict__ gi, const int* __restrict__ gj,
                const int* __restrict__ posw,
                float* __restrict__ lg4, bf16* __restrict__ fout,
                int M, const int* __restrict__ flagp) {
  constexpr int K = NK * 32;
  int tid = threadIdx.x;
  int w = tid >> 6, lane = tid & 63, l15 = lane & 15, q = lane >> 4;
  int f = (mode == 2) ? *flagp : mode;
  if (Ac && f) { A = Ac; f = 0; }
  int m0 = blockIdx.x * 64 + w * 16;
  int mA = m0 + l15; if (mA > M - 1) mA = M - 1;
  const char* rowA = (const char*)A + (size_t)mA * K * (f ? 4 : 2);
  bf16x8 af[NK];
#pragma unroll
  for (int i = 0; i < NK; ++i) af[i] = ldA8(rowA, q * 8 + 32 * i, f);
  int pIdx[4]; bool okr[4];
  bf16x8 gv1[4][2], gv2[4][2];
#pragma unroll
  for (int r = 0; r < 4; ++r) {
    int m = m0 + q * 4 + r;
    okr[r] = m < M; int mc = okr[r] ? m : M - 1;
    pIdx[r] = posw ? posw[mc] : mc;
    const bf16* p1 = G1 + (size_t)gi[mc] * 256 + l15 * 16;
    const bf16* p2 = G2 + (size_t)gj[mc] * 256 + l15 * 16;
    gv1[r][0] = *(const bf16x8*)p1; gv1[r][1] = *(const bf16x8*)(p1 + 8);
    gv2[r][0] = *(const bf16x8*)p2; gv2[r][1] = *(const bf16x8*)(p2 + 8);
  }
  f32x4 fs[4] = {{0,0,0,0},{0,0,0,0},{0,0,0,0},{0,0,0,0}};
#pragma unroll
  for (int h = 0; h < 4; ++h) {
    const bf16* Wh = W + (size_t)h * whs;
    f32x4 acc[4] = {{0,0,0,0},{0,0,0,0},{0,0,0,0},{0,0,0,0}};
#pragma unroll
    for (int i = 0; i < NK; ++i) {
      const bf16* wb = Wh + (size_t)l15 * K + q * 8 + 32 * i;
#pragma unroll
      for (int t = 0; t < 4; ++t)
        acc[t] = __builtin_amdgcn_mfma_f32_16x16x32_bf16(
            af[i], *(const bf16x8*)(wb + (size_t)(t * 16) * K), acc[t], 0, 0, 0);
    }
    float bv[4], av[4];
#pragma unroll
    for (int t = 0; t < 4; ++t) {
      bv[t] = b2f(bias[h * 64 + t * 16 + l15]);
      av[t] = b2f(attn[h * 64 + t * 16 + l15]);
    }
    float part[4];
#pragma unroll
    for (int r = 0; r < 4; ++r) {
      float p = 0.0f;
#pragma unroll
      for (int t = 0; t < 4; ++t) {
        float v = acc[t][r] + bv[t] + sb2f(gv1[r][h >> 1][(h & 1) * 4 + t])
                                    + sb2f(gv2[r][h >> 1][(h & 1) * 4 + t]);
        v = leaky(v);
        p += v * av[t];
        fs[t][r] += v;
      }
      part[r] = p;
    }
#pragma unroll
    for (int o = 1; o < 16; o <<= 1)
#pragma unroll
      for (int r = 0; r < 4; ++r) part[r] += __shfl_xor(part[r], o, 64);
    if (l15 == 0) {
#pragma unroll
      for (int r = 0; r < 4; ++r)
        if (okr[r]) lg4[(size_t)pIdx[r] * 4 + h] = part[r];
    }
  }
  if (fout) {
#pragma unroll
    for (int t = 0; t < 4; ++t) {
      int col = t * 16 + l15;
#pragma unroll
      for (int r = 0; r < 4; ++r)
        if (okr[r]) fout[(size_t)(m0 + q * 4 + r) * 64 + col] = f2b(fs[t][r]);
    }
  }
}

// ====== 2-head fused combine (P2/P3): one 16B gather per (r,table) ======
template<int NK>
__global__ __launch_bounds__(256)
void k_mcomb2h(const void* __restrict__ A, const void* __restrict__ Ac, int mode,
               const bf16* __restrict__ W, int whs, int h0,
               const bf16* __restrict__ bias, const bf16* __restrict__ attn,
               const bf16* __restrict__ G1, const bf16* __restrict__ G2,
               const int* __restrict__ gi, const int* __restrict__ gj,
               const int* __restrict__ posw,
               float* __restrict__ lg4, int M, const int* __restrict__ flagp) {
  constexpr int K = NK * 32;
  int tid = threadIdx.x;
  int w = tid >> 6, lane = tid & 63, l15 = lane & 15, q = lane >> 4;
  int f = (mode == 2) ? *flagp : mode;
  if (Ac && f) { A = Ac; f = 0; }
  int m0 = blockIdx.x * 64 + w * 16;
  int mA = m0 + l15; if (mA > M - 1) mA = M - 1;
  const char* rowA = (const char*)A + (size_t)mA * K * (f ? 4 : 2);
  bf16x8 af[NK];
#pragma unroll
  for (int i = 0; i < NK; ++i) af[i] = ldA8(rowA, q * 8 + 32 * i, f);
  int pIdx[4]; bool okr[4];
  bf16x8 gv1[4], gv2[4];
#pragma unroll
  for (int r = 0; r < 4; ++r) {
    int m = m0 + q * 4 + r;
    okr[r] = m < M; int mc = okr[r] ? m : M - 1;
    pIdx[r] = posw ? posw[mc] : mc;
    gv1[r] = *(const bf16x8*)(G1 + (size_t)gi[mc] * 128 + l15 * 8);
    gv2[r] = *(const bf16x8*)(G2 + (size_t)gj[mc] * 128 + l15 * 8);
  }
#pragma unroll
  for (int hy = 0; hy < 2; ++hy) {
    int h = h0 + hy;
    const bf16* Wh = W + (size_t)h * whs;
    f32x4 acc[4] = {{0,0,0,0},{0,0,0,0},{0,0,0,0},{0,0,0,0}};
#pragma unroll
    for (int i = 0; i < NK; ++i) {
      const bf16* wb = Wh + (size_t)l15 * K + q * 8 + 32 * i;
#pragma unroll
      for (int t = 0; t < 4; ++t)
        acc[t] = __builtin_amdgcn_mfma_f32_16x16x32_bf16(
            af[i], *(const bf16x8*)(wb + (size_t)(t * 16) * K), acc[t], 0, 0, 0);
    }
    float bv[4], av[4];
#pragma unroll
    for (int t = 0; t < 4; ++t) {
      bv[t] = b2f(bias[h * 64 + t * 16 + l15]);
      av[t] = b2f(attn[h * 64 + t * 16 + l15]);
    }
    float part[4];
#pragma unroll
    for (int r = 0; r < 4; ++r) {
      float p = 0.0f;
#pragma unroll
      for (int t = 0; t < 4; ++t) {
        float v = acc[t][r] + bv[t] + sb2f(gv1[r][hy * 4 + t]) + sb2f(gv2[r][hy * 4 + t]);
        p += leaky(v) * av[t];
      }
      part[r] = p;
    }
#pragma unroll
    for (int o = 1; o < 16; o <<= 1)
#pragma unroll
      for (int r = 0; r < 4; ++r) part[r] += __shfl_xor(part[r], o, 64);
    if (l15 == 0) {
#pragma unroll
      for (int r = 0; r < 4; ++r)
        if (okr[r]) lg4[(size_t)pIdx[r] * 4 + h] = part[r];
    }
  }
}

// ---------------- fused per-row CSR softmax (normalizes in place) ----------------
__global__ __launch_bounds__(256)
void k_smax4_csr(float* __restrict__ lg, const int* __restrict__ rp, int n) {
  int tid = blockIdx.x * 256 + threadIdx.x;
  int row = tid >> 2, h = tid & 3;
  if (row >= n) return;
  int b = rp[row], e = rp[row + 1];
  float m = -INFINITY;
  for (int j = b; j < e; ++j) m = fmaxf(m, lg[(size_t)j * 4 + h]);
  float s = 0.0f;
  for (int j = b; j < e; ++j) {
    float ex = expf(lg[(size_t)j * 4 + h] - m);
    lg[(size_t)j * 4 + h] = ex;
    s += ex;
  }
  float inv = 1.0f / s;
  for (int j = b; j < e; ++j) lg[(size_t)j * 4 + h] *= inv;
}
__global__ __launch_bounds__(256)
void k_smax4_eid(float* __restrict__ lg, const int* __restrict__ rp,
                 const int* __restrict__ eid, int n) {
  int tid = blockIdx.x * 256 + threadIdx.x;
  int row = tid >> 2, h = tid & 3;
  if (row >= n) return;
  int b = rp[row], e = rp[row + 1];
  float m = -INFINITY;
  for (int j = b; j < e; ++j) m = fmaxf(m, lg[(size_t)eid[j] * 4 + h]);
  float s = 0.0f;
  for (int j = b; j < e; ++j) {
    float ex = expf(lg[(size_t)eid[j] * 4 + h] - m);
    lg[(size_t)eid[j] * 4 + h] = ex;
    s += ex;
  }
  float inv = 1.0f / s;
  for (int j = b; j < e; ++j) lg[(size_t)eid[j] * 4 + h] *= inv;
}

// ---- P1 epilogue: one node/block, head = wave ----
__global__ __launch_bounds__(256)
void k_ghnode(const bf16* __restrict__ H, const float* __restrict__ lg4c,
              const int* __restrict__ rp, const int* __restrict__ srcv,
              bf16* __restrict__ hnode, int N) {
  int d = threadIdx.x, h = threadIdx.y;
  int n = blockIdx.x;
  int b = rp[n], e = rp[n + 1];
  float s = 0.0f;
  for (int j = b; j < e; ++j)
    s += b2f(H[(size_t)srcv[j] * 256 + h * 64 + d]) * lg4c[(size_t)j * 4 + h];
  float v = leaky(s);
  __shared__ float sh[4][64];
  if (h > 0) sh[h][d] = v;
  __syncthreads();
  if (h == 0)
    hnode[(size_t)n * 64 + d] = f2b(v + sh[1][d] + sh[2][d] + sh[3][d]);
}

// ---- P2 epilogue: normalized lgE4 in CSR order (head h), lsv materialized ----
__global__ void k_gout2(const bf16* __restrict__ M1, const float* __restrict__ lgE4,
                        int h, const int* __restrict__ rp, const int* __restrict__ lsv,
                        float* __restrict__ out, int E, int first) {
  int d = threadIdx.x;
  int t = blockIdx.x * 4 + threadIdx.y;
  if (t >= E) return;
  int b = rp[t], e = rp[t + 1];
  float s = 0.0f;
  for (int j = b; j < e; ++j)
    s += b2f(M1[(size_t)lsv[j] * 64 + d]) * lgE4[(size_t)j * 4 + h];
  float val = leaky(s);
  if (first) out[(size_t)t * 64 + d] = val;
  else       out[(size_t)t * 64 + d] += val;
}

// ---- P3 linearity: AGG[t,0:64]=sum ne[lsv[j]], AGG[t,64:128]=sum fedge[lsv[j]] ----
__global__ void k_gagg(const bf16* __restrict__ ne, const bf16* __restrict__ fe,
                       const int* __restrict__ rp, const int* __restrict__ lsv,
                       bf16* __restrict__ agg, int E) {
  int d = threadIdx.x;
  int t = blockIdx.x * 4 + threadIdx.y;
  if (t >= E) return;
  int b = rp[t], e = rp[t + 1];
  float s1 = 0.0f, s2 = 0.0f;
  for (int j = b; j < e; ++j) {
    size_t row = (size_t)lsv[j] * 64 + d;
    s1 += b2f(ne[row]);
    s2 += b2f(fe[row]);
  }
  agg[(size_t)t * 128 + d]      = f2b(s1);
  agg[(size_t)t * 128 + 64 + d] = f2b(s2);
}

// ---- P3 fused: out[t,col] += sum_h leaky( a[t,h] * (AGG[t]@W_h^T + deg[t]*b_h) ) ----
__global__ __launch_bounds__(256)
void k_mgemm3(const bf16* __restrict__ A, const bf16* __restrict__ W, int whs,
              const bf16* __restrict__ bias, const float* __restrict__ lg4n,
              const int* __restrict__ rp, float* __restrict__ out, int M) {
  int tid = threadIdx.x;
  int w = tid >> 6, lane = tid & 63, l15 = lane & 15, q = lane >> 4;
  int m0 = blockIdx.x * 64 + w * 16;
  int mA = m0 + l15; if (mA > M - 1) mA = M - 1;
  const bf16* rowA = A + (size_t)mA * 128;
  bf16x8 af[4];
#pragma unroll
  for (int i = 0; i < 4; ++i) af[i] = *(const bf16x8*)(rowA + q * 8 + 32 * i);
  bool okr[4]; float degv[4]; float av[4][4];
#pragma unroll
  for (int r = 0; r < 4; ++r) {
    int m = m0 + q * 4 + r;
    okr[r] = m < M; int mc = okr[r] ? m : M - 1;
    degv[r] = (float)(rp[mc + 1] - rp[mc]);
#pragma unroll
    for (int h = 0; h < 4; ++h) av[r][h] = lg4n[(size_t)mc * 4 + h];
  }
  float osum[4][4] = {{0,0,0,0},{0,0,0,0},{0,0,0,0},{0,0,0,0}};
#pragma unroll
  for (int h = 0; h < 4; ++h) {
    const bf16* Wh = W + (size_t)h * whs;
    f32x4 acc[4] = {{0,0,0,0},{0,0,0,0},{0,0,0,0},{0,0,0,0}};
#pragma unroll
    for (int i = 0; i < 4; ++i) {
      const bf16* wb = Wh + (size_t)l15 * 128 + q * 8 + 32 * i;
#pragma unroll
      for (int t = 0; t < 4; ++t)
        acc[t] = __builtin_amdgcn_mfma_f32_16x16x32_bf16(
            af[i], *(const bf16x8*)(wb + (size_t)(t * 16) * 128), acc[t], 0, 0, 0);
    }
#pragma unroll
    for (int t = 0; t < 4; ++t) {
      float bv = b2f(bias[h * 64 + t * 16 + l15]);
#pragma unroll
      for (int r = 0; r < 4; ++r)
        osum[t][r] += leaky(av[r][h] * (acc[t][r] + degv[r] * bv));
    }
  }
#pragma unroll
  for (int t = 0; t < 4; ++t) {
    int col = t * 16 + l15;
#pragma unroll
    for (int r = 0; r < 4; ++r) {
      int m = m0 + q * 4 + r;
      if (m < M) out[(size_t)m * 64 + col] += osum[t][r];
    }
  }
}

// ---- P3 pre: ne[e] = hnode[src[e]] + hnode[dst[e]] ----
__global__ void k_addpair(const bf16* __restrict__ hn, const int* __restrict__ src,
                          const int* __restrict__ dst, bf16* __restrict__ ne, int E) {
  int d = threadIdx.x;
  int e = blockIdx.x * 4 + threadIdx.y;
  if (e >= E) return;
  ne[(size_t)e * 64 + d] =
      f2b(b2f(hn[(size_t)src[e] * 64 + d]) + b2f(hn[(size_t)dst[e] * 64 + d]));
}

__global__ void k_cast(void* __restrict__ out, const float* __restrict__ a, size_t n,
                       const int* __restrict__ flagp) {
  int f = *flagp;
  size_t i = (size_t)blockIdx.x * blockDim.x + threadIdx.x;
  size_t st = (size_t)gridDim.x * blockDim.x;
  for (; i < n; i += st) {
    if (f) ((float*)out)[i] = a[i];
    else   ((bf16*)out)[i] = f2b(a[i]);
  }
}

extern "C" void kernel_launch(void* const* d_in, const int* in_sizes, int n_in,
                              void* d_out, int out_size, void* d_ws, size_t ws_size,
                              hipStream_t stream) {
  const int* src  = (const int*)d_in[24];
  const int* dst  = (const int*)d_in[25];
  const int* lsrc = (const int*)d_in[26];
  const int* ldst = (const int*)d_in[27];

  const int N  = in_sizes[0] / 128;
  const int E  = in_sizes[24];
  const int EL = in_sizes[26];
  (void)n_in; (void)out_size; (void)ws_size;

  // ---- workspace (~150 MB) ----
  char* base = (char*)d_ws;
  size_t off = 0;
  auto alloc = [&](size_t bytes) -> char* {
    char* p = base + off;
    off = (off + bytes + 255) & ~(size_t)255;
    return p;
  };
  int* flag = (int*)alloc(256);
  size_t wofs[28]; size_t wtot = 0;
  for (int i = 3; i <= 23; ++i) { wofs[i] = wtot; wtot += (size_t)((in_sizes[i] + 127) & ~127); }
  bf16* WA = (bf16*)alloc(wtot * 2);

  int*   tmpi  = (int*)alloc((size_t)2 * E * 4);        // deg | cur
  int*   rpN   = (int*)alloc((size_t)(N + 1) * 4);
  int*   eidN  = (int*)alloc((size_t)E * 4);
  int*   srcv  = (int*)alloc((size_t)E * 4);            // src[eid] (CSR order)
  int*   posN  = (int*)alloc((size_t)E * 4);            // edge -> CSR slot
  int*   rpE   = (int*)alloc((size_t)(E + 1) * 4);
  int*   eidEL = (int*)alloc((size_t)EL * 4);
  int*   lsv   = (int*)alloc((size_t)EL * 4);           // lsrc[eid] (CSR order)
  int*   posE  = (int*)alloc((size_t)EL * 4);           // lg-edge -> CSR slot
  int*   bsum  = (int*)alloc(((size_t)((E > N ? E : N) + 4095) / 4096 + 8) * 4);
  bf16*  fedge = (bf16*)alloc((size_t)E * 64 * 2);      // P1 -> P2/P3 (element order)
  bf16*  hnode = (bf16*)alloc((size_t)N * 64 * 2);
  float* outacc= (float*)alloc((size_t)E * 64 * 4);     // accumulator; aliased as table SBo
  bf16*  aggB  = (bf16*)alloc((size_t)E * 64 * 2);      // P1 agg[N,128]/P2 aggx/P3 ne
  size_t saElems = (size_t)E * 128 > (size_t)N * 256 ? (size_t)E * 128 : (size_t)N * 256;
  bf16*  SA    = (bf16*)alloc(saElems * 2);             // 38.4 MB table/AGG region
  float* logE4 = (float*)alloc((size_t)E * 4 * 4);
  float* logEL4= (float*)alloc((size_t)EL * 4 * 4);
  bf16*  nb    = (bf16*)alloc((size_t)N * 128 * 2);     // nfeats bf16 canonical

  bf16* SBo = (bf16*)outacc;      // second table region (free until P2 phase B)
  bf16* xb  = (bf16*)d_out;       // xfeats bf16 canonical (scratch until final cast)

  dim3 blk(256);
  const unsigned tN = (N + 63) / 64, tEg = (E + 63) / 64, tELg = (EL + 63) / 64;
  const unsigned gE4 = (E + 3) / 4;
  const unsigned cE = (E + 255) / 256, cEL = (EL + 255) / 256;
  const int nbN = (N + 4095) / 4096, nbE = (E + 4095) / 4096;

  // ---- dtype detect + weights + nfeats/xfeats canonicalization ----
  k_detect<<<dim3(1), blk, 0, stream>>>((const unsigned*)d_in[0], flag);
  WArgs wa;
  for (int i = 3; i <= 23; ++i) {
    wa.src[i - 3] = d_in[i];
    wa.beg[i - 3] = (int)wofs[i];
    wa.len[i - 3] = in_sizes[i];
  }
  wa.beg[21] = (int)wtot;
  k_cvt_all<<<dim3(512), blk, 0, stream>>>(wa, WA, (int)wtot, flag);
  k_cvt2<<<dim3(2048), blk, 0, stream>>>(
      (const float*)d_in[0], nb, (size_t)N * 128,
      (const float*)d_in[2], xb, (size_t)EL * 64, flag);

  // ---- CSR builds ----
  int* deg = tmpi; int* cur = tmpi + E;
  k_izero<<<dim3(1024), blk, 0, stream>>>(tmpi, 2 * E);
  k_hist<<<dim3(cE), blk, 0, stream>>>(dst, deg, E);
  k_scan_local<<<dim3(nbN), blk, 0, stream>>>(deg, rpN, bsum, N);
  k_scan_bsum<<<dim3(1), blk, 0, stream>>>(bsum, nbN);
  if (nbN > 1) k_scan_add<<<dim3(nbN - 1), blk, 0, stream>>>(rpN, bsum, N);
  k_slot<<<dim3(cE), blk, 0, stream>>>(dst, rpN, cur, eidN, src, srcv, posN, E);
  k_izero<<<dim3(1024), blk, 0, stream>>>(tmpi, 2 * E);
  k_hist<<<dim3(cEL), blk, 0, stream>>>(ldst, deg, EL);
  k_scan_local<<<dim3(nbE), blk, 0, stream>>>(deg, rpE, bsum, E);
  k_scan_bsum<<<dim3(1), blk, 0, stream>>>(bsum, nbE);
  if (nbE > 1) k_scan_add<<<dim3(nbE - 1), blk, 0, stream>>>(rpE, bsum, E);
  k_slot<<<dim3(cEL), blk, 0, stream>>>(ldst, rpE, cur, eidEL, lsrc, lsv, posE, EL);

  // ================= Phase 1: EGAT =================
  k_gmean<<<dim3((N + 1) / 2), dim3(128, 2), 0, stream>>>(d_in[1], nullptr, 2, rpN, eidN,
                                                          aggB, N, 128, flag);
  k_mgemm2sw<<<dim3(tN, 4), blk, 0, stream>>>(d_in[0], nb, 2, 128,
      WA + wofs[3], WA + wofs[4], 8192, 0, 4, SA, SBo, N, flag);
  k_mcomb4sw<4><<<dim3(tEg), blk, 0, stream>>>(d_in[1], nullptr, 2, WA + wofs[5], 8192,
      WA + wofs[9], WA + wofs[8], SA, SBo, src, dst, posN, logE4, fedge, E, flag);
  k_smax4_csr<<<dim3((N * 4 + 255) / 256), blk, 0, stream>>>(logE4, rpN, N);
  k_mgemm<<<dim3(tN, 4), blk, 0, stream>>>(d_in[0], nb, 2, 128, aggB, 0, 256,
      WA + wofs[6], 16384, WA + wofs[7], SA, 256, N, flag);
  k_ghnode<<<dim3(N), dim3(64, 4), 0, stream>>>(SA, logE4, rpN, srcv, hnode, N);

  // ================= Phase 2: line-graph branch =================
  k_gmean<<<dim3(gE4), dim3(64, 4), 0, stream>>>(d_in[2], xb, 2, rpE, eidEL, aggB, E, 64, flag);
  for (int p = 0; p < 2; ++p) {
    k_mgemm2sw<<<dim3(tEg, 2), blk, 0, stream>>>(fedge, nullptr, 0, 64,
        WA + wofs[10], WA + wofs[11], 4096, 2 * p, 2, SA, SBo, E, flag);
    k_mcomb2h<2><<<dim3(tELg), blk, 0, stream>>>(d_in[2], xb, 2, WA + wofs[12], 4096, 2 * p,
        WA + wofs[16], WA + wofs[15], SA, SBo, lsrc, ldst, posE, logEL4, EL, flag);
  }
  k_smax4_csr<<<dim3((E * 4 + 255) / 256), blk, 0, stream>>>(logEL4, rpE, E);
  for (int h = 0; h < 4; ++h) {
    k_mgemm<<<dim3(tEg, 1), blk, 0, stream>>>(fedge, nullptr, 0, 64, aggB, 0, 128,
        WA + wofs[13] + (size_t)h * 8192, 0, WA + wofs[14] + h * 64,
        SA, 64, E, flag);
    k_gout2<<<dim3(gE4), dim3(64, 4), 0, stream>>>(SA, logEL4, h, rpE, lsv,
                                                   outacc, E, h == 0 ? 1 : 0);
  }

  // ================= Phase 3: graph branch =================
  for (int p = 0; p < 2; ++p) {
    k_mgemm2sw<<<dim3(tN, 2), blk, 0, stream>>>(hnode, nullptr, 0, 64,
        WA + wofs[17], WA + wofs[18], 4096, 2 * p, 2, SA, SA + (size_t)N * 128, N, flag);
    k_mcomb2h<2><<<dim3(tEg), blk, 0, stream>>>(fedge, nullptr, 0, WA + wofs[19], 4096, 2 * p,
        WA + wofs[23], WA + wofs[22], SA, SA + (size_t)N * 128, src, dst, nullptr,
        logE4, E, flag);
  }
  k_smax4_eid<<<dim3((N * 4 + 255) / 256), blk, 0, stream>>>(logE4, rpN, eidN, N);
  k_addpair<<<dim3(gE4), dim3(64, 4), 0, stream>>>(hnode, src, dst, aggB, E);
  // linearity: aggregate [ne|fedge] once over line-CSR, then one fused 4-head GEMM epilogue
  k_gagg<<<dim3(gE4), dim3(64, 4), 0, stream>>>(aggB, fedge, rpE, lsv, SA, E);
  k_mgemm3<<<dim3(tEg), blk, 0, stream>>>(SA, WA + wofs[20], 8192, WA + wofs[21],
                                          logE4, rpE, outacc, E);

  k_cast<<<dim3(2048), blk, 0, stream>>>(d_out, outacc, (size_t)E * 64, flag);
}

// Round 8
// 1618.951 us; speedup vs baseline: 1.1511x; 1.0124x over previous
//
#include <hip/hip_runtime.h>
#include <hip/hip_bf16.h>
#include <math.h>

typedef __hip_bfloat16 bf16;
typedef short bf16x8 __attribute__((ext_vector_type(8)));
typedef short s16x4 __attribute__((ext_vector_type(4)));
typedef float f32x4 __attribute__((ext_vector_type(4)));

__device__ __forceinline__ float b2f(bf16 x) { return __bfloat162float(x); }
__device__ __forceinline__ bf16  f2b(float x) { return __float2bfloat16(x); }
__device__ __forceinline__ float leaky(float x) { return x >= 0.0f ? x : 0.01f * x; }
__device__ __forceinline__ float sb2f(short s) {
  return __uint_as_float(((unsigned)(unsigned short)s) << 16);
}
__device__ __forceinline__ short f2bs(float x) {
  unsigned u = __float_as_uint(x);
  u += 0x7FFFu + ((u >> 16) & 1u);
  return (short)(u >> 16);
}
__device__ __forceinline__ float ldF(const void* p, size_t i, int f) {
  return f ? ((const float*)p)[i] : b2f(((const bf16*)p)[i]);
}
__device__ __forceinline__ bf16x8 ldA8(const char* row, int k, int f) {
  if (!f) return *(const bf16x8*)(row + (size_t)k * 2);
  const float4* p = (const float4*)(row + (size_t)k * 4);
  float4 a = p[0], b = p[1];
  bf16x8 r;
  r[0] = f2bs(a.x); r[1] = f2bs(a.y); r[2] = f2bs(a.z); r[3] = f2bs(a.w);
  r[4] = f2bs(b.x); r[5] = f2bs(b.y); r[6] = f2bs(b.z); r[7] = f2bs(b.w);
  return r;
}

// ---- dtype detector ----
__global__ void k_detect(const unsigned* __restrict__ w, int* __restrict__ flag) {
  __shared__ int cnt[256];
  unsigned x = w[threadIdx.x];
  unsigned ex = (x >> 7) & 0xFFu;
  cnt[threadIdx.x] = (ex >= 96u && ex <= 144u) ? 1 : 0;
  __syncthreads();
  for (int s = 128; s > 0; s >>= 1) {
    if (threadIdx.x < s) cnt[threadIdx.x] += cnt[threadIdx.x + s];
    __syncthreads();
  }
  if (threadIdx.x == 0) *flag = (cnt[0] < 128) ? 1 : 0;  // 1 = f32 inputs
}

// ---- all-weights canonicalization ----
struct WArgs { const void* src[21]; int beg[22]; int len[21]; };
__global__ void k_cvt_all(WArgs wa, bf16* __restrict__ dst, int total,
                          const int* __restrict__ flagp) {
  int f = *flagp;
  for (int i = blockIdx.x * 256 + threadIdx.x; i < total; i += gridDim.x * 256) {
    int t = 0;
    while (t < 20 && i >= wa.beg[t + 1]) ++t;
    int loc = i - wa.beg[t];
    bf16 v = f2b(0.0f);
    if (loc < wa.len[t])
      v = f ? f2b(((const float*)wa.src[t])[loc]) : ((const bf16*)wa.src[t])[loc];
    dst[i] = v;
  }
}

// ---- nfeats/efeats f32->bf16 canonicalization (no-op in bf16 mode) ----
__global__ void k_cvt2(const float* __restrict__ a, bf16* __restrict__ da, size_t na,
                       const float* __restrict__ c, bf16* __restrict__ dc, size_t nc,
                       const int* __restrict__ flagp) {
  if (!*flagp) return;
  size_t tot = (na + nc) >> 2;
  for (size_t i = (size_t)blockIdx.x * 256 + threadIdx.x; i < tot;
       i += (size_t)gridDim.x * 256) {
    size_t j = i << 2;
    const float* s; bf16* d; size_t loc;
    if (j < na) { s = a; d = da; loc = j; }
    else        { s = c; d = dc; loc = j - na; }
    float4 v = *(const float4*)(s + loc);
    s16x4 o; o[0] = f2bs(v.x); o[1] = f2bs(v.y); o[2] = f2bs(v.z); o[3] = f2bs(v.w);
    *(s16x4*)(d + loc) = o;
  }
}

// ---- single-array f32->bf16 (xfeats, run between P1 and P2) ----
__global__ void k_cvt1(const float* __restrict__ c, bf16* __restrict__ dc, size_t nc,
                       const int* __restrict__ flagp) {
  if (!*flagp) return;
  size_t tot = nc >> 2;
  for (size_t i = (size_t)blockIdx.x * 256 + threadIdx.x; i < tot;
       i += (size_t)gridDim.x * 256) {
    size_t loc = i << 2;
    float4 v = *(const float4*)(c + loc);
    s16x4 o; o[0] = f2bs(v.x); o[1] = f2bs(v.y); o[2] = f2bs(v.z); o[3] = f2bs(v.w);
    *(s16x4*)(dc + loc) = o;
  }
}

__global__ void k_izero(int* __restrict__ p, int n) {
  int i = blockIdx.x * 256 + threadIdx.x;
  for (; i < n; i += gridDim.x * 256) p[i] = 0;
}

// ---------------- CSR build ----------------
__global__ void k_hist(const int* __restrict__ seg, int* __restrict__ deg, int n) {
  int i = blockIdx.x * 256 + threadIdx.x;
  if (i < n) atomicAdd(&deg[seg[i]], 1);
}

__global__ __launch_bounds__(256)
void k_scan_local(const int* __restrict__ deg, int* __restrict__ rp,
                  int* __restrict__ bsum, int n) {
  __shared__ int sh[256];
  int tid = threadIdx.x;
  int base = blockIdx.x * 4096 + tid * 16;
  int v[16]; int s = 0;
#pragma unroll
  for (int j = 0; j < 16; ++j) { v[j] = (base + j < n) ? deg[base + j] : 0; s += v[j]; }
  sh[tid] = s;
  __syncthreads();
  for (int o = 1; o < 256; o <<= 1) {
    int t = (tid >= o) ? sh[tid - o] : 0;
    __syncthreads();
    sh[tid] += t;
    __syncthreads();
  }
  int run = sh[tid] - s;
#pragma unroll
  for (int j = 0; j < 16; ++j) {
    run += v[j];
    if (base + j < n) rp[base + j + 1] = run;
  }
  if (tid == 255) bsum[blockIdx.x] = sh[255];
  if (blockIdx.x == 0 && tid == 0) rp[0] = 0;
}
__global__ __launch_bounds__(256)
void k_scan_bsum(int* __restrict__ bsum, int nb) {
  __shared__ int sh[256];
  __shared__ int carry;
  int tid = threadIdx.x;
  if (tid == 0) carry = 0;
  __syncthreads();
  for (int base = 0; base < nb; base += 256) {
    int i = base + tid;
    int v = (i < nb) ? bsum[i] : 0;
    sh[tid] = v;
    __syncthreads();
    for (int o = 1; o < 256; o <<= 1) {
      int t = (tid >= o) ? sh[tid - o] : 0;
      __syncthreads();
      sh[tid] += t;
      __syncthreads();
    }
    if (i < nb) bsum[i] = carry + sh[tid] - v;
    int tot = sh[255];
    __syncthreads();
    if (tid == 0) carry += tot;
    __syncthreads();
  }
}
__global__ __launch_bounds__(256)
void k_scan_add(int* __restrict__ rp, const int* __restrict__ bsum, int n) {
  int b = blockIdx.x + 1;
  int ofs = bsum[b];
  int base = b * 4096 + threadIdx.x * 16;
#pragma unroll
  for (int j = 0; j < 16; ++j) {
    int idx = base + j + 1;
    if (idx <= n) rp[idx] += ofs;
  }
}

__global__ void k_slot(const int* __restrict__ seg, const int* __restrict__ rp,
                       int* __restrict__ cur, int* __restrict__ eid,
                       const int* __restrict__ aux1, int* __restrict__ av1,
                       int* __restrict__ pos, int n) {
  int i = blockIdx.x * 256 + threadIdx.x;
  if (i >= n) return;
  int t = seg[i];
  int p = atomicAdd(&cur[t], 1);
  int j = rp[t] + p;
  eid[j] = i;
  if (av1) av1[j] = aux1[i];
  if (pos) pos[i] = j;
}

// ---------------- gather-mean ----------------
__global__ void k_gmean(const void* __restrict__ X, const void* __restrict__ Xc, int mode,
                        const int* __restrict__ rp, const int* __restrict__ eid,
                        bf16* __restrict__ out, int n, int width,
                        const int* __restrict__ flagp) {
  int f = (mode == 2) ? *flagp : mode;
  if (Xc && f) { X = Xc; f = 0; }
  int d = threadIdx.x;
  int row = blockIdx.x * blockDim.y + threadIdx.y;
  if (row >= n) return;
  int b = rp[row], e = rp[row + 1];
  float s = 0.0f;
  for (int j = b; j < e; ++j) s += ldF(X, (size_t)eid[j] * width + d, f);
  out[(size_t)row * width + d] = f2b(s / fmaxf((float)(e - b), 1.0f));
}

// =================== MFMA GEMM: C[.,colofs+0..63] = A @ Wh^T (+bias), unswizzled ====
__global__ __launch_bounds__(256)
void k_mgemm(const void* __restrict__ A0, const void* __restrict__ A0c, int m0mode, int K0,
             const void* __restrict__ A1, int m1mode, int Ktot,
             const bf16* __restrict__ W, int whs, const bf16* __restrict__ bias,
             bf16* __restrict__ C, int cs, int M,
             const int* __restrict__ flagp) {
  int tid = threadIdx.x;
  int w = tid >> 6, lane = tid & 63, l15 = lane & 15, q = lane >> 4;
  int h = blockIdx.y;
  int fl = *flagp;
  int f0 = (m0mode == 2) ? fl : m0mode;
  if (A0c && f0) { A0 = A0c; f0 = 0; }
  int f1 = (m1mode == 2) ? fl : m1mode;
  const bf16* Wh = W + (size_t)h * whs;
  int colofs = h * 64;
  int m0 = blockIdx.x * 64 + w * 16;
  int mA = m0 + l15; if (mA > M - 1) mA = M - 1;
  const char* rowA0 = (const char*)A0 + (size_t)mA * K0 * (f0 ? 4 : 2);
  const char* rowA1 = A1 ? (const char*)A1 + (size_t)mA * (Ktot - K0) * (f1 ? 4 : 2) : nullptr;

  f32x4 acc[4] = {{0,0,0,0},{0,0,0,0},{0,0,0,0},{0,0,0,0}};
  for (int k = q * 8; k < Ktot; k += 32) {
    bf16x8 a;
    if (k < K0) a = ldA8(rowA0, k, f0);
    else        a = ldA8(rowA1, k - K0, f1);
    const bf16* wb = Wh + (size_t)l15 * Ktot + k;
#pragma unroll
    for (int t = 0; t < 4; ++t)
      acc[t] = __builtin_amdgcn_mfma_f32_16x16x32_bf16(
          a, *(const bf16x8*)(wb + (size_t)(t * 16) * Ktot), acc[t], 0, 0, 0);
  }
#pragma unroll
  for (int t = 0; t < 4; ++t) {
    int col = t * 16 + l15;
    float bv = bias ? b2f(bias[colofs + col]) : 0.0f;
#pragma unroll
    for (int r = 0; r < 4; ++r) {
      int m = m0 + q * 4 + r;
      if (m < M) C[(size_t)m * cs + colofs + col] = f2b(acc[t][r] + bv);
    }
  }
}

// ---- dual-output GEMM, h-contiguous swizzle: elem(h,col=t*16+l15) at l15*4*HB+hy*4+t ----
__global__ __launch_bounds__(256)
void k_mgemm2sw(const void* __restrict__ A, const void* __restrict__ Ac, int mode, int K,
                const bf16* __restrict__ W1, const bf16* __restrict__ W2, int whs,
                int h0, int HB, bf16* __restrict__ C1, bf16* __restrict__ C2, int M,
                const int* __restrict__ flagp) {
  int tid = threadIdx.x;
  int w = tid >> 6, lane = tid & 63, l15 = lane & 15, q = lane >> 4;
  int hy = blockIdx.y;
  int h = h0 + hy;
  int f = (mode == 2) ? *flagp : mode;
  if (Ac && f) { A = Ac; f = 0; }
  const bf16* W1h = W1 + (size_t)h * whs;
  const bf16* W2h = W2 + (size_t)h * whs;
  int cs = HB * 64;
  int m0 = blockIdx.x * 64 + w * 16;
  int mA = m0 + l15; if (mA > M - 1) mA = M - 1;
  const char* rowA = (const char*)A + (size_t)mA * K * (f ? 4 : 2);

  f32x4 a1[4] = {{0,0,0,0},{0,0,0,0},{0,0,0,0},{0,0,0,0}};
  f32x4 a2[4] = {{0,0,0,0},{0,0,0,0},{0,0,0,0},{0,0,0,0}};
  for (int k = q * 8; k < K; k += 32) {
    bf16x8 a = ldA8(rowA, k, f);
    const bf16* w1 = W1h + (size_t)l15 * K + k;
    const bf16* w2 = W2h + (size_t)l15 * K + k;
#pragma unroll
    for (int t = 0; t < 4; ++t) {
      a1[t] = __builtin_amdgcn_mfma_f32_16x16x32_bf16(
          a, *(const bf16x8*)(w1 + (size_t)(t * 16) * K), a1[t], 0, 0, 0);
      a2[t] = __builtin_amdgcn_mfma_f32_16x16x32_bf16(
          a, *(const bf16x8*)(w2 + (size_t)(t * 16) * K), a2[t], 0, 0, 0);
    }
  }
  int ofs = l15 * 4 * HB + hy * 4;
#pragma unroll
  for (int r = 0; r < 4; ++r) {
    int m = m0 + q * 4 + r;
    if (m < M) {
      s16x4 o1, o2;
#pragma unroll
      for (int t = 0; t < 4; ++t) { o1[t] = f2bs(a1[t][r]); o2[t] = f2bs(a2[t][r]); }
      *(s16x4*)(C1 + (size_t)m * cs + ofs) = o1;
      *(s16x4*)(C2 + (size_t)m * cs + ofs) = o2;
    }
  }
}

// ====== all-heads fused combine (P1), bf16-only A-stream ======
template<int NK>
__global__ __launch_bounds__(256)
void k_mcomb4sw(const bf16* __restrict__ A, const bf16* __restrict__ Ac,
                const bf16* __restrict__ W, int whs,
                const bf16* __restrict__ bias, const bf16* __restrict__ attn,
                const bf16* __restrict__ G1, const bf16* __restrict__ G2,
                const int* __restrict__ gi, const int* __restrict__ gj,
                const int* __restrict__ posw,
                float* __restrict__ lg4, bf16* __restrict__ fout,
                int M, const int* __restrict__ flagp) {
  constexpr int K = NK * 32;
  int tid = threadIdx.x;
  int w = tid >> 6, lane = tid & 63, l15 = lane & 15, q = lane >> 4;
  if (Ac && *flagp) A = Ac;
  int m0 = blockIdx.x * 64 + w * 16;
  int mA = m0 + l15; if (mA > M - 1) mA = M - 1;
  const bf16* rowA = A + (size_t)mA * K;
  bf16x8 af[NK];
#pragma unroll
  for (int i = 0; i < NK; ++i) af[i] = *(const bf16x8*)(rowA + q * 8 + 32 * i);
  int pIdx[4]; bool okr[4];
  bf16x8 gv1[4][2], gv2[4][2];
#pragma unroll
  for (int r = 0; r < 4; ++r) {
    int m = m0 + q * 4 + r;
    okr[r] = m < M; int mc = okr[r] ? m : M - 1;
    pIdx[r] = posw ? posw[mc] : mc;
    const bf16* p1 = G1 + (size_t)gi[mc] * 256 + l15 * 16;
    const bf16* p2 = G2 + (size_t)gj[mc] * 256 + l15 * 16;
    gv1[r][0] = *(const bf16x8*)p1; gv1[r][1] = *(const bf16x8*)(p1 + 8);
    gv2[r][0] = *(const bf16x8*)p2; gv2[r][1] = *(const bf16x8*)(p2 + 8);
  }
  f32x4 fs[4] = {{0,0,0,0},{0,0,0,0},{0,0,0,0},{0,0,0,0}};
#pragma unroll
  for (int h = 0; h < 4; ++h) {
    const bf16* Wh = W + (size_t)h * whs;
    f32x4 acc[4] = {{0,0,0,0},{0,0,0,0},{0,0,0,0},{0,0,0,0}};
#pragma unroll
    for (int i = 0; i < NK; ++i) {
      const bf16* wb = Wh + (size_t)l15 * K + q * 8 + 32 * i;
#pragma unroll
      for (int t = 0; t < 4; ++t)
        acc[t] = __builtin_amdgcn_mfma_f32_16x16x32_bf16(
            af[i], *(const bf16x8*)(wb + (size_t)(t * 16) * K), acc[t], 0, 0, 0);
    }
    float bv[4], av[4];
#pragma unroll
    for (int t = 0; t < 4; ++t) {
      bv[t] = b2f(bias[h * 64 + t * 16 + l15]);
      av[t] = b2f(attn[h * 64 + t * 16 + l15]);
    }
    float part[4];
#pragma unroll
    for (int r = 0; r < 4; ++r) {
      float p = 0.0f;
#pragma unroll
      for (int t = 0; t < 4; ++t) {
        float v = acc[t][r] + bv[t] + sb2f(gv1[r][h >> 1][(h & 1) * 4 + t])
                                    + sb2f(gv2[r][h >> 1][(h & 1) * 4 + t]);
        v = leaky(v);
        p += v * av[t];
        fs[t][r] += v;
      }
      part[r] = p;
    }
#pragma unroll
    for (int o = 1; o < 16; o <<= 1)
#pragma unroll
      for (int r = 0; r < 4; ++r) part[r] += __shfl_xor(part[r], o, 64);
    if (l15 == 0) {
#pragma unroll
      for (int r = 0; r < 4; ++r)
        if (okr[r]) lg4[(size_t)pIdx[r] * 4 + h] = part[r];
    }
  }
  if (fout) {
#pragma unroll
    for (int t = 0; t < 4; ++t) {
      int col = t * 16 + l15;
#pragma unroll
      for (int r = 0; r < 4; ++r)
        if (okr[r]) fout[(size_t)(m0 + q * 4 + r) * 64 + col] = f2b(fs[t][r]);
    }
  }
}

// ====== 2-head fused combine (P2/P3), bf16-only A-stream ======
template<int NK>
__global__ __launch_bounds__(256)
void k_mcomb2h(const bf16* __restrict__ A, const bf16* __restrict__ Ac,
               const bf16* __restrict__ W, int whs, int h0,
               const bf16* __restrict__ bias, const bf16* __restrict__ attn,
               const bf16* __restrict__ G1, const bf16* __restrict__ G2,
               const int* __restrict__ gi, const int* __restrict__ gj,
               const int* __restrict__ posw,
               float* __restrict__ lg4, int M, const int* __restrict__ flagp) {
  constexpr int K = NK * 32;
  int tid = threadIdx.x;
  int w = tid >> 6, lane = tid & 63, l15 = lane & 15, q = lane >> 4;
  if (Ac && *flagp) A = Ac;
  int m0 = blockIdx.x * 64 + w * 16;
  int mA = m0 + l15; if (mA > M - 1) mA = M - 1;
  const bf16* rowA = A + (size_t)mA * K;
  bf16x8 af[NK];
#pragma unroll
  for (int i = 0; i < NK; ++i) af[i] = *(const bf16x8*)(rowA + q * 8 + 32 * i);
  int pIdx[4]; bool okr[4];
  bf16x8 gv1[4], gv2[4];
#pragma unroll
  for (int r = 0; r < 4; ++r) {
    int m = m0 + q * 4 + r;
    okr[r] = m < M; int mc = okr[r] ? m : M - 1;
    pIdx[r] = posw ? posw[mc] : mc;
    gv1[r] = *(const bf16x8*)(G1 + (size_t)gi[mc] * 128 + l15 * 8);
    gv2[r] = *(const bf16x8*)(G2 + (size_t)gj[mc] * 128 + l15 * 8);
  }
#pragma unroll
  for (int hy = 0; hy < 2; ++hy) {
    int h = h0 + hy;
    const bf16* Wh = W + (size_t)h * whs;
    f32x4 acc[4] = {{0,0,0,0},{0,0,0,0},{0,0,0,0},{0,0,0,0}};
#pragma unroll
    for (int i = 0; i < NK; ++i) {
      const bf16* wb = Wh + (size_t)l15 * K + q * 8 + 32 * i;
#pragma unroll
      for (int t = 0; t < 4; ++t)
        acc[t] = __builtin_amdgcn_mfma_f32_16x16x32_bf16(
            af[i], *(const bf16x8*)(wb + (size_t)(t * 16) * K), acc[t], 0, 0, 0);
    }
    float bv[4], av[4];
#pragma unroll
    for (int t = 0; t < 4; ++t) {
      bv[t] = b2f(bias[h * 64 + t * 16 + l15]);
      av[t] = b2f(attn[h * 64 + t * 16 + l15]);
    }
    float part[4];
#pragma unroll
    for (int r = 0; r < 4; ++r) {
      float p = 0.0f;
#pragma unroll
      for (int t = 0; t < 4; ++t) {
        float v = acc[t][r] + bv[t] + sb2f(gv1[r][hy * 4 + t]) + sb2f(gv2[r][hy * 4 + t]);
        p += leaky(v) * av[t];
      }
      part[r] = p;
    }
#pragma unroll
    for (int o = 1; o < 16; o <<= 1)
#pragma unroll
      for (int r = 0; r < 4; ++r) part[r] += __shfl_xor(part[r], o, 64);
    if (l15 == 0) {
#pragma unroll
      for (int r = 0; r < 4; ++r)
        if (okr[r]) lg4[(size_t)pIdx[r] * 4 + h] = part[r];
    }
  }
}

// ---------------- fused per-row CSR softmax (normalizes in place) ----------------
__global__ __launch_bounds__(256)
void k_smax4_csr(float* __restrict__ lg, const int* __restrict__ rp, int n) {
  int tid = blockIdx.x * 256 + threadIdx.x;
  int row = tid >> 2, h = tid & 3;
  if (row >= n) return;
  int b = rp[row], e = rp[row + 1];
  float m = -INFINITY;
  for (int j = b; j < e; ++j) m = fmaxf(m, lg[(size_t)j * 4 + h]);
  float s = 0.0f;
  for (int j = b; j < e; ++j) {
    float ex = expf(lg[(size_t)j * 4 + h] - m);
    lg[(size_t)j * 4 + h] = ex;
    s += ex;
  }
  float inv = 1.0f / s;
  for (int j = b; j < e; ++j) lg[(size_t)j * 4 + h] *= inv;
}
__global__ __launch_bounds__(256)
void k_smax4_eid(float* __restrict__ lg, const int* __restrict__ rp,
                 const int* __restrict__ eid, int n) {
  int tid = blockIdx.x * 256 + threadIdx.x;
  int row = tid >> 2, h = tid & 3;
  if (row >= n) return;
  int b = rp[row], e = rp[row + 1];
  float m = -INFINITY;
  for (int j = b; j < e; ++j) m = fmaxf(m, lg[(size_t)eid[j] * 4 + h]);
  float s = 0.0f;
  for (int j = b; j < e; ++j) {
    float ex = expf(lg[(size_t)eid[j] * 4 + h] - m);
    lg[(size_t)eid[j] * 4 + h] = ex;
    s += ex;
  }
  float inv = 1.0f / s;
  for (int j = b; j < e; ++j) lg[(size_t)eid[j] * 4 + h] *= inv;
}

// ---- P1 epilogue: one node/block, head = wave ----
__global__ __launch_bounds__(256)
void k_ghnode(const bf16* __restrict__ H, const float* __restrict__ lg4c,
              const int* __restrict__ rp, const int* __restrict__ srcv,
              bf16* __restrict__ hnode, int N) {
  int d = threadIdx.x, h = threadIdx.y;
  int n = blockIdx.x;
  int b = rp[n], e = rp[n + 1];
  float s = 0.0f;
  for (int j = b; j < e; ++j)
    s += b2f(H[(size_t)srcv[j] * 256 + h * 64 + d]) * lg4c[(size_t)j * 4 + h];
  float v = leaky(s);
  __shared__ float sh[4][64];
  if (h > 0) sh[h][d] = v;
  __syncthreads();
  if (h == 0)
    hnode[(size_t)n * 64 + d] = f2b(v + sh[1][d] + sh[2][d] + sh[3][d]);
}

// ---- P2 epilogue: normalized lgE4 in CSR order (head h), lsv materialized ----
__global__ void k_gout2(const bf16* __restrict__ M1, const float* __restrict__ lgE4,
                        int h, const int* __restrict__ rp, const int* __restrict__ lsv,
                        float* __restrict__ out, int E, int first) {
  int d = threadIdx.x;
  int t = blockIdx.x * 4 + threadIdx.y;
  if (t >= E) return;
  int b = rp[t], e = rp[t + 1];
  float s = 0.0f;
  for (int j = b; j < e; ++j)
    s += b2f(M1[(size_t)lsv[j] * 64 + d]) * lgE4[(size_t)j * 4 + h];
  float val = leaky(s);
  if (first) out[(size_t)t * 64 + d] = val;
  else       out[(size_t)t * 64 + d] += val;
}

// ---- P3 linearity: AGG[t,0:64]=sum ne[lsv[j]], AGG[t,64:128]=sum fedge[lsv[j]] ----
__global__ void k_gagg(const bf16* __restrict__ ne, const bf16* __restrict__ fe,
                       const int* __restrict__ rp, const int* __restrict__ lsv,
                       bf16* __restrict__ agg, int E) {
  int d = threadIdx.x;
  int t = blockIdx.x * 4 + threadIdx.y;
  if (t >= E) return;
  int b = rp[t], e = rp[t + 1];
  float s1 = 0.0f, s2 = 0.0f;
  for (int j = b; j < e; ++j) {
    size_t row = (size_t)lsv[j] * 64 + d;
    s1 += b2f(ne[row]);
    s2 += b2f(fe[row]);
  }
  agg[(size_t)t * 128 + d]      = f2b(s1);
  agg[(size_t)t * 128 + 64 + d] = f2b(s2);
}

// ---- P3 fused: out[t,col] += sum_h leaky( a[t,h] * (AGG[t]@W_h^T + deg[t]*b_h) ) ----
__global__ __launch_bounds__(256)
void k_mgemm3(const bf16* __restrict__ A, const bf16* __restrict__ W, int whs,
              const bf16* __restrict__ bias, const float* __restrict__ lg4n,
              const int* __restrict__ rp, float* __restrict__ out, int M) {
  int tid = threadIdx.x;
  int w = tid >> 6, lane = tid & 63, l15 = lane & 15, q = lane >> 4;
  int m0 = blockIdx.x * 64 + w * 16;
  int mA = m0 + l15; if (mA > M - 1) mA = M - 1;
  const bf16* rowA = A + (size_t)mA * 128;
  bf16x8 af[4];
#pragma unroll
  for (int i = 0; i < 4; ++i) af[i] = *(const bf16x8*)(rowA + q * 8 + 32 * i);
  bool okr[4]; float degv[4]; float av[4][4];
#pragma unroll
  for (int r = 0; r < 4; ++r) {
    int m = m0 + q * 4 + r;
    okr[r] = m < M; int mc = okr[r] ? m : M - 1;
    degv[r] = (float)(rp[mc + 1] - rp[mc]);
#pragma unroll
    for (int h = 0; h < 4; ++h) av[r][h] = lg4n[(size_t)mc * 4 + h];
  }
  float osum[4][4] = {{0,0,0,0},{0,0,0,0},{0,0,0,0},{0,0,0,0}};
#pragma unroll
  for (int h = 0; h < 4; ++h) {
    const bf16* Wh = W + (size_t)h * whs;
    f32x4 acc[4] = {{0,0,0,0},{0,0,0,0},{0,0,0,0},{0,0,0,0}};
#pragma unroll
    for (int i = 0; i < 4; ++i) {
      const bf16* wb = Wh + (size_t)l15 * 128 + q * 8 + 32 * i;
#pragma unroll
      for (int t = 0; t < 4; ++t)
        acc[t] = __builtin_amdgcn_mfma_f32_16x16x32_bf16(
            af[i], *(const bf16x8*)(wb + (size_t)(t * 16) * 128), acc[t], 0, 0, 0);
    }
#pragma unroll
    for (int t = 0; t < 4; ++t) {
      float bv = b2f(bias[h * 64 + t * 16 + l15]);
#pragma unroll
      for (int r = 0; r < 4; ++r)
        osum[t][r] += leaky(av[r][h] * (acc[t][r] + degv[r] * bv));
    }
  }
#pragma unroll
  for (int t = 0; t < 4; ++t) {
    int col = t * 16 + l15;
#pragma unroll
    for (int r = 0; r < 4; ++r) {
      int m = m0 + q * 4 + r;
      if (m < M) out[(size_t)m * 64 + col] += osum[t][r];
    }
  }
}

// ---- P3 pre: ne[e] = hnode[src[e]] + hnode[dst[e]] ----
__global__ void k_addpair(const bf16* __restrict__ hn, const int* __restrict__ src,
                          const int* __restrict__ dst, bf16* __restrict__ ne, int E) {
  int d = threadIdx.x;
  int e = blockIdx.x * 4 + threadIdx.y;
  if (e >= E) return;
  ne[(size_t)e * 64 + d] =
      f2b(b2f(hn[(size_t)src[e] * 64 + d]) + b2f(hn[(size_t)dst[e] * 64 + d]));
}

__global__ void k_cast(void* __restrict__ out, const float* __restrict__ a, size_t n,
                       const int* __restrict__ flagp) {
  int f = *flagp;
  size_t i = (size_t)blockIdx.x * blockDim.x + threadIdx.x;
  size_t st = (size_t)gridDim.x * blockDim.x;
  for (; i < n; i += st) {
    if (f) ((float*)out)[i] = a[i];
    else   ((bf16*)out)[i] = f2b(a[i]);
  }
}

extern "C" void kernel_launch(void* const* d_in, const int* in_sizes, int n_in,
                              void* d_out, int out_size, void* d_ws, size_t ws_size,
                              hipStream_t stream) {
  const int* src  = (const int*)d_in[24];
  const int* dst  = (const int*)d_in[25];
  const int* lsrc = (const int*)d_in[26];
  const int* ldst = (const int*)d_in[27];

  const int N  = in_sizes[0] / 128;
  const int E  = in_sizes[24];
  const int EL = in_sizes[26];
  (void)n_in; (void)out_size; (void)ws_size;

  // ---- workspace (~150 MB) ----
  char* base = (char*)d_ws;
  size_t off = 0;
  auto alloc = [&](size_t bytes) -> char* {
    char* p = base + off;
    off = (off + bytes + 255) & ~(size_t)255;
    return p;
  };
  int* flag = (int*)alloc(256);
  size_t wofs[28]; size_t wtot = 0;
  for (int i = 3; i <= 23; ++i) { wofs[i] = wtot; wtot += (size_t)((in_sizes[i] + 127) & ~127); }
  bf16* WA = (bf16*)alloc(wtot * 2);

  int*   tmpi  = (int*)alloc((size_t)2 * E * 4);        // deg | cur
  int*   rpN   = (int*)alloc((size_t)(N + 1) * 4);
  int*   eidN  = (int*)alloc((size_t)E * 4);
  int*   srcv  = (int*)alloc((size_t)E * 4);            // src[eid] (CSR order)
  int*   posN  = (int*)alloc((size_t)E * 4);            // edge -> CSR slot
  int*   rpE   = (int*)alloc((size_t)(E + 1) * 4);
  int*   eidEL = (int*)alloc((size_t)EL * 4);
  int*   lsv   = (int*)alloc((size_t)EL * 4);           // lsrc[eid] (CSR order)
  int*   posE  = (int*)alloc((size_t)EL * 4);           // lg-edge -> CSR slot
  int*   bsum  = (int*)alloc(((size_t)((E > N ? E : N) + 4095) / 4096 + 8) * 4);
  bf16*  fedge = (bf16*)alloc((size_t)E * 64 * 2);      // P1 -> P2/P3 (element order)
  bf16*  hnode = (bf16*)alloc((size_t)N * 64 * 2);
  float* outacc= (float*)alloc((size_t)E * 64 * 4);     // accumulator; aliased as table SBo
  bf16*  aggB  = (bf16*)alloc((size_t)E * 64 * 2);      // P1 agg[N,128]/P2 aggx/P3 ne
  size_t saElems = (size_t)E * 128 > (size_t)N * 256 ? (size_t)E * 128 : (size_t)N * 256;
  bf16*  SA    = (bf16*)alloc(saElems * 2);             // 38.4 MB table/AGG region
  float* logE4 = (float*)alloc((size_t)E * 4 * 4);
  float* logEL4= (float*)alloc((size_t)EL * 4 * 4);
  bf16*  nb    = (bf16*)alloc((size_t)N * 128 * 2);     // nfeats bf16 canonical

  bf16* SBo = (bf16*)outacc;      // second table region (free until P2 phase B)
  // d_out time-shared scratch: eb (efeats bf16) during P1, then xb (xfeats bf16) for P2
  bf16* eb = (bf16*)d_out;
  bf16* xb = (bf16*)d_out;

  dim3 blk(256);
  const unsigned tN = (N + 63) / 64, tEg = (E + 63) / 64, tELg = (EL + 63) / 64;
  const unsigned gE4 = (E + 3) / 4;
  const unsigned cE = (E + 255) / 256, cEL = (EL + 255) / 256;
  const int nbN = (N + 4095) / 4096, nbE = (E + 4095) / 4096;

  // ---- dtype detect + weights + nfeats/efeats canonicalization ----
  k_detect<<<dim3(1), blk, 0, stream>>>((const unsigned*)d_in[0], flag);
  WArgs wa;
  for (int i = 3; i <= 23; ++i) {
    wa.src[i - 3] = d_in[i];
    wa.beg[i - 3] = (int)wofs[i];
    wa.len[i - 3] = in_sizes[i];
  }
  wa.beg[21] = (int)wtot;
  k_cvt_all<<<dim3(512), blk, 0, stream>>>(wa, WA, (int)wtot, flag);
  k_cvt2<<<dim3(2048), blk, 0, stream>>>(
      (const float*)d_in[0], nb, (size_t)N * 128,
      (const float*)d_in[1], eb, (size_t)E * 128, flag);

  // ---- CSR builds ----
  int* deg = tmpi; int* cur = tmpi + E;
  k_izero<<<dim3(1024), blk, 0, stream>>>(tmpi, 2 * E);
  k_hist<<<dim3(cE), blk, 0, stream>>>(dst, deg, E);
  k_scan_local<<<dim3(nbN), blk, 0, stream>>>(deg, rpN, bsum, N);
  k_scan_bsum<<<dim3(1), blk, 0, stream>>>(bsum, nbN);
  if (nbN > 1) k_scan_add<<<dim3(nbN - 1), blk, 0, stream>>>(rpN, bsum, N);
  k_slot<<<dim3(cE), blk, 0, stream>>>(dst, rpN, cur, eidN, src, srcv, posN, E);
  k_izero<<<dim3(1024), blk, 0, stream>>>(tmpi, 2 * E);
  k_hist<<<dim3(cEL), blk, 0, stream>>>(ldst, deg, EL);
  k_scan_local<<<dim3(nbE), blk, 0, stream>>>(deg, rpE, bsum, E);
  k_scan_bsum<<<dim3(1), blk, 0, stream>>>(bsum, nbE);
  if (nbE > 1) k_scan_add<<<dim3(nbE - 1), blk, 0, stream>>>(rpE, bsum, E);
  k_slot<<<dim3(cEL), blk, 0, stream>>>(ldst, rpE, cur, eidEL, lsrc, lsv, posE, EL);

  // ================= Phase 1: EGAT =================
  k_gmean<<<dim3((N + 1) / 2), dim3(128, 2), 0, stream>>>(d_in[1], eb, 2, rpN, eidN,
                                                          aggB, N, 128, flag);
  k_mgemm2sw<<<dim3(tN, 4), blk, 0, stream>>>(d_in[0], nb, 2, 128,
      WA + wofs[3], WA + wofs[4], 8192, 0, 4, SA, SBo, N, flag);
  k_mcomb4sw<4><<<dim3(tEg), blk, 0, stream>>>((const bf16*)d_in[1], eb,
      WA + wofs[5], 8192, WA + wofs[9], WA + wofs[8], SA, SBo,
      src, dst, posN, logE4, fedge, E, flag);
  k_smax4_csr<<<dim3((N * 4 + 255) / 256), blk, 0, stream>>>(logE4, rpN, N);
  k_mgemm<<<dim3(tN, 4), blk, 0, stream>>>(d_in[0], nb, 2, 128, aggB, 0, 256,
      WA + wofs[6], 16384, WA + wofs[7], SA, 256, N, flag);
  k_ghnode<<<dim3(N), dim3(64, 4), 0, stream>>>(SA, logE4, rpN, srcv, hnode, N);

  // ---- d_out handoff: eb dead, convert xfeats -> xb (same region) ----
  k_cvt1<<<dim3(2048), blk, 0, stream>>>((const float*)d_in[2], xb,
                                         (size_t)EL * 64, flag);

  // ================= Phase 2: line-graph branch =================
  k_gmean<<<dim3(gE4), dim3(64, 4), 0, stream>>>(d_in[2], xb, 2, rpE, eidEL, aggB, E, 64, flag);
  for (int p = 0; p < 2; ++p) {
    k_mgemm2sw<<<dim3(tEg, 2), blk, 0, stream>>>(fedge, nullptr, 0, 64,
        WA + wofs[10], WA + wofs[11], 4096, 2 * p, 2, SA, SBo, E, flag);
    k_mcomb2h<2><<<dim3(tELg), blk, 0, stream>>>((const bf16*)d_in[2], xb,
        WA + wofs[12], 4096, 2 * p, WA + wofs[16], WA + wofs[15],
        SA, SBo, lsrc, ldst, posE, logEL4, EL, flag);
  }
  k_smax4_csr<<<dim3((E * 4 + 255) / 256), blk, 0, stream>>>(logEL4, rpE, E);
  for (int h = 0; h < 4; ++h) {
    k_mgemm<<<dim3(tEg, 1), blk, 0, stream>>>(fedge, nullptr, 0, 64, aggB, 0, 128,
        WA + wofs[13] + (size_t)h * 8192, 0, WA + wofs[14] + h * 64,
        SA, 64, E, flag);
    k_gout2<<<dim3(gE4), dim3(64, 4), 0, stream>>>(SA, logEL4, h, rpE, lsv,
                                                   outacc, E, h == 0 ? 1 : 0);
  }

  // ================= Phase 3: graph branch =================
  for (int p = 0; p < 2; ++p) {
    k_mgemm2sw<<<dim3(tN, 2), blk, 0, stream>>>(hnode, nullptr, 0, 64,
        WA + wofs[17], WA + wofs[18], 4096, 2 * p, 2, SA, SA + (size_t)N * 128, N, flag);
    k_mcomb2h<2><<<dim3(tEg), blk, 0, stream>>>(fedge, nullptr,
        WA + wofs[19], 4096, 2 * p, WA + wofs[23], WA + wofs[22],
        SA, SA + (size_t)N * 128, src, dst, nullptr, logE4, E, flag);
  }
  k_smax4_eid<<<dim3((N * 4 + 255) / 256), blk, 0, stream>>>(logE4, rpN, eidN, N);
  k_addpair<<<dim3(gE4), dim3(64, 4), 0, stream>>>(hnode, src, dst, aggB, E);
  // linearity: aggregate [ne|fedge] once over line-CSR, then one fused 4-head GEMM epilogue
  k_gagg<<<dim3(gE4), dim3(64, 4), 0, stream>>>(aggB, fedge, rpE, lsv, SA, E);
  k_mgemm3<<<dim3(tEg), blk, 0, stream>>>(SA, WA + wofs[20], 8192, WA + wofs[21],
                                          logE4, rpE, outacc, E);

  k_cast<<<dim3(2048), blk, 0, stream>>>(d_out, outacc, (size_t)E * 64, flag);
}

// Round 9
// 1513.227 us; speedup vs baseline: 1.2316x; 1.0699x over previous
//
#include <hip/hip_runtime.h>
#include <hip/hip_bf16.h>
#include <math.h>

typedef __hip_bfloat16 bf16;
typedef short bf16x8 __attribute__((ext_vector_type(8)));
typedef short s16x4 __attribute__((ext_vector_type(4)));
typedef float f32x4 __attribute__((ext_vector_type(4)));

__device__ __forceinline__ float b2f(bf16 x) { return __bfloat162float(x); }
__device__ __forceinline__ bf16  f2b(float x) { return __float2bfloat16(x); }
__device__ __forceinline__ float leaky(float x) { return x >= 0.0f ? x : 0.01f * x; }
__device__ __forceinline__ float sb2f(short s) {
  return __uint_as_float(((unsigned)(unsigned short)s) << 16);
}
__device__ __forceinline__ short f2bs(float x) {
  unsigned u = __float_as_uint(x);
  u += 0x7FFFu + ((u >> 16) & 1u);
  return (short)(u >> 16);
}
__device__ __forceinline__ float ldF(const void* p, size_t i, int f) {
  return f ? ((const float*)p)[i] : b2f(((const bf16*)p)[i]);
}
__device__ __forceinline__ bf16x8 ldA8(const char* row, int k, int f) {
  if (!f) return *(const bf16x8*)(row + (size_t)k * 2);
  const float4* p = (const float4*)(row + (size_t)k * 4);
  float4 a = p[0], b = p[1];
  bf16x8 r;
  r[0] = f2bs(a.x); r[1] = f2bs(a.y); r[2] = f2bs(a.z); r[3] = f2bs(a.w);
  r[4] = f2bs(b.x); r[5] = f2bs(b.y); r[6] = f2bs(b.z); r[7] = f2bs(b.w);
  return r;
}

// ---- dtype detector ----
__global__ void k_detect(const unsigned* __restrict__ w, int* __restrict__ flag) {
  __shared__ int cnt[256];
  unsigned x = w[threadIdx.x];
  unsigned ex = (x >> 7) & 0xFFu;
  cnt[threadIdx.x] = (ex >= 96u && ex <= 144u) ? 1 : 0;
  __syncthreads();
  for (int s = 128; s > 0; s >>= 1) {
    if (threadIdx.x < s) cnt[threadIdx.x] += cnt[threadIdx.x + s];
    __syncthreads();
  }
  if (threadIdx.x == 0) *flag = (cnt[0] < 128) ? 1 : 0;  // 1 = f32 inputs
}

// ---- all-weights canonicalization ----
struct WArgs { const void* src[21]; int beg[22]; int len[21]; };
__global__ void k_cvt_all(WArgs wa, bf16* __restrict__ dst, int total,
                          const int* __restrict__ flagp) {
  int f = *flagp;
  for (int i = blockIdx.x * 256 + threadIdx.x; i < total; i += gridDim.x * 256) {
    int t = 0;
    while (t < 20 && i >= wa.beg[t + 1]) ++t;
    int loc = i - wa.beg[t];
    bf16 v = f2b(0.0f);
    if (loc < wa.len[t])
      v = f ? f2b(((const float*)wa.src[t])[loc]) : ((const bf16*)wa.src[t])[loc];
    dst[i] = v;
  }
}

// ---- nfeats/efeats f32->bf16 canonicalization (no-op in bf16 mode) ----
__global__ void k_cvt2(const float* __restrict__ a, bf16* __restrict__ da, size_t na,
                       const float* __restrict__ c, bf16* __restrict__ dc, size_t nc,
                       const int* __restrict__ flagp) {
  if (!*flagp) return;
  size_t tot = (na + nc) >> 2;
  for (size_t i = (size_t)blockIdx.x * 256 + threadIdx.x; i < tot;
       i += (size_t)gridDim.x * 256) {
    size_t j = i << 2;
    const float* s; bf16* d; size_t loc;
    if (j < na) { s = a; d = da; loc = j; }
    else        { s = c; d = dc; loc = j - na; }
    float4 v = *(const float4*)(s + loc);
    s16x4 o; o[0] = f2bs(v.x); o[1] = f2bs(v.y); o[2] = f2bs(v.z); o[3] = f2bs(v.w);
    *(s16x4*)(d + loc) = o;
  }
}

// ---- single-array f32->bf16 (xfeats, run between P1 and P2) ----
__global__ void k_cvt1(const float* __restrict__ c, bf16* __restrict__ dc, size_t nc,
                       const int* __restrict__ flagp) {
  if (!*flagp) return;
  size_t tot = nc >> 2;
  for (size_t i = (size_t)blockIdx.x * 256 + threadIdx.x; i < tot;
       i += (size_t)gridDim.x * 256) {
    size_t loc = i << 2;
    float4 v = *(const float4*)(c + loc);
    s16x4 o; o[0] = f2bs(v.x); o[1] = f2bs(v.y); o[2] = f2bs(v.z); o[3] = f2bs(v.w);
    *(s16x4*)(dc + loc) = o;
  }
}

__global__ void k_izero(int* __restrict__ p, int n) {
  int i = blockIdx.x * 256 + threadIdx.x;
  for (; i < n; i += gridDim.x * 256) p[i] = 0;
}

// ---------------- CSR build ----------------
__global__ void k_hist(const int* __restrict__ seg, int* __restrict__ deg, int n) {
  int i = blockIdx.x * 256 + threadIdx.x;
  if (i < n) atomicAdd(&deg[seg[i]], 1);
}

__global__ __launch_bounds__(256)
void k_scan_local(const int* __restrict__ deg, int* __restrict__ rp,
                  int* __restrict__ bsum, int n) {
  __shared__ int sh[256];
  int tid = threadIdx.x;
  int base = blockIdx.x * 4096 + tid * 16;
  int v[16]; int s = 0;
#pragma unroll
  for (int j = 0; j < 16; ++j) { v[j] = (base + j < n) ? deg[base + j] : 0; s += v[j]; }
  sh[tid] = s;
  __syncthreads();
  for (int o = 1; o < 256; o <<= 1) {
    int t = (tid >= o) ? sh[tid - o] : 0;
    __syncthreads();
    sh[tid] += t;
    __syncthreads();
  }
  int run = sh[tid] - s;
#pragma unroll
  for (int j = 0; j < 16; ++j) {
    run += v[j];
    if (base + j < n) rp[base + j + 1] = run;
  }
  if (tid == 255) bsum[blockIdx.x] = sh[255];
  if (blockIdx.x == 0 && tid == 0) rp[0] = 0;
}
__global__ __launch_bounds__(256)
void k_scan_bsum(int* __restrict__ bsum, int nb) {
  __shared__ int sh[256];
  __shared__ int carry;
  int tid = threadIdx.x;
  if (tid == 0) carry = 0;
  __syncthreads();
  for (int base = 0; base < nb; base += 256) {
    int i = base + tid;
    int v = (i < nb) ? bsum[i] : 0;
    sh[tid] = v;
    __syncthreads();
    for (int o = 1; o < 256; o <<= 1) {
      int t = (tid >= o) ? sh[tid - o] : 0;
      __syncthreads();
      sh[tid] += t;
      __syncthreads();
    }
    if (i < nb) bsum[i] = carry + sh[tid] - v;
    int tot = sh[255];
    __syncthreads();
    if (tid == 0) carry += tot;
    __syncthreads();
  }
}
__global__ __launch_bounds__(256)
void k_scan_add(int* __restrict__ rp, const int* __restrict__ bsum, int n) {
  int b = blockIdx.x + 1;
  int ofs = bsum[b];
  int base = b * 4096 + threadIdx.x * 16;
#pragma unroll
  for (int j = 0; j < 16; ++j) {
    int idx = base + j + 1;
    if (idx <= n) rp[idx] += ofs;
  }
}

__global__ void k_slot(const int* __restrict__ seg, const int* __restrict__ rp,
                       int* __restrict__ cur, int* __restrict__ eid,
                       const int* __restrict__ aux1, int* __restrict__ av1,
                       int* __restrict__ pos, int n) {
  int i = blockIdx.x * 256 + threadIdx.x;
  if (i >= n) return;
  int t = seg[i];
  int p = atomicAdd(&cur[t], 1);
  int j = rp[t] + p;
  eid[j] = i;
  if (av1) av1[j] = aux1[i];
  if (pos) pos[i] = j;
}

// ---------------- gather-mean ----------------
__global__ void k_gmean(const void* __restrict__ X, const void* __restrict__ Xc, int mode,
                        const int* __restrict__ rp, const int* __restrict__ eid,
                        bf16* __restrict__ out, int n, int width,
                        const int* __restrict__ flagp) {
  int f = (mode == 2) ? *flagp : mode;
  if (Xc && f) { X = Xc; f = 0; }
  int d = threadIdx.x;
  int row = blockIdx.x * blockDim.y + threadIdx.y;
  if (row >= n) return;
  int b = rp[row], e = rp[row + 1];
  float s = 0.0f;
  for (int j = b; j < e; ++j) s += ldF(X, (size_t)eid[j] * width + d, f);
  out[(size_t)row * width + d] = f2b(s / fmaxf((float)(e - b), 1.0f));
}

// =================== MFMA GEMM: C[.,colofs+0..63] = A @ Wh^T (+bias), unswizzled ====
__global__ __launch_bounds__(256)
void k_mgemm(const void* __restrict__ A0, const void* __restrict__ A0c, int m0mode, int K0,
             const void* __restrict__ A1, int m1mode, int Ktot,
             const bf16* __restrict__ W, int whs, const bf16* __restrict__ bias,
             bf16* __restrict__ C, int cs, int M,
             const int* __restrict__ flagp) {
  int tid = threadIdx.x;
  int w = tid >> 6, lane = tid & 63, l15 = lane & 15, q = lane >> 4;
  int h = blockIdx.y;
  int fl = *flagp;
  int f0 = (m0mode == 2) ? fl : m0mode;
  if (A0c && f0) { A0 = A0c; f0 = 0; }
  int f1 = (m1mode == 2) ? fl : m1mode;
  const bf16* Wh = W + (size_t)h * whs;
  int colofs = h * 64;
  int m0 = blockIdx.x * 64 + w * 16;
  int mA = m0 + l15; if (mA > M - 1) mA = M - 1;
  const char* rowA0 = (const char*)A0 + (size_t)mA * K0 * (f0 ? 4 : 2);
  const char* rowA1 = A1 ? (const char*)A1 + (size_t)mA * (Ktot - K0) * (f1 ? 4 : 2) : nullptr;

  f32x4 acc[4] = {{0,0,0,0},{0,0,0,0},{0,0,0,0},{0,0,0,0}};
  for (int k = q * 8; k < Ktot; k += 32) {
    bf16x8 a;
    if (k < K0) a = ldA8(rowA0, k, f0);
    else        a = ldA8(rowA1, k - K0, f1);
    const bf16* wb = Wh + (size_t)l15 * Ktot + k;
#pragma unroll
    for (int t = 0; t < 4; ++t)
      acc[t] = __builtin_amdgcn_mfma_f32_16x16x32_bf16(
          a, *(const bf16x8*)(wb + (size_t)(t * 16) * Ktot), acc[t], 0, 0, 0);
  }
#pragma unroll
  for (int t = 0; t < 4; ++t) {
    int col = t * 16 + l15;
    float bv = bias ? b2f(bias[colofs + col]) : 0.0f;
#pragma unroll
    for (int r = 0; r < 4; ++r) {
      int m = m0 + q * 4 + r;
      if (m < M) C[(size_t)m * cs + colofs + col] = f2b(acc[t][r] + bv);
    }
  }
}

// ---- dual-output GEMM, h-contiguous swizzle: elem(h,col=t*16+l15) at l15*4*HB+hy*4+t ----
__global__ __launch_bounds__(256)
void k_mgemm2sw(const void* __restrict__ A, const void* __restrict__ Ac, int mode, int K,
                const bf16* __restrict__ W1, const bf16* __restrict__ W2, int whs,
                int h0, int HB, bf16* __restrict__ C1, bf16* __restrict__ C2, int M,
                const int* __restrict__ flagp) {
  int tid = threadIdx.x;
  int w = tid >> 6, lane = tid & 63, l15 = lane & 15, q = lane >> 4;
  int hy = blockIdx.y;
  int h = h0 + hy;
  int f = (mode == 2) ? *flagp : mode;
  if (Ac && f) { A = Ac; f = 0; }
  const bf16* W1h = W1 + (size_t)h * whs;
  const bf16* W2h = W2 + (size_t)h * whs;
  int cs = HB * 64;
  int m0 = blockIdx.x * 64 + w * 16;
  int mA = m0 + l15; if (mA > M - 1) mA = M - 1;
  const char* rowA = (const char*)A + (size_t)mA * K * (f ? 4 : 2);

  f32x4 a1[4] = {{0,0,0,0},{0,0,0,0},{0,0,0,0},{0,0,0,0}};
  f32x4 a2[4] = {{0,0,0,0},{0,0,0,0},{0,0,0,0},{0,0,0,0}};
  for (int k = q * 8; k < K; k += 32) {
    bf16x8 a = ldA8(rowA, k, f);
    const bf16* w1 = W1h + (size_t)l15 * K + k;
    const bf16* w2 = W2h + (size_t)l15 * K + k;
#pragma unroll
    for (int t = 0; t < 4; ++t) {
      a1[t] = __builtin_amdgcn_mfma_f32_16x16x32_bf16(
          a, *(const bf16x8*)(w1 + (size_t)(t * 16) * K), a1[t], 0, 0, 0);
      a2[t] = __builtin_amdgcn_mfma_f32_16x16x32_bf16(
          a, *(const bf16x8*)(w2 + (size_t)(t * 16) * K), a2[t], 0, 0, 0);
    }
  }
  int ofs = l15 * 4 * HB + hy * 4;
#pragma unroll
  for (int r = 0; r < 4; ++r) {
    int m = m0 + q * 4 + r;
    if (m < M) {
      s16x4 o1, o2;
#pragma unroll
      for (int t = 0; t < 4; ++t) { o1[t] = f2bs(a1[t][r]); o2[t] = f2bs(a2[t][r]); }
      *(s16x4*)(C1 + (size_t)m * cs + ofs) = o1;
      *(s16x4*)(C2 + (size_t)m * cs + ofs) = o2;
    }
  }
}

// ====== all-heads fused combine (P1/P3), bf16-only A-stream ======
template<int NK>
__global__ __launch_bounds__(256)
void k_mcomb4sw(const bf16* __restrict__ A, const bf16* __restrict__ Ac,
                const bf16* __restrict__ W, int whs,
                const bf16* __restrict__ bias, const bf16* __restrict__ attn,
                const bf16* __restrict__ G1, const bf16* __restrict__ G2,
                const int* __restrict__ gi, const int* __restrict__ gj,
                const int* __restrict__ posw,
                float* __restrict__ lg4, bf16* __restrict__ fout,
                int M, const int* __restrict__ flagp) {
  constexpr int K = NK * 32;
  int tid = threadIdx.x;
  int w = tid >> 6, lane = tid & 63, l15 = lane & 15, q = lane >> 4;
  if (Ac && *flagp) A = Ac;
  int m0 = blockIdx.x * 64 + w * 16;
  int mA = m0 + l15; if (mA > M - 1) mA = M - 1;
  const bf16* rowA = A + (size_t)mA * K;
  bf16x8 af[NK];
#pragma unroll
  for (int i = 0; i < NK; ++i) af[i] = *(const bf16x8*)(rowA + q * 8 + 32 * i);
  int pIdx[4]; bool okr[4];
  bf16x8 gv1[4][2], gv2[4][2];
#pragma unroll
  for (int r = 0; r < 4; ++r) {
    int m = m0 + q * 4 + r;
    okr[r] = m < M; int mc = okr[r] ? m : M - 1;
    pIdx[r] = posw ? posw[mc] : mc;
    const bf16* p1 = G1 + (size_t)gi[mc] * 256 + l15 * 16;
    const bf16* p2 = G2 + (size_t)gj[mc] * 256 + l15 * 16;
    gv1[r][0] = *(const bf16x8*)p1; gv1[r][1] = *(const bf16x8*)(p1 + 8);
    gv2[r][0] = *(const bf16x8*)p2; gv2[r][1] = *(const bf16x8*)(p2 + 8);
  }
  f32x4 fs[4] = {{0,0,0,0},{0,0,0,0},{0,0,0,0},{0,0,0,0}};
#pragma unroll
  for (int h = 0; h < 4; ++h) {
    const bf16* Wh = W + (size_t)h * whs;
    f32x4 acc[4] = {{0,0,0,0},{0,0,0,0},{0,0,0,0},{0,0,0,0}};
#pragma unroll
    for (int i = 0; i < NK; ++i) {
      const bf16* wb = Wh + (size_t)l15 * K + q * 8 + 32 * i;
#pragma unroll
      for (int t = 0; t < 4; ++t)
        acc[t] = __builtin_amdgcn_mfma_f32_16x16x32_bf16(
            af[i], *(const bf16x8*)(wb + (size_t)(t * 16) * K), acc[t], 0, 0, 0);
    }
    float bv[4], av[4];
#pragma unroll
    for (int t = 0; t < 4; ++t) {
      bv[t] = b2f(bias[h * 64 + t * 16 + l15]);
      av[t] = b2f(attn[h * 64 + t * 16 + l15]);
    }
    float part[4];
#pragma unroll
    for (int r = 0; r < 4; ++r) {
      float p = 0.0f;
#pragma unroll
      for (int t = 0; t < 4; ++t) {
        float v = acc[t][r] + bv[t] + sb2f(gv1[r][h >> 1][(h & 1) * 4 + t])
                                    + sb2f(gv2[r][h >> 1][(h & 1) * 4 + t]);
        v = leaky(v);
        p += v * av[t];
        fs[t][r] += v;
      }
      part[r] = p;
    }
#pragma unroll
    for (int o = 1; o < 16; o <<= 1)
#pragma unroll
      for (int r = 0; r < 4; ++r) part[r] += __shfl_xor(part[r], o, 64);
    if (l15 == 0) {
#pragma unroll
      for (int r = 0; r < 4; ++r)
        if (okr[r]) lg4[(size_t)pIdx[r] * 4 + h] = part[r];
    }
  }
  if (fout) {
#pragma unroll
    for (int t = 0; t < 4; ++t) {
      int col = t * 16 + l15;
#pragma unroll
      for (int r = 0; r < 4; ++r)
        if (okr[r]) fout[(size_t)(m0 + q * 4 + r) * 64 + col] = f2b(fs[t][r]);
    }
  }
}

// ====== 2-head fused combine (P2), bf16-only A-stream ======
template<int NK>
__global__ __launch_bounds__(256)
void k_mcomb2h(const bf16* __restrict__ A, const bf16* __restrict__ Ac,
               const bf16* __restrict__ W, int whs, int h0,
               const bf16* __restrict__ bias, const bf16* __restrict__ attn,
               const bf16* __restrict__ G1, const bf16* __restrict__ G2,
               const int* __restrict__ gi, const int* __restrict__ gj,
               const int* __restrict__ posw,
               float* __restrict__ lg4, int M, const int* __restrict__ flagp) {
  constexpr int K = NK * 32;
  int tid = threadIdx.x;
  int w = tid >> 6, lane = tid & 63, l15 = lane & 15, q = lane >> 4;
  if (Ac && *flagp) A = Ac;
  int m0 = blockIdx.x * 64 + w * 16;
  int mA = m0 + l15; if (mA > M - 1) mA = M - 1;
  const bf16* rowA = A + (size_t)mA * K;
  bf16x8 af[NK];
#pragma unroll
  for (int i = 0; i < NK; ++i) af[i] = *(const bf16x8*)(rowA + q * 8 + 32 * i);
  int pIdx[4]; bool okr[4];
  bf16x8 gv1[4], gv2[4];
#pragma unroll
  for (int r = 0; r < 4; ++r) {
    int m = m0 + q * 4 + r;
    okr[r] = m < M; int mc = okr[r] ? m : M - 1;
    pIdx[r] = posw ? posw[mc] : mc;
    gv1[r] = *(const bf16x8*)(G1 + (size_t)gi[mc] * 128 + l15 * 8);
    gv2[r] = *(const bf16x8*)(G2 + (size_t)gj[mc] * 128 + l15 * 8);
  }
#pragma unroll
  for (int hy = 0; hy < 2; ++hy) {
    int h = h0 + hy;
    const bf16* Wh = W + (size_t)h * whs;
    f32x4 acc[4] = {{0,0,0,0},{0,0,0,0},{0,0,0,0},{0,0,0,0}};
#pragma unroll
    for (int i = 0; i < NK; ++i) {
      const bf16* wb = Wh + (size_t)l15 * K + q * 8 + 32 * i;
#pragma unroll
      for (int t = 0; t < 4; ++t)
        acc[t] = __builtin_amdgcn_mfma_f32_16x16x32_bf16(
            af[i], *(const bf16x8*)(wb + (size_t)(t * 16) * K), acc[t], 0, 0, 0);
    }
    float bv[4], av[4];
#pragma unroll
    for (int t = 0; t < 4; ++t) {
      bv[t] = b2f(bias[h * 64 + t * 16 + l15]);
      av[t] = b2f(attn[h * 64 + t * 16 + l15]);
    }
    float part[4];
#pragma unroll
    for (int r = 0; r < 4; ++r) {
      float p = 0.0f;
#pragma unroll
      for (int t = 0; t < 4; ++t) {
        float v = acc[t][r] + bv[t] + sb2f(gv1[r][hy * 4 + t]) + sb2f(gv2[r][hy * 4 + t]);
        p += leaky(v) * av[t];
      }
      part[r] = p;
    }
#pragma unroll
    for (int o = 1; o < 16; o <<= 1)
#pragma unroll
      for (int r = 0; r < 4; ++r) part[r] += __shfl_xor(part[r], o, 64);
    if (l15 == 0) {
#pragma unroll
      for (int r = 0; r < 4; ++r)
        if (okr[r]) lg4[(size_t)pIdx[r] * 4 + h] = part[r];
    }
  }
}

// ---------------- fused per-row CSR softmax (normalizes in place) ----------------
__global__ __launch_bounds__(256)
void k_smax4_csr(float* __restrict__ lg, const int* __restrict__ rp, int n) {
  int tid = blockIdx.x * 256 + threadIdx.x;
  int row = tid >> 2, h = tid & 3;
  if (row >= n) return;
  int b = rp[row], e = rp[row + 1];
  float m = -INFINITY;
  for (int j = b; j < e; ++j) m = fmaxf(m, lg[(size_t)j * 4 + h]);
  float s = 0.0f;
  for (int j = b; j < e; ++j) {
    float ex = expf(lg[(size_t)j * 4 + h] - m);
    lg[(size_t)j * 4 + h] = ex;
    s += ex;
  }
  float inv = 1.0f / s;
  for (int j = b; j < e; ++j) lg[(size_t)j * 4 + h] *= inv;
}
__global__ __launch_bounds__(256)
void k_smax4_eid(float* __restrict__ lg, const int* __restrict__ rp,
                 const int* __restrict__ eid, int n) {
  int tid = blockIdx.x * 256 + threadIdx.x;
  int row = tid >> 2, h = tid & 3;
  if (row >= n) return;
  int b = rp[row], e = rp[row + 1];
  float m = -INFINITY;
  for (int j = b; j < e; ++j) m = fmaxf(m, lg[(size_t)eid[j] * 4 + h]);
  float s = 0.0f;
  for (int j = b; j < e; ++j) {
    float ex = expf(lg[(size_t)eid[j] * 4 + h] - m);
    lg[(size_t)eid[j] * 4 + h] = ex;
    s += ex;
  }
  float inv = 1.0f / s;
  for (int j = b; j < e; ++j) lg[(size_t)eid[j] * 4 + h] *= inv;
}

// ---- P1 epilogue: one node/block, head = wave ----
__global__ __launch_bounds__(256)
void k_ghnode(const bf16* __restrict__ H, const float* __restrict__ lg4c,
              const int* __restrict__ rp, const int* __restrict__ srcv,
              bf16* __restrict__ hnode, int N) {
  int d = threadIdx.x, h = threadIdx.y;
  int n = blockIdx.x;
  int b = rp[n], e = rp[n + 1];
  float s = 0.0f;
  for (int j = b; j < e; ++j)
    s += b2f(H[(size_t)srcv[j] * 256 + h * 64 + d]) * lg4c[(size_t)j * 4 + h];
  float v = leaky(s);
  __shared__ float sh[4][64];
  if (h > 0) sh[h][d] = v;
  __syncthreads();
  if (h == 0)
    hnode[(size_t)n * 64 + d] = f2b(v + sh[1][d] + sh[2][d] + sh[3][d]);
}

// ---- P2 epilogue: 2 heads per pass, M1 = [E,128] (head pair columns) ----
__global__ void k_gout2x2(const bf16* __restrict__ M1, const float* __restrict__ lgE4,
                          int h0, const int* __restrict__ rp, const int* __restrict__ lsv,
                          float* __restrict__ out, int E, int first) {
  int d = threadIdx.x;
  int t = blockIdx.x * 4 + threadIdx.y;
  if (t >= E) return;
  int b = rp[t], e = rp[t + 1];
  float s0 = 0.0f, s1 = 0.0f;
  for (int j = b; j < e; ++j) {
    size_t row = (size_t)lsv[j] * 128;
    float w0 = lgE4[(size_t)j * 4 + h0];
    float w1 = lgE4[(size_t)j * 4 + h0 + 1];
    s0 += b2f(M1[row + d]) * w0;
    s1 += b2f(M1[row + 64 + d]) * w1;
  }
  float val = leaky(s0) + leaky(s1);
  if (first) out[(size_t)t * 64 + d] = val;
  else       out[(size_t)t * 64 + d] += val;
}

// ---- P3 linearity: AGG[t,0:64]=sum ne[lsv[j]], AGG[t,64:128]=sum fedge[lsv[j]] ----
__global__ void k_gagg(const bf16* __restrict__ ne, const bf16* __restrict__ fe,
                       const int* __restrict__ rp, const int* __restrict__ lsv,
                       bf16* __restrict__ agg, int E) {
  int d = threadIdx.x;
  int t = blockIdx.x * 4 + threadIdx.y;
  if (t >= E) return;
  int b = rp[t], e = rp[t + 1];
  float s1 = 0.0f, s2 = 0.0f;
  for (int j = b; j < e; ++j) {
    size_t row = (size_t)lsv[j] * 64 + d;
    s1 += b2f(ne[row]);
    s2 += b2f(fe[row]);
  }
  agg[(size_t)t * 128 + d]      = f2b(s1);
  agg[(size_t)t * 128 + 64 + d] = f2b(s2);
}

// ---- P3 fused: out[t,col] += sum_h leaky( a[t,h] * (AGG[t]@W_h^T + deg[t]*b_h) ) ----
__global__ __launch_bounds__(256)
void k_mgemm3(const bf16* __restrict__ A, const bf16* __restrict__ W, int whs,
              const bf16* __restrict__ bias, const float* __restrict__ lg4n,
              const int* __restrict__ rp, float* __restrict__ out, int M) {
  int tid = threadIdx.x;
  int w = tid >> 6, lane = tid & 63, l15 = lane & 15, q = lane >> 4;
  int m0 = blockIdx.x * 64 + w * 16;
  int mA = m0 + l15; if (mA > M - 1) mA = M - 1;
  const bf16* rowA = A + (size_t)mA * 128;
  bf16x8 af[4];
#pragma unroll
  for (int i = 0; i < 4; ++i) af[i] = *(const bf16x8*)(rowA + q * 8 + 32 * i);
  bool okr[4]; float degv[4]; float av[4][4];
#pragma unroll
  for (int r = 0; r < 4; ++r) {
    int m = m0 + q * 4 + r;
    okr[r] = m < M; int mc = okr[r] ? m : M - 1;
    degv[r] = (float)(rp[mc + 1] - rp[mc]);
#pragma unroll
    for (int h = 0; h < 4; ++h) av[r][h] = lg4n[(size_t)mc * 4 + h];
  }
  float osum[4][4] = {{0,0,0,0},{0,0,0,0},{0,0,0,0},{0,0,0,0}};
#pragma unroll
  for (int h = 0; h < 4; ++h) {
    const bf16* Wh = W + (size_t)h * whs;
    f32x4 acc[4] = {{0,0,0,0},{0,0,0,0},{0,0,0,0},{0,0,0,0}};
#pragma unroll
    for (int i = 0; i < 4; ++i) {
      const bf16* wb = Wh + (size_t)l15 * 128 + q * 8 + 32 * i;
#pragma unroll
      for (int t = 0; t < 4; ++t)
        acc[t] = __builtin_amdgcn_mfma_f32_16x16x32_bf16(
            af[i], *(const bf16x8*)(wb + (size_t)(t * 16) * 128), acc[t], 0, 0, 0);
    }
#pragma unroll
    for (int t = 0; t < 4; ++t) {
      float bv = b2f(bias[h * 64 + t * 16 + l15]);
#pragma unroll
      for (int r = 0; r < 4; ++r)
        osum[t][r] += leaky(av[r][h] * (acc[t][r] + degv[r] * bv));
    }
  }
#pragma unroll
  for (int t = 0; t < 4; ++t) {
    int col = t * 16 + l15;
#pragma unroll
    for (int r = 0; r < 4; ++r) {
      int m = m0 + q * 4 + r;
      if (m < M) out[(size_t)m * 64 + col] += osum[t][r];
    }
  }
}

// ---- P3 pre: ne[e] = hnode[src[e]] + hnode[dst[e]] ----
__global__ void k_addpair(const bf16* __restrict__ hn, const int* __restrict__ src,
                          const int* __restrict__ dst, bf16* __restrict__ ne, int E) {
  int d = threadIdx.x;
  int e = blockIdx.x * 4 + threadIdx.y;
  if (e >= E) return;
  ne[(size_t)e * 64 + d] =
      f2b(b2f(hn[(size_t)src[e] * 64 + d]) + b2f(hn[(size_t)dst[e] * 64 + d]));
}

__global__ void k_cast(void* __restrict__ out, const float* __restrict__ a, size_t n,
                       const int* __restrict__ flagp) {
  int f = *flagp;
  size_t i = (size_t)blockIdx.x * blockDim.x + threadIdx.x;
  size_t st = (size_t)gridDim.x * blockDim.x;
  for (; i < n; i += st) {
    if (f) ((float*)out)[i] = a[i];
    else   ((bf16*)out)[i] = f2b(a[i]);
  }
}

extern "C" void kernel_launch(void* const* d_in, const int* in_sizes, int n_in,
                              void* d_out, int out_size, void* d_ws, size_t ws_size,
                              hipStream_t stream) {
  const int* src  = (const int*)d_in[24];
  const int* dst  = (const int*)d_in[25];
  const int* lsrc = (const int*)d_in[26];
  const int* ldst = (const int*)d_in[27];

  const int N  = in_sizes[0] / 128;
  const int E  = in_sizes[24];
  const int EL = in_sizes[26];
  (void)n_in; (void)out_size; (void)ws_size;

  // ---- workspace (~163 MB, under proven 167 MB) ----
  char* base = (char*)d_ws;
  size_t off = 0;
  auto alloc = [&](size_t bytes) -> char* {
    char* p = base + off;
    off = (off + bytes + 255) & ~(size_t)255;
    return p;
  };
  int* flag = (int*)alloc(256);
  size_t wofs[28]; size_t wtot = 0;
  for (int i = 3; i <= 23; ++i) { wofs[i] = wtot; wtot += (size_t)((in_sizes[i] + 127) & ~127); }
  bf16* WA = (bf16*)alloc(wtot * 2);

  int*   tmpi  = (int*)alloc((size_t)2 * E * 4);        // deg | cur
  int*   rpN   = (int*)alloc((size_t)(N + 1) * 4);
  int*   eidN  = (int*)alloc((size_t)E * 4);
  int*   srcv  = (int*)alloc((size_t)E * 4);            // src[eid] (CSR order)
  int*   posN  = (int*)alloc((size_t)E * 4);            // edge -> CSR slot
  int*   rpE   = (int*)alloc((size_t)(E + 1) * 4);
  int*   eidEL = (int*)alloc((size_t)EL * 4);
  int*   lsv   = (int*)alloc((size_t)EL * 4);           // lsrc[eid] (CSR order)
  int*   posE  = (int*)alloc((size_t)EL * 4);           // lg-edge -> CSR slot
  int*   bsum  = (int*)alloc(((size_t)((E > N ? E : N) + 4095) / 4096 + 8) * 4);
  bf16*  fedge = (bf16*)alloc((size_t)E * 64 * 2);      // P1 -> P2/P3 (element order)
  bf16*  hnode = (bf16*)alloc((size_t)N * 64 * 2);
  float* outacc= (float*)alloc((size_t)E * 64 * 4);     // accumulator; aliased as table SBo
  bf16*  aggB  = (bf16*)alloc((size_t)E * 64 * 2);      // P1 agg[N,128]/P2 aggx/P3 ne
  size_t saElems = (size_t)E * 128 > (size_t)2 * N * 256 ? (size_t)E * 128
                                                         : (size_t)2 * N * 256;
  bf16*  SA    = (bf16*)alloc(saElems * 2);             // table/AGG region (P3: 2x[N,256])
  float* logE4 = (float*)alloc((size_t)E * 4 * 4);
  float* logEL4= (float*)alloc((size_t)EL * 4 * 4);
  bf16*  nb    = (bf16*)alloc((size_t)N * 128 * 2);     // nfeats bf16 canonical

  bf16* SBo = (bf16*)outacc;      // second table region (free until P2 phase B)
  // d_out time-shared scratch: eb (efeats bf16) during P1, then xb (xfeats bf16) for P2
  bf16* eb = (bf16*)d_out;
  bf16* xb = (bf16*)d_out;

  dim3 blk(256);
  const unsigned tN = (N + 63) / 64, tEg = (E + 63) / 64, tELg = (EL + 63) / 64;
  const unsigned gE4 = (E + 3) / 4;
  const unsigned cE = (E + 255) / 256, cEL = (EL + 255) / 256;
  const int nbN = (N + 4095) / 4096, nbE = (E + 4095) / 4096;

  // ---- dtype detect + weights + nfeats/efeats canonicalization ----
  k_detect<<<dim3(1), blk, 0, stream>>>((const unsigned*)d_in[0], flag);
  WArgs wa;
  for (int i = 3; i <= 23; ++i) {
    wa.src[i - 3] = d_in[i];
    wa.beg[i - 3] = (int)wofs[i];
    wa.len[i - 3] = in_sizes[i];
  }
  wa.beg[21] = (int)wtot;
  k_cvt_all<<<dim3(512), blk, 0, stream>>>(wa, WA, (int)wtot, flag);
  k_cvt2<<<dim3(2048), blk, 0, stream>>>(
      (const float*)d_in[0], nb, (size_t)N * 128,
      (const float*)d_in[1], eb, (size_t)E * 128, flag);

  // ---- CSR builds ----
  int* deg = tmpi; int* cur = tmpi + E;
  k_izero<<<dim3(1024), blk, 0, stream>>>(tmpi, 2 * E);
  k_hist<<<dim3(cE), blk, 0, stream>>>(dst, deg, E);
  k_scan_local<<<dim3(nbN), blk, 0, stream>>>(deg, rpN, bsum, N);
  k_scan_bsum<<<dim3(1), blk, 0, stream>>>(bsum, nbN);
  if (nbN > 1) k_scan_add<<<dim3(nbN - 1), blk, 0, stream>>>(rpN, bsum, N);
  k_slot<<<dim3(cE), blk, 0, stream>>>(dst, rpN, cur, eidN, src, srcv, posN, E);
  k_izero<<<dim3(1024), blk, 0, stream>>>(tmpi, 2 * E);
  k_hist<<<dim3(cEL), blk, 0, stream>>>(ldst, deg, EL);
  k_scan_local<<<dim3(nbE), blk, 0, stream>>>(deg, rpE, bsum, E);
  k_scan_bsum<<<dim3(1), blk, 0, stream>>>(bsum, nbE);
  if (nbE > 1) k_scan_add<<<dim3(nbE - 1), blk, 0, stream>>>(rpE, bsum, E);
  k_slot<<<dim3(cEL), blk, 0, stream>>>(ldst, rpE, cur, eidEL, lsrc, lsv, posE, EL);

  // ================= Phase 1: EGAT =================
  k_gmean<<<dim3((N + 1) / 2), dim3(128, 2), 0, stream>>>(d_in[1], eb, 2, rpN, eidN,
                                                          aggB, N, 128, flag);
  k_mgemm2sw<<<dim3(tN, 4), blk, 0, stream>>>(d_in[0], nb, 2, 128,
      WA + wofs[3], WA + wofs[4], 8192, 0, 4, SA, SBo, N, flag);
  k_mcomb4sw<4><<<dim3(tEg), blk, 0, stream>>>((const bf16*)d_in[1], eb,
      WA + wofs[5], 8192, WA + wofs[9], WA + wofs[8], SA, SBo,
      src, dst, posN, logE4, fedge, E, flag);
  k_smax4_csr<<<dim3((N * 4 + 255) / 256), blk, 0, stream>>>(logE4, rpN, N);
  k_mgemm<<<dim3(tN, 4), blk, 0, stream>>>(d_in[0], nb, 2, 128, aggB, 0, 256,
      WA + wofs[6], 16384, WA + wofs[7], SA, 256, N, flag);
  k_ghnode<<<dim3(N), dim3(64, 4), 0, stream>>>(SA, logE4, rpN, srcv, hnode, N);

  // ---- d_out handoff: eb dead, convert xfeats -> xb (same region) ----
  k_cvt1<<<dim3(2048), blk, 0, stream>>>((const float*)d_in[2], xb,
                                         (size_t)EL * 64, flag);

  // ================= Phase 2: line-graph branch =================
  k_gmean<<<dim3(gE4), dim3(64, 4), 0, stream>>>(d_in[2], xb, 2, rpE, eidEL, aggB, E, 64, flag);
  // phase A: all-head logits in 2 passes (2 heads per pass; tables [E,128] swizzled)
  for (int p = 0; p < 2; ++p) {
    k_mgemm2sw<<<dim3(tEg, 2), blk, 0, stream>>>(fedge, nullptr, 0, 64,
        WA + wofs[10], WA + wofs[11], 4096, 2 * p, 2, SA, SBo, E, flag);
    k_mcomb2h<2><<<dim3(tELg), blk, 0, stream>>>((const bf16*)d_in[2], xb,
        WA + wofs[12], 4096, 2 * p, WA + wofs[16], WA + wofs[15],
        SA, SBo, lsrc, ldst, posE, logEL4, EL, flag);
  }
  k_smax4_csr<<<dim3((E * 4 + 255) / 256), blk, 0, stream>>>(logEL4, rpE, E);
  // phase B: 2 head-pairs; batched mgemm (y=2) into SA[E,128], fused 2-head gather
  for (int p = 0; p < 2; ++p) {
    k_mgemm<<<dim3(tEg, 2), blk, 0, stream>>>(fedge, nullptr, 0, 64, aggB, 0, 128,
        WA + wofs[13] + (size_t)(2 * p) * 8192, 8192, WA + wofs[14] + 2 * p * 64,
        SA, 128, E, flag);
    k_gout2x2<<<dim3(gE4), dim3(64, 4), 0, stream>>>(SA, logEL4, 2 * p, rpE, lsv,
                                                     outacc, E, p == 0 ? 1 : 0);
  }

  // ================= Phase 3: graph branch =================
  // single 4-head pass: tables 2x[N,256] both inside SA (outacc live)
  k_mgemm2sw<<<dim3(tN, 4), blk, 0, stream>>>(hnode, nullptr, 0, 64,
      WA + wofs[17], WA + wofs[18], 4096, 0, 4, SA, SA + (size_t)N * 256, N, flag);
  k_mcomb4sw<2><<<dim3(tEg), blk, 0, stream>>>(fedge, nullptr,
      WA + wofs[19], 4096, WA + wofs[23], WA + wofs[22],
      SA, SA + (size_t)N * 256, src, dst, nullptr, logE4, nullptr, E, flag);
  k_smax4_eid<<<dim3((N * 4 + 255) / 256), blk, 0, stream>>>(logE4, rpN, eidN, N);
  k_addpair<<<dim3(gE4), dim3(64, 4), 0, stream>>>(hnode, src, dst, aggB, E);
  // linearity: aggregate [ne|fedge] once over line-CSR, then one fused 4-head GEMM epilogue
  k_gagg<<<dim3(gE4), dim3(64, 4), 0, stream>>>(aggB, fedge, rpE, lsv, SA, E);
  k_mgemm3<<<dim3(tEg), blk, 0, stream>>>(SA, WA + wofs[20], 8192, WA + wofs[21],
                                          logE4, rpE, outacc, E);

  k_cast<<<dim3(2048), blk, 0, stream>>>(d_out, outacc, (size_t)E * 64, flag);
}